// Round 13
// baseline (236.769 us; speedup 1.0000x reference)
//
#include <hip/hip_runtime.h>
#include <hip/hip_bf16.h>
#include <cstddef>

#define IN_DIM 128
#define MEM 256
#define KTOT 384
#define NLEAF 65536
#define NBLK_TAIL 8

typedef float f32x4 __attribute__((ext_vector_type(4)));
typedef short s16x8 __attribute__((ext_vector_type(8)));
typedef unsigned int u32;

__device__ inline unsigned short f2bf(float f){
    unsigned int u = __builtin_bit_cast(unsigned int, f);
    u += 0x7fff + ((u >> 16) & 1);
    return (unsigned short)(u >> 16);
}

__device__ inline void gld_lds16(const void* g, void* l){
    __builtin_amdgcn_global_load_lds((const __attribute__((address_space(1))) u32*)g,
                                     (__attribute__((address_space(3))) u32*)l, 16, 0, 0);
}

__device__ inline float fsigm(float x){
    return __builtin_amdgcn_rcpf(1.f + __expf(-x));
}
__device__ inline float ftanh(float x){
    return 2.f * __builtin_amdgcn_rcpf(1.f + __expf(-2.f * x)) - 1.f;
}

// A-arena element offsets: leaf (l=16) at 0, stride 128; levels 15..0 stride 384.
__host__ __device__ inline size_t offA(int l){
    if (l == 16) return 0;
    return 8388608u + 384u * (65536u - (1u << (l + 1)));
}
#define ARENA_ELEMS 33554048u
#define ARENA_PAD   65536u

// device-scope grid barrier (8 co-resident blocks). RELAXED polls (round-10 lesson).
__device__ inline void grid_barrier(unsigned* ctr, unsigned target){
    __syncthreads();
    if (threadIdx.x == 0){
        __threadfence();
        __hip_atomic_fetch_add(ctr, 1u, __ATOMIC_RELEASE, __HIP_MEMORY_SCOPE_AGENT);
        while (__hip_atomic_load(ctr, __ATOMIC_RELAXED, __HIP_MEMORY_SCOPE_AGENT) < target)
            __builtin_amdgcn_s_sleep(2);
    }
    __syncthreads();
    __threadfence();
}

// ---------------- fused pack: W (+bias, +ctr reset) and all x rows -> bf16 arena
__global__ void pack_kernel(const float* __restrict__ x,
                            const float* __restrict__ W_ih, const float* __restrict__ b_ih,
                            const float* __restrict__ W_hh, const float* __restrict__ b_hh,
                            unsigned short* __restrict__ Wp, float* __restrict__ bp,
                            unsigned short* __restrict__ Aarena, unsigned* __restrict__ ctr){
    const int stride = gridDim.x * blockDim.x;
    const int tid0 = blockIdx.x * blockDim.x + threadIdx.x;
    if (tid0 == 0){ ctr[0] = 0; }

    for (int g = tid0; g < 1024 * 48; g += stride){
        int row = g / 48, ko = (g - row * 48) * 8;
        const float* s = (ko < IN_DIM) ? (W_ih + (size_t)row * IN_DIM + ko)
                                       : (W_hh + (size_t)row * MEM + (ko - IN_DIM));
        f32x4 v0 = *(const f32x4*)s, v1 = *(const f32x4*)(s + 4);
        s16x8 o;
        #pragma unroll
        for (int e = 0; e < 4; ++e){ o[e] = (short)f2bf(v0[e]); o[4+e] = (short)f2bf(v1[e]); }
        *(s16x8*)(Wp + (size_t)row * KTOT + ko) = o;
        if (ko == 0) bp[row] = b_ih[row] + b_hh[row];
    }

    const int TOTAL_G = 131071 * 16;
    for (int g = tid0; g < TOTAL_G; g += stride){
        int i  = g >> 4;
        int ko = (g & 15) * 8;
        int l  = 31 - __clz(i + 1);
        int j  = i + 1 - (1 << l);
        size_t dst = offA(l) + (size_t)j * ((l == 16) ? 128 : 384) + ko;
        const f32x4* s = (const f32x4*)(x + (size_t)i * IN_DIM + ko);
        f32x4 v0 = s[0], v1 = s[1];
        s16x8 o;
        #pragma unroll
        for (int e = 0; e < 4; ++e){ o[e] = (short)f2bf(v0[e]); o[4+e] = (short)f2bf(v1[e]); }
        *(s16x8*)(Aarena + dst) = o;
    }
}

// ================= 8-phase-style 256-row GEMM + LSTM + pair-sum (leaf, l15, l14) =================
// Block: 256 rows x 64 mem cols (256 gate cols). 512 threads, 8 waves (wm 2 x wn 4).
// Wave: 128 rows x 64 gate cols -> acc[8][4]; per-lane all 4 gates of col mg.
// Half-tile staging, 2-dbuf (128 KB LDS), counted vmcnt(4), 4 compute phases/K-tile,
// setprio around MFMA clusters, slot-XOR swizzle both-sides. csum in f16.
template<int NK>
__global__ __launch_bounds__(512, 1) void gemm_lstm8p_kernel(
    const unsigned short* __restrict__ A, int n,
    const unsigned short* __restrict__ Wp, const float* __restrict__ bp,
    const _Float16* __restrict__ csum_in, int leaf,
    unsigned short* __restrict__ A_next, _Float16* __restrict__ csum_out)
{
    __shared__ __align__(16) unsigned short As[2][2][128 * 64];   // [buf][half] 64 KB
    __shared__ __align__(16) unsigned short Bs[2][2][128 * 64];   // 64 KB

    const int tid  = threadIdx.x;
    const int lane = tid & 63;
    const int wid  = tid >> 6;        // 0..7
    const int wm   = wid >> 2;        // A row-half (128 rows)
    const int wn   = wid & 3;         // mem 16-col group
    const int row0 = blockIdx.x * 256;
    const int m0   = blockIdx.y * 64;
    const int mg   = m0 + wn * 16 + (lane & 15);

    auto stageA = [&](int kt, int h){
        #pragma unroll
        for (int i = 0; i < 2; ++i){
            int p  = i * 512 + tid;
            int r  = p >> 3;
            int ls = (p & 7) ^ (r & 7);
            gld_lds16(A + (size_t)(row0 + h * 128 + r) * NK + kt * 64 + ls * 8,
                      (char*)As[kt & 1][h] + (size_t)(i * 512 + wid * 64) * 16);
        }
    };
    auto stageB = [&](int kt, int h){
        #pragma unroll
        for (int i = 0; i < 2; ++i){
            int p  = i * 512 + tid;
            int r  = p >> 3;
            int b  = h * 128 + r;
            int grow = (b >> 6) * 256 + m0 + (b & 63);
            int ls = (p & 7) ^ (r & 7);
            gld_lds16(Wp + (size_t)grow * KTOT + kt * 64 + ls * 8,
                      (char*)Bs[kt & 1][h] + (size_t)(i * 512 + wid * 64) * 16);
        }
    };

    f32x4 acc[8][4];
    #pragma unroll
    for (int r = 0; r < 8; ++r)
        #pragma unroll
        for (int q = 0; q < 4; ++q)
            acc[r][q] = (f32x4){0.f, 0.f, 0.f, 0.f};

    constexpr int nkt = NK / 64;
    stageA(0, 0); stageA(0, 1); stageB(0, 0);
    if (nkt > 1) stageB(1, 0);
    stageB(0, 1);

    s16x8 bfr[2][2];

    #pragma unroll
    for (int t = 0; t < nkt; ++t){
        const unsigned short* Ab = As[t & 1][wm];
        const unsigned short* Bb0 = Bs[t & 1][0];
        const unsigned short* Bb1 = Bs[t & 1][1];

        if (t + 1 < nkt) { asm volatile("s_waitcnt vmcnt(4)" ::: "memory"); }
        else             { asm volatile("s_waitcnt vmcnt(2)" ::: "memory"); }
        __builtin_amdgcn_s_barrier();
        asm volatile("" ::: "memory");

        #pragma unroll
        for (int rh = 0; rh < 2; ++rh){
            s16x8 a[4][2];
            #pragma unroll
            for (int j = 0; j < 4; ++j)
                #pragma unroll
                for (int ks = 0; ks < 2; ++ks){
                    int kb = (((ks * 4 + (lane >> 4)) ^ (lane & 7))) * 8;
                    a[j][ks] = *(const s16x8*)(Ab + (size_t)(rh * 64 + j * 16 + (lane & 15)) * 64 + kb);
                }
            if (rh == 0){
                #pragma unroll
                for (int q2 = 0; q2 < 2; ++q2)
                    #pragma unroll
                    for (int ks = 0; ks < 2; ++ks){
                        int kb = (((ks * 4 + (lane >> 4)) ^ (lane & 7))) * 8;
                        bfr[q2][ks] = *(const s16x8*)(Bb0 + (size_t)(q2 * 64 + wn * 16 + (lane & 15)) * 64 + kb);
                    }
                if (t + 1 < nkt) stageA(t + 1, 0);
            } else {
                if (t + 1 < nkt) stageA(t + 1, 1);
            }
            __builtin_amdgcn_s_setprio(1);
            #pragma unroll
            for (int j = 0; j < 4; ++j)
                #pragma unroll
                for (int q2 = 0; q2 < 2; ++q2)
                    #pragma unroll
                    for (int ks = 0; ks < 2; ++ks)
                        acc[rh * 4 + j][q2] = __builtin_amdgcn_mfma_f32_16x16x32_bf16(
                            a[j][ks], bfr[q2][ks], acc[rh * 4 + j][q2], 0, 0, 0);
            __builtin_amdgcn_s_setprio(0);
        }

        if (t + 1 < nkt) { asm volatile("s_waitcnt vmcnt(4)" ::: "memory"); }
        else             { asm volatile("s_waitcnt vmcnt(0)" ::: "memory"); }
        __builtin_amdgcn_s_barrier();
        asm volatile("" ::: "memory");

        #pragma unroll
        for (int rh = 0; rh < 2; ++rh){
            s16x8 a[4][2];
            #pragma unroll
            for (int j = 0; j < 4; ++j)
                #pragma unroll
                for (int ks = 0; ks < 2; ++ks){
                    int kb = (((ks * 4 + (lane >> 4)) ^ (lane & 7))) * 8;
                    a[j][ks] = *(const s16x8*)(Ab + (size_t)(rh * 64 + j * 16 + (lane & 15)) * 64 + kb);
                }
            if (rh == 0){
                #pragma unroll
                for (int q2 = 0; q2 < 2; ++q2)
                    #pragma unroll
                    for (int ks = 0; ks < 2; ++ks){
                        int kb = (((ks * 4 + (lane >> 4)) ^ (lane & 7))) * 8;
                        bfr[q2][ks] = *(const s16x8*)(Bb1 + (size_t)(q2 * 64 + wn * 16 + (lane & 15)) * 64 + kb);
                    }
                if (t + 2 < nkt) stageB(t + 2, 0);
            } else {
                if (t + 1 < nkt) stageB(t + 1, 1);
            }
            __builtin_amdgcn_s_setprio(1);
            #pragma unroll
            for (int j = 0; j < 4; ++j)
                #pragma unroll
                for (int q2 = 0; q2 < 2; ++q2)
                    #pragma unroll
                    for (int ks = 0; ks < 2; ++ks)
                        acc[rh * 4 + j][2 + q2] = __builtin_amdgcn_mfma_f32_16x16x32_bf16(
                            a[j][ks], bfr[q2][ks], acc[rh * 4 + j][2 + q2], 0, 0, 0);
            __builtin_amdgcn_s_setprio(0);
        }
        __builtin_amdgcn_s_barrier();
        asm volatile("" ::: "memory");
    }

    // -------- epilogue: lane owns 32 rows x col mg, all 4 gates
    const float b0 = bp[0 * 256 + mg];
    const float b1 = bp[1 * 256 + mg];
    const float b2 = bp[2 * 256 + mg];
    const float b3 = bp[3 * 256 + mg];
    #pragma unroll
    for (int r = 0; r < 8; ++r){
        const int base = row0 + wm * 128 + r * 16 + (lane >> 4) * 4;
        float cpre[4];
        #pragma unroll
        for (int e = 0; e < 4; ++e)
            cpre[e] = leaf ? 0.f : (float)csum_in[(size_t)(base + e) * MEM + mg];
        float cn[4], hn[4];
        #pragma unroll
        for (int e = 0; e < 4; ++e){
            float iv = acc[r][0][e] + b0;
            float fv = acc[r][1][e] + b1;
            float gv = acc[r][2][e] + b2;
            float ov = acc[r][3][e] + b3;
            float c  = fsigm(fv) * cpre[e] + fsigm(iv) * ftanh(gv);
            cn[e] = c;
            hn[e] = fsigm(ov) * ftanh(c);
        }
        int p0 = base >> 1;
        A_next[(size_t)p0 * KTOT + IN_DIM + mg] = f2bf(hn[0] + hn[1]);
        csum_out[(size_t)p0 * MEM + mg] = (_Float16)(cn[0] + cn[1]);
        A_next[(size_t)(p0 + 1) * KTOT + IN_DIM + mg] = f2bf(hn[2] + hn[3]);
        csum_out[(size_t)(p0 + 1) * MEM + mg] = (_Float16)(cn[2] + cn[3]);
    }
}

// ================= proven 128-row GEMM + LSTM + pair-sum (round-8 schedule; csum f16) =================
#define BM 128
#define KC 64

template<int NK>
__global__ __launch_bounds__(256) void gemm_lstm_kernel(
    const unsigned short* __restrict__ A, int n,
    const unsigned short* __restrict__ Wp, const float* __restrict__ bp,
    const _Float16* __restrict__ csum_in, int leaf,
    unsigned short* __restrict__ A_next, _Float16* __restrict__ csum_out)
{
    __shared__ __align__(16) unsigned short As[2][BM * KC];
    __shared__ __align__(16) unsigned short Bs[2][BM * KC];

    const int tid  = threadIdx.x;
    const int lane = tid & 63;
    const int wid  = tid >> 6;
    const int wm   = wid >> 1;
    const int wc   = wid & 1;
    const int row0 = blockIdx.x * BM;
    const int m0   = blockIdx.y * 32;

    const int srow = lane >> 3;
    const int scol = ((lane & 7) ^ srow) * 8;

    const int mg = m0 + wc * 16 + (lane & 15);

    const float b0 = bp[0 * 256 + mg];
    const float b1 = bp[1 * 256 + mg];
    const float b2 = bp[2 * 256 + mg];
    const float b3 = bp[3 * 256 + mg];
    float cpre[4][4];
    if (!leaf){
        #pragma unroll
        for (int r = 0; r < 4; ++r){
            const int base = row0 + wm * 64 + r * 16 + (lane >> 4) * 4;
            #pragma unroll
            for (int e = 0; e < 4; ++e)
                cpre[r][e] = (float)csum_in[(size_t)(base + e) * MEM + mg];
        }
    } else {
        #pragma unroll
        for (int r = 0; r < 4; ++r)
            #pragma unroll
            for (int e = 0; e < 4; ++e) cpre[r][e] = 0.f;
    }

    f32x4 acc[4][4];
    #pragma unroll
    for (int r = 0; r < 4; ++r)
        #pragma unroll
        for (int q = 0; q < 4; ++q)
            acc[r][q] = (f32x4){0.f, 0.f, 0.f, 0.f};

    auto stage = [&](int d, int kk){
        char* asb = (char*)As[d];
        char* bsb = (char*)Bs[d];
        #pragma unroll
        for (int q = 0; q < 4; ++q){
            int t = wid * 4 + q;
            int r = t * 8 + srow;
            gld_lds16(A + (size_t)(row0 + r) * NK + kk + scol, asb + t * 1024);
        }
        #pragma unroll
        for (int q = 0; q < 4; ++q){
            int t = wid * 4 + q;
            int b = t * 8 + srow;
            int grow = (b >> 5) * 256 + m0 + (b & 31);
            gld_lds16(Wp + (size_t)grow * KTOT + kk + scol, bsb + t * 1024);
        }
    };

    constexpr int nIter = NK / KC;
    stage(0, 0);
    int buf = 0;
    #pragma unroll
    for (int it = 0; it < nIter; ++it){
        if (it + 1 < nIter){
            stage(buf ^ 1, (it + 1) * KC);
            asm volatile("s_waitcnt vmcnt(8)" ::: "memory");
        } else {
            asm volatile("s_waitcnt vmcnt(0)" ::: "memory");
        }
        __builtin_amdgcn_s_barrier();
        const unsigned short* Ab = As[buf];
        const unsigned short* Bb = Bs[buf];
        #pragma unroll
        for (int ks = 0; ks < 2; ++ks){
            const int slot = ks * 4 + (lane >> 4);
            const int kb = (slot ^ (lane & 7)) * 8;
            s16x8 a[4], b[4];
            #pragma unroll
            for (int r = 0; r < 4; ++r)
                a[r] = *(const s16x8*)(Ab + (wm * 64 + r * 16 + (lane & 15)) * KC + kb);
            #pragma unroll
            for (int q = 0; q < 4; ++q)
                b[q] = *(const s16x8*)(Bb + (q * 32 + wc * 16 + (lane & 15)) * KC + kb);
            #pragma unroll
            for (int r = 0; r < 4; ++r)
                #pragma unroll
                for (int q = 0; q < 4; ++q)
                    acc[r][q] = __builtin_amdgcn_mfma_f32_16x16x32_bf16(a[r], b[q], acc[r][q], 0, 0, 0);
        }
        __builtin_amdgcn_s_barrier();
        buf ^= 1;
    }

    #pragma unroll
    for (int r = 0; r < 4; ++r){
        const int base = row0 + wm * 64 + r * 16 + (lane >> 4) * 4;
        float cn[4], hn[4];
        #pragma unroll
        for (int e = 0; e < 4; ++e){
            float iv = acc[r][0][e] + b0;
            float fv = acc[r][1][e] + b1;
            float gv = acc[r][2][e] + b2;
            float ov = acc[r][3][e] + b3;
            float c  = fsigm(fv) * cpre[r][e] + fsigm(iv) * ftanh(gv);
            cn[e] = c;
            hn[e] = fsigm(ov) * ftanh(c);
        }
        if (base < n){
            int p0 = base >> 1;
            A_next[(size_t)p0 * KTOT + IN_DIM + mg] = f2bf(hn[0] + hn[1]);
            csum_out[(size_t)p0 * MEM + mg] = (_Float16)(cn[0] + cn[1]);
        }
        if (base + 2 < n){
            int p1 = (base >> 1) + 1;
            A_next[(size_t)p1 * KTOT + IN_DIM + mg] = f2bf(hn[2] + hn[3]);
            csum_out[(size_t)p1 * MEM + mg] = (_Float16)(cn[2] + cn[3]);
        }
    }
}

// ---------------- tail: levels 7..0 + FC fused, 8 blocks, device grid barrier (csum f16)
__global__ __launch_bounds__(256) void tail_kernel(
    const unsigned short* __restrict__ arena,
    const unsigned short* __restrict__ Wp, const float* __restrict__ bp,
    _Float16* cs_in, _Float16* cs_out,
    float* __restrict__ c_root,
    const float* __restrict__ W_fc, const float* __restrict__ b_fc,
    float* __restrict__ out, unsigned* __restrict__ ctr)
{
    __shared__ __align__(16) unsigned short WpL[128 * KTOT];   // 96 KB
    __shared__ __align__(16) unsigned short AL[64 * KTOT];     // 48 KB

    const int tid  = threadIdx.x;
    const int lane = tid & 63;
    const int wid  = tid >> 6;
    const int wm   = wid >> 1;
    const int wc   = wid & 1;
    const int m0   = blockIdx.x * 32;
    const int mg   = m0 + wc * 16 + (lane & 15);

    #pragma unroll
    for (int i = 0; i < 24; ++i){
        int p0 = wid * 1536 + i * 64;
        int p  = p0 + lane;
        int lrow  = p / 48;
        int pslot = p % 48;
        int lslot = pslot ^ (lrow & 7);
        int grow  = (lrow >> 5) * 256 + m0 + (lrow & 31);
        gld_lds16(Wp + (size_t)grow * KTOT + lslot * 8, (char*)WpL + (size_t)p0 * 16);
    }

    const float b0 = bp[0 * 256 + mg];
    const float b1 = bp[1 * 256 + mg];
    const float b2 = bp[2 * 256 + mg];
    const float b3 = bp[3 * 256 + mg];

    asm volatile("s_waitcnt vmcnt(0)" ::: "memory");
    __builtin_amdgcn_s_barrier();

    unsigned gen = 0;
    for (int l = 7; l >= 0; --l){
        const int n = 1 << l;
        const unsigned short* Al = arena + offA(l);
        const int nhalf = (n > 64) ? (n >> 6) : 1;

        for (int h = 0; h < nhalf; ++h){
            const int r0 = h * 64;
            const int rows = (n < 64) ? n : 64;

            const int nslots = rows * 48;
            for (int t = 0; t * 256 < nslots; ++t){
                int pbase = t * 256 + wid * 64;
                int p = pbase + lane;
                if (p < nslots){
                    int row   = p / 48;
                    int pslot = p - row * 48;
                    int lslot = pslot ^ (row & 7);
                    gld_lds16(Al + (size_t)(r0 + row) * KTOT + lslot * 8,
                              (char*)AL + (size_t)pbase * 16);
                }
            }

            float cpre[2][4];
            #pragma unroll
            for (int r = 0; r < 2; ++r){
                const int base = r0 + wm * 32 + r * 16 + (lane >> 4) * 4;
                #pragma unroll
                for (int e = 0; e < 4; ++e)
                    cpre[r][e] = (float)cs_in[(size_t)(base + e) * MEM + mg];
            }

            asm volatile("s_waitcnt vmcnt(0)" ::: "memory");
            __builtin_amdgcn_s_barrier();

            f32x4 acc[2][4];
            #pragma unroll
            for (int r = 0; r < 2; ++r)
                #pragma unroll
                for (int q = 0; q < 4; ++q)
                    acc[r][q] = (f32x4){0.f, 0.f, 0.f, 0.f};

            #pragma unroll
            for (int kc = 0; kc < 12; ++kc){
                const int ls = kc * 4 + (lane >> 4);
                const int kb = (ls ^ (lane & 7)) * 8;
                s16x8 a[2], b[4];
                #pragma unroll
                for (int r = 0; r < 2; ++r)
                    a[r] = *(const s16x8*)(AL + (size_t)(wm * 32 + r * 16 + (lane & 15)) * KTOT + kb);
                #pragma unroll
                for (int q = 0; q < 4; ++q)
                    b[q] = *(const s16x8*)(WpL + (q * 32 + wc * 16 + (lane & 15)) * KTOT + kb);
                #pragma unroll
                for (int r = 0; r < 2; ++r)
                    #pragma unroll
                    for (int q = 0; q < 4; ++q)
                        acc[r][q] = __builtin_amdgcn_mfma_f32_16x16x32_bf16(a[r], b[q], acc[r][q], 0, 0, 0);
            }

            #pragma unroll
            for (int r = 0; r < 2; ++r){
                const int base = r0 + wm * 32 + r * 16 + (lane >> 4) * 4;
                float cn[4], hn[4];
                #pragma unroll
                for (int e = 0; e < 4; ++e){
                    float iv = acc[r][0][e] + b0;
                    float fv = acc[r][1][e] + b1;
                    float gv = acc[r][2][e] + b2;
                    float ov = acc[r][3][e] + b3;
                    float c  = fsigm(fv) * cpre[r][e] + fsigm(iv) * ftanh(gv);
                    cn[e] = c;
                    hn[e] = fsigm(ov) * ftanh(c);
                }
                if (l == 0){
                    if (base == 0) c_root[mg] = cn[0];
                } else {
                    unsigned short* A_next = (unsigned short*)arena + offA(l - 1);
                    if (base < n){
                        int p0 = base >> 1;
                        A_next[(size_t)p0 * KTOT + IN_DIM + mg] = f2bf(hn[0] + hn[1]);
                        cs_out[(size_t)p0 * MEM + mg] = (_Float16)(cn[0] + cn[1]);
                    }
                    if (base + 2 < n){
                        int p1 = (base >> 1) + 1;
                        A_next[(size_t)p1 * KTOT + IN_DIM + mg] = f2bf(hn[2] + hn[3]);
                        cs_out[(size_t)p1 * MEM + mg] = (_Float16)(cn[2] + cn[3]);
                    }
                }
            }
            __builtin_amdgcn_s_barrier();
        }

        _Float16* t = cs_in; cs_in = cs_out; cs_out = t;
        ++gen;
        grid_barrier(ctr, (unsigned)(NBLK_TAIL * gen));
    }

    if (blockIdx.x == 0){
        int w = wid;
        for (int cls = w * 3; cls < w * 3 + 3; ++cls){
            float s = 0.f;
            for (int m = lane; m < 256; m += 64)
                s += c_root[m] * W_fc[cls * 256 + m];
            #pragma unroll
            for (int off = 32; off; off >>= 1)
                s += __shfl_down(s, off, 64);
            if (lane == 0) out[cls] = s + b_fc[cls];
        }
    }
}

extern "C" void kernel_launch(void* const* d_in, const int* in_sizes, int n_in,
                              void* d_out, int out_size, void* d_ws, size_t ws_size,
                              hipStream_t stream)
{
    const float* x    = (const float*)d_in[0];
    const float* W_ih = (const float*)d_in[1];
    const float* b_ih = (const float*)d_in[2];
    const float* W_hh = (const float*)d_in[3];
    const float* b_hh = (const float*)d_in[4];
    const float* W_fc = (const float*)d_in[5];
    const float* b_fc = (const float*)d_in[6];
    float* out = (float*)d_out;

    const size_t OFF_WP = 0;
    const size_t OFF_BP = 786432;
    const size_t OFF_A  = 790528;
    const size_t OFF_CS0 = OFF_A + (size_t)(ARENA_ELEMS + ARENA_PAD) * 2;
    const size_t OFF_CS1 = OFF_CS0 + 16777216;          // csum now f16: 65536*256*2 /2 rows... 32768*256*2 = 16.7MB
    const size_t OFF_CR  = OFF_CS1 + 16777216;
    const size_t OFF_CTR = OFF_CR + 1024;
    const size_t NEEDED  = OFF_CTR + 64;
    if (ws_size < NEEDED) return;

    char* ws = (char*)d_ws;
    unsigned short* Wp    = (unsigned short*)(ws + OFF_WP);
    float* bp             = (float*)(ws + OFF_BP);
    unsigned short* arena = (unsigned short*)(ws + OFF_A);
    _Float16* cs0         = (_Float16*)(ws + OFF_CS0);
    _Float16* cs1         = (_Float16*)(ws + OFF_CS1);
    float* c_root         = (float*)(ws + OFF_CR);
    unsigned* ctr         = (unsigned*)(ws + OFF_CTR);

    pack_kernel<<<dim3(2048), dim3(256), 0, stream>>>(
        x, W_ih, b_ih, W_hh, b_hh, Wp, bp, arena, ctr);

    // ---- leaf (l=16): n=65536, K=128 -> A(15), cs0 (8-phase kernel, nkt=2 full prefetch)
    gemm_lstm8p_kernel<IN_DIM><<<dim3(NLEAF / 256, 4), dim3(512), 0, stream>>>(
        arena + offA(16), NLEAF, Wp, bp,
        nullptr, 1, arena + offA(15), cs0);

    // ---- l=15, l=14: 8-phase 256-row kernel
    gemm_lstm8p_kernel<KTOT><<<dim3(128, 4), dim3(512), 0, stream>>>(
        arena + offA(15), 32768, Wp, bp, cs0, 0, arena + offA(14), cs1);
    gemm_lstm8p_kernel<KTOT><<<dim3(64, 4), dim3(512), 0, stream>>>(
        arena + offA(14), 16384, Wp, bp, cs1, 0, arena + offA(13), cs0);

    // ---- l=13..8: proven 128-kernel
    _Float16* cs_in = cs0; _Float16* cs_out = cs1;
    for (int l = 13; l >= 8; --l){
        int n = 1 << l;
        gemm_lstm_kernel<KTOT><<<dim3(n / BM, 8), dim3(256), 0, stream>>>(
            arena + offA(l), n, Wp, bp,
            cs_in, 0, arena + offA(l - 1), cs_out);
        _Float16* t = cs_in; cs_in = cs_out; cs_out = t;
    }

    // ---- tail: levels 7..0 + FC (8 co-resident blocks + grid barrier)
    tail_kernel<<<dim3(NBLK_TAIL), dim3(256), 0, stream>>>(
        arena, Wp, bp, cs_in, cs_out, c_root, W_fc, b_fc, out, ctr);
}

// Round 14
// 213.076 us; speedup vs baseline: 1.1112x; 1.1112x over previous
//
#include <hip/hip_runtime.h>
#include <hip/hip_bf16.h>
#include <cstddef>

#define IN_DIM 128
#define MEM 256
#define KTOT 384
#define NLEAF 65536
#define NBLK_TAIL 8

typedef float f32x4 __attribute__((ext_vector_type(4)));
typedef short s16x8 __attribute__((ext_vector_type(8)));
typedef unsigned int u32;

__device__ inline unsigned short f2bf(float f){
    unsigned int u = __builtin_bit_cast(unsigned int, f);
    u += 0x7fff + ((u >> 16) & 1);
    return (unsigned short)(u >> 16);
}

__device__ inline void gld_lds16(const void* g, void* l){
    __builtin_amdgcn_global_load_lds((const __attribute__((address_space(1))) u32*)g,
                                     (__attribute__((address_space(3))) u32*)l, 16, 0, 0);
}

__device__ inline float fsigm(float x){
    return __builtin_amdgcn_rcpf(1.f + __expf(-x));
}
__device__ inline float ftanh(float x){
    return 2.f * __builtin_amdgcn_rcpf(1.f + __expf(-2.f * x)) - 1.f;
}

// A-arena element offsets: leaf (l=16) at 0, stride 128; levels 15..0 stride 384.
__host__ __device__ inline size_t offA(int l){
    if (l == 16) return 0;
    return 8388608u + 384u * (65536u - (1u << (l + 1)));
}
#define ARENA_ELEMS 33554048u
#define ARENA_PAD   65536u

// device-scope grid barrier (8 co-resident blocks). RELAXED polls (round-10 lesson).
__device__ inline void grid_barrier(unsigned* ctr, unsigned target){
    __syncthreads();
    if (threadIdx.x == 0){
        __threadfence();
        __hip_atomic_fetch_add(ctr, 1u, __ATOMIC_RELEASE, __HIP_MEMORY_SCOPE_AGENT);
        while (__hip_atomic_load(ctr, __ATOMIC_RELAXED, __HIP_MEMORY_SCOPE_AGENT) < target)
            __builtin_amdgcn_s_sleep(2);
    }
    __syncthreads();
    __threadfence();
}

// ---------------- fused pack: W (+bias, +ctr reset) and all x rows -> bf16 arena
__global__ void pack_kernel(const float* __restrict__ x,
                            const float* __restrict__ W_ih, const float* __restrict__ b_ih,
                            const float* __restrict__ W_hh, const float* __restrict__ b_hh,
                            unsigned short* __restrict__ Wp, float* __restrict__ bp,
                            unsigned short* __restrict__ Aarena, unsigned* __restrict__ ctr){
    const int stride = gridDim.x * blockDim.x;
    const int tid0 = blockIdx.x * blockDim.x + threadIdx.x;
    if (tid0 == 0){ ctr[0] = 0; }

    for (int g = tid0; g < 1024 * 48; g += stride){
        int row = g / 48, ko = (g - row * 48) * 8;
        const float* s = (ko < IN_DIM) ? (W_ih + (size_t)row * IN_DIM + ko)
                                       : (W_hh + (size_t)row * MEM + (ko - IN_DIM));
        f32x4 v0 = *(const f32x4*)s, v1 = *(const f32x4*)(s + 4);
        s16x8 o;
        #pragma unroll
        for (int e = 0; e < 4; ++e){ o[e] = (short)f2bf(v0[e]); o[4+e] = (short)f2bf(v1[e]); }
        *(s16x8*)(Wp + (size_t)row * KTOT + ko) = o;
        if (ko == 0) bp[row] = b_ih[row] + b_hh[row];
    }

    const int TOTAL_G = 131071 * 16;
    for (int g = tid0; g < TOTAL_G; g += stride){
        int i  = g >> 4;
        int ko = (g & 15) * 8;
        int l  = 31 - __clz(i + 1);
        int j  = i + 1 - (1 << l);
        size_t dst = offA(l) + (size_t)j * ((l == 16) ? 128 : 384) + ko;
        const f32x4* s = (const f32x4*)(x + (size_t)i * IN_DIM + ko);
        f32x4 v0 = s[0], v1 = s[1];
        s16x8 o;
        #pragma unroll
        for (int e = 0; e < 4; ++e){ o[e] = (short)f2bf(v0[e]); o[4+e] = (short)f2bf(v1[e]); }
        *(s16x8*)(Aarena + dst) = o;
    }
}

// ================= 8-phase-style 256-row GEMM + LSTM + pair-sum (l15, l14) =================
// Block: 256 rows x 64 mem cols (256 gate cols). 512 threads, 8 waves (wm 2 x wn 4).
// Wave: 128 rows x 64 gate cols -> acc[8][4]; per-lane all 4 gates of col mg.
// Half-tile staging (A0/A1/B0/B1 = 16 KB each), 2-dbuf (128 KB LDS), counted vmcnt(4),
// 4 compute phases (quadrants) per K-tile, 2 sync points/K-tile, setprio around MFMA.
template<int NK>
__global__ __launch_bounds__(512, 1) void gemm_lstm8p_kernel(
    const unsigned short* __restrict__ A, int n,
    const unsigned short* __restrict__ Wp, const float* __restrict__ bp,
    const float* __restrict__ csum_in,
    unsigned short* __restrict__ A_next, float* __restrict__ csum_out)
{
    __shared__ __align__(16) unsigned short As[2][2][128 * 64];   // [buf][half] 64 KB
    __shared__ __align__(16) unsigned short Bs[2][2][128 * 64];   // 64 KB

    const int tid  = threadIdx.x;
    const int lane = tid & 63;
    const int wid  = tid >> 6;        // 0..7
    const int wm   = wid >> 2;        // A row-half (128 rows)
    const int wn   = wid & 3;         // mem 16-col group
    const int row0 = blockIdx.x * 256;
    const int m0   = blockIdx.y * 64;
    const int mg   = m0 + wn * 16 + (lane & 15);

    auto stageA = [&](int kt, int h){
        #pragma unroll
        for (int i = 0; i < 2; ++i){
            int p  = i * 512 + tid;
            int r  = p >> 3;                       // 0..127 within half
            int ls = (p & 7) ^ (r & 7);            // pre-swizzled source slot
            gld_lds16(A + (size_t)(row0 + h * 128 + r) * NK + kt * 64 + ls * 8,
                      (char*)As[kt & 1][h] + (size_t)(i * 512 + wid * 64) * 16);
        }
    };
    auto stageB = [&](int kt, int h){
        #pragma unroll
        for (int i = 0; i < 2; ++i){
            int p  = i * 512 + tid;
            int r  = p >> 3;
            int b  = h * 128 + r;                  // B tile row 0..255
            int grow = (b >> 6) * 256 + m0 + (b & 63);
            int ls = (p & 7) ^ (r & 7);            // b&7 == r&7
            gld_lds16(Wp + (size_t)grow * KTOT + kt * 64 + ls * 8,
                      (char*)Bs[kt & 1][h] + (size_t)(i * 512 + wid * 64) * 16);
        }
    };

    f32x4 acc[8][4];
    #pragma unroll
    for (int r = 0; r < 8; ++r)
        #pragma unroll
        for (int q = 0; q < 4; ++q)
            acc[r][q] = (f32x4){0.f, 0.f, 0.f, 0.f};

    constexpr int nkt = NK / 64;
    // prologue: A0(0), A1(0), B0(0), B0(1), B1(0)
    stageA(0, 0); stageA(0, 1); stageB(0, 0);
    if (nkt > 1) stageB(1, 0);
    stageB(0, 1);

    s16x8 bfr[2][2];   // B frags, reused across rh phases

    #pragma unroll
    for (int t = 0; t < nkt; ++t){
        const unsigned short* Ab = As[t & 1][wm];
        const unsigned short* Bb0 = Bs[t & 1][0];
        const unsigned short* Bb1 = Bs[t & 1][1];

        // ---- SYNC-1: A0(t),A1(t),B0(t) landed (allow B0(t+1),B1(t) in flight)
        if (t + 1 < nkt) { asm volatile("s_waitcnt vmcnt(4)" ::: "memory"); }
        else             { asm volatile("s_waitcnt vmcnt(2)" ::: "memory"); }
        __builtin_amdgcn_s_barrier();
        asm volatile("" ::: "memory");

        #pragma unroll
        for (int rh = 0; rh < 2; ++rh){
            s16x8 a[4][2];
            #pragma unroll
            for (int j = 0; j < 4; ++j)
                #pragma unroll
                for (int ks = 0; ks < 2; ++ks){
                    int kb = (((ks * 4 + (lane >> 4)) ^ (lane & 7))) * 8;
                    a[j][ks] = *(const s16x8*)(Ab + (size_t)(rh * 64 + j * 16 + (lane & 15)) * 64 + kb);
                }
            if (rh == 0){
                #pragma unroll
                for (int q2 = 0; q2 < 2; ++q2)
                    #pragma unroll
                    for (int ks = 0; ks < 2; ++ks){
                        int kb = (((ks * 4 + (lane >> 4)) ^ (lane & 7))) * 8;
                        bfr[q2][ks] = *(const s16x8*)(Bb0 + (size_t)(q2 * 64 + wn * 16 + (lane & 15)) * 64 + kb);
                    }
                if (t + 1 < nkt) stageA(t + 1, 0);
            } else {
                if (t + 1 < nkt) stageA(t + 1, 1);
            }
            __builtin_amdgcn_s_setprio(1);
            #pragma unroll
            for (int j = 0; j < 4; ++j)
                #pragma unroll
                for (int q2 = 0; q2 < 2; ++q2)
                    #pragma unroll
                    for (int ks = 0; ks < 2; ++ks)
                        acc[rh * 4 + j][q2] = __builtin_amdgcn_mfma_f32_16x16x32_bf16(
                            a[j][ks], bfr[q2][ks], acc[rh * 4 + j][q2], 0, 0, 0);
            __builtin_amdgcn_s_setprio(0);
        }

        // ---- SYNC-2: B1(t) landed (allow A0(t+1),A1(t+1) in flight); also B0(t) WAR done
        if (t + 1 < nkt) { asm volatile("s_waitcnt vmcnt(4)" ::: "memory"); }
        else             { asm volatile("s_waitcnt vmcnt(0)" ::: "memory"); }
        __builtin_amdgcn_s_barrier();
        asm volatile("" ::: "memory");

        #pragma unroll
        for (int rh = 0; rh < 2; ++rh){
            s16x8 a[4][2];
            #pragma unroll
            for (int j = 0; j < 4; ++j)
                #pragma unroll
                for (int ks = 0; ks < 2; ++ks){
                    int kb = (((ks * 4 + (lane >> 4)) ^ (lane & 7))) * 8;
                    a[j][ks] = *(const s16x8*)(Ab + (size_t)(rh * 64 + j * 16 + (lane & 15)) * 64 + kb);
                }
            if (rh == 0){
                #pragma unroll
                for (int q2 = 0; q2 < 2; ++q2)
                    #pragma unroll
                    for (int ks = 0; ks < 2; ++ks){
                        int kb = (((ks * 4 + (lane >> 4)) ^ (lane & 7))) * 8;
                        bfr[q2][ks] = *(const s16x8*)(Bb1 + (size_t)(q2 * 64 + wn * 16 + (lane & 15)) * 64 + kb);
                    }
                if (t + 2 < nkt) stageB(t + 2, 0);
            } else {
                if (t + 1 < nkt) stageB(t + 1, 1);
            }
            __builtin_amdgcn_s_setprio(1);
            #pragma unroll
            for (int j = 0; j < 4; ++j)
                #pragma unroll
                for (int q2 = 0; q2 < 2; ++q2)
                    #pragma unroll
                    for (int ks = 0; ks < 2; ++ks)
                        acc[rh * 4 + j][2 + q2] = __builtin_amdgcn_mfma_f32_16x16x32_bf16(
                            a[j][ks], bfr[q2][ks], acc[rh * 4 + j][2 + q2], 0, 0, 0);
            __builtin_amdgcn_s_setprio(0);
        }
        __builtin_amdgcn_s_barrier();   // close K-tile: protect A(t) before A(t+2) restage
        asm volatile("" ::: "memory");
    }

    // -------- epilogue: lane owns 32 rows x col mg, all 4 gates in acc[r][q]
    const float b0 = bp[0 * 256 + mg];
    const float b1 = bp[1 * 256 + mg];
    const float b2 = bp[2 * 256 + mg];
    const float b3 = bp[3 * 256 + mg];
    #pragma unroll
    for (int r = 0; r < 8; ++r){
        const int base = row0 + wm * 128 + r * 16 + (lane >> 4) * 4;
        float cpre[4];
        #pragma unroll
        for (int e = 0; e < 4; ++e)
            cpre[e] = csum_in[(size_t)(base + e) * MEM + mg];
        float cn[4], hn[4];
        #pragma unroll
        for (int e = 0; e < 4; ++e){
            float iv = acc[r][0][e] + b0;
            float fv = acc[r][1][e] + b1;
            float gv = acc[r][2][e] + b2;
            float ov = acc[r][3][e] + b3;
            float c  = fsigm(fv) * cpre[e] + fsigm(iv) * ftanh(gv);
            cn[e] = c;
            hn[e] = fsigm(ov) * ftanh(c);
        }
        int p0 = base >> 1;
        A_next[(size_t)p0 * KTOT + IN_DIM + mg] = f2bf(hn[0] + hn[1]);
        csum_out[(size_t)p0 * MEM + mg] = cn[0] + cn[1];
        A_next[(size_t)(p0 + 1) * KTOT + IN_DIM + mg] = f2bf(hn[2] + hn[3]);
        csum_out[(size_t)(p0 + 1) * MEM + mg] = cn[2] + cn[3];
    }
}

// ================= proven 128-row GEMM + LSTM + pair-sum (round-8 schedule, verbatim) =================
#define BM 128
#define KC 64

template<int NK>
__global__ __launch_bounds__(256) void gemm_lstm_kernel(
    const unsigned short* __restrict__ A, int n,
    const unsigned short* __restrict__ Wp, const float* __restrict__ bp,
    const float* __restrict__ csum_in, int leaf,
    unsigned short* __restrict__ A_next, float* __restrict__ csum_out)
{
    __shared__ __align__(16) unsigned short As[2][BM * KC];
    __shared__ __align__(16) unsigned short Bs[2][BM * KC];

    const int tid  = threadIdx.x;
    const int lane = tid & 63;
    const int wid  = tid >> 6;
    const int wm   = wid >> 1;
    const int wc   = wid & 1;
    const int row0 = blockIdx.x * BM;
    const int m0   = blockIdx.y * 32;

    const int srow = lane >> 3;
    const int scol = ((lane & 7) ^ srow) * 8;

    const int mg = m0 + wc * 16 + (lane & 15);

    const float b0 = bp[0 * 256 + mg];
    const float b1 = bp[1 * 256 + mg];
    const float b2 = bp[2 * 256 + mg];
    const float b3 = bp[3 * 256 + mg];
    float cpre[4][4];
    if (!leaf){
        #pragma unroll
        for (int r = 0; r < 4; ++r){
            const int base = row0 + wm * 64 + r * 16 + (lane >> 4) * 4;
            #pragma unroll
            for (int e = 0; e < 4; ++e)
                cpre[r][e] = csum_in[(size_t)(base + e) * MEM + mg];
        }
    } else {
        #pragma unroll
        for (int r = 0; r < 4; ++r)
            #pragma unroll
            for (int e = 0; e < 4; ++e) cpre[r][e] = 0.f;
    }

    f32x4 acc[4][4];
    #pragma unroll
    for (int r = 0; r < 4; ++r)
        #pragma unroll
        for (int q = 0; q < 4; ++q)
            acc[r][q] = (f32x4){0.f, 0.f, 0.f, 0.f};

    auto stage = [&](int d, int kk){
        char* asb = (char*)As[d];
        char* bsb = (char*)Bs[d];
        #pragma unroll
        for (int q = 0; q < 4; ++q){
            int t = wid * 4 + q;
            int r = t * 8 + srow;
            gld_lds16(A + (size_t)(row0 + r) * NK + kk + scol, asb + t * 1024);
        }
        #pragma unroll
        for (int q = 0; q < 4; ++q){
            int t = wid * 4 + q;
            int b = t * 8 + srow;
            int grow = (b >> 5) * 256 + m0 + (b & 31);
            gld_lds16(Wp + (size_t)grow * KTOT + kk + scol, bsb + t * 1024);
        }
    };

    constexpr int nIter = NK / KC;
    stage(0, 0);
    int buf = 0;
    #pragma unroll
    for (int it = 0; it < nIter; ++it){
        if (it + 1 < nIter){
            stage(buf ^ 1, (it + 1) * KC);
            asm volatile("s_waitcnt vmcnt(8)" ::: "memory");
        } else {
            asm volatile("s_waitcnt vmcnt(0)" ::: "memory");
        }
        __builtin_amdgcn_s_barrier();
        const unsigned short* Ab = As[buf];
        const unsigned short* Bb = Bs[buf];
        #pragma unroll
        for (int ks = 0; ks < 2; ++ks){
            const int slot = ks * 4 + (lane >> 4);
            const int kb = (slot ^ (lane & 7)) * 8;
            s16x8 a[4], b[4];
            #pragma unroll
            for (int r = 0; r < 4; ++r)
                a[r] = *(const s16x8*)(Ab + (wm * 64 + r * 16 + (lane & 15)) * KC + kb);
            #pragma unroll
            for (int q = 0; q < 4; ++q)
                b[q] = *(const s16x8*)(Bb + (q * 32 + wc * 16 + (lane & 15)) * KC + kb);
            #pragma unroll
            for (int r = 0; r < 4; ++r)
                #pragma unroll
                for (int q = 0; q < 4; ++q)
                    acc[r][q] = __builtin_amdgcn_mfma_f32_16x16x32_bf16(a[r], b[q], acc[r][q], 0, 0, 0);
        }
        __builtin_amdgcn_s_barrier();
        buf ^= 1;
    }

    #pragma unroll
    for (int r = 0; r < 4; ++r){
        const int base = row0 + wm * 64 + r * 16 + (lane >> 4) * 4;
        float cn[4], hn[4];
        #pragma unroll
        for (int e = 0; e < 4; ++e){
            float iv = acc[r][0][e] + b0;
            float fv = acc[r][1][e] + b1;
            float gv = acc[r][2][e] + b2;
            float ov = acc[r][3][e] + b3;
            float c  = fsigm(fv) * cpre[r][e] + fsigm(iv) * ftanh(gv);
            cn[e] = c;
            hn[e] = fsigm(ov) * ftanh(c);
        }
        if (base < n){
            int p0 = base >> 1;
            A_next[(size_t)p0 * KTOT + IN_DIM + mg] = f2bf(hn[0] + hn[1]);
            csum_out[(size_t)p0 * MEM + mg] = cn[0] + cn[1];
        }
        if (base + 2 < n){
            int p1 = (base >> 1) + 1;
            A_next[(size_t)p1 * KTOT + IN_DIM + mg] = f2bf(hn[2] + hn[3]);
            csum_out[(size_t)p1 * MEM + mg] = cn[2] + cn[3];
        }
    }
}

// ---------------- tail: levels 7..0 + FC fused, 8 blocks, device grid barrier (verbatim r11)
__global__ __launch_bounds__(256) void tail_kernel(
    const unsigned short* __restrict__ arena,
    const unsigned short* __restrict__ Wp, const float* __restrict__ bp,
    float* cs_in, float* cs_out,
    float* __restrict__ c_root,
    const float* __restrict__ W_fc, const float* __restrict__ b_fc,
    float* __restrict__ out, unsigned* __restrict__ ctr)
{
    __shared__ __align__(16) unsigned short WpL[128 * KTOT];   // 96 KB
    __shared__ __align__(16) unsigned short AL[64 * KTOT];     // 48 KB

    const int tid  = threadIdx.x;
    const int lane = tid & 63;
    const int wid  = tid >> 6;
    const int wm   = wid >> 1;
    const int wc   = wid & 1;
    const int m0   = blockIdx.x * 32;
    const int mg   = m0 + wc * 16 + (lane & 15);

    #pragma unroll
    for (int i = 0; i < 24; ++i){
        int p0 = wid * 1536 + i * 64;
        int p  = p0 + lane;
        int lrow  = p / 48;
        int pslot = p % 48;
        int lslot = pslot ^ (lrow & 7);
        int grow  = (lrow >> 5) * 256 + m0 + (lrow & 31);
        gld_lds16(Wp + (size_t)grow * KTOT + lslot * 8, (char*)WpL + (size_t)p0 * 16);
    }

    const float b0 = bp[0 * 256 + mg];
    const float b1 = bp[1 * 256 + mg];
    const float b2 = bp[2 * 256 + mg];
    const float b3 = bp[3 * 256 + mg];

    asm volatile("s_waitcnt vmcnt(0)" ::: "memory");
    __builtin_amdgcn_s_barrier();

    unsigned gen = 0;
    for (int l = 7; l >= 0; --l){
        const int n = 1 << l;
        const unsigned short* Al = arena + offA(l);
        const int nhalf = (n > 64) ? (n >> 6) : 1;

        for (int h = 0; h < nhalf; ++h){
            const int r0 = h * 64;
            const int rows = (n < 64) ? n : 64;

            const int nslots = rows * 48;
            for (int t = 0; t * 256 < nslots; ++t){
                int pbase = t * 256 + wid * 64;
                int p = pbase + lane;
                if (p < nslots){
                    int row   = p / 48;
                    int pslot = p - row * 48;
                    int lslot = pslot ^ (row & 7);
                    gld_lds16(Al + (size_t)(r0 + row) * KTOT + lslot * 8,
                              (char*)AL + (size_t)pbase * 16);
                }
            }

            float cpre[2][4];
            #pragma unroll
            for (int r = 0; r < 2; ++r){
                const int base = r0 + wm * 32 + r * 16 + (lane >> 4) * 4;
                #pragma unroll
                for (int e = 0; e < 4; ++e)
                    cpre[r][e] = cs_in[(size_t)(base + e) * MEM + mg];
            }

            asm volatile("s_waitcnt vmcnt(0)" ::: "memory");
            __builtin_amdgcn_s_barrier();

            f32x4 acc[2][4];
            #pragma unroll
            for (int r = 0; r < 2; ++r)
                #pragma unroll
                for (int q = 0; q < 4; ++q)
                    acc[r][q] = (f32x4){0.f, 0.f, 0.f, 0.f};

            #pragma unroll
            for (int kc = 0; kc < 12; ++kc){
                const int ls = kc * 4 + (lane >> 4);
                const int kb = (ls ^ (lane & 7)) * 8;
                s16x8 a[2], b[4];
                #pragma unroll
                for (int r = 0; r < 2; ++r)
                    a[r] = *(const s16x8*)(AL + (size_t)(wm * 32 + r * 16 + (lane & 15)) * KTOT + kb);
                #pragma unroll
                for (int q = 0; q < 4; ++q)
                    b[q] = *(const s16x8*)(WpL + (q * 32 + wc * 16 + (lane & 15)) * KTOT + kb);
                #pragma unroll
                for (int r = 0; r < 2; ++r)
                    #pragma unroll
                    for (int q = 0; q < 4; ++q)
                        acc[r][q] = __builtin_amdgcn_mfma_f32_16x16x32_bf16(a[r], b[q], acc[r][q], 0, 0, 0);
            }

            #pragma unroll
            for (int r = 0; r < 2; ++r){
                const int base = r0 + wm * 32 + r * 16 + (lane >> 4) * 4;
                float cn[4], hn[4];
                #pragma unroll
                for (int e = 0; e < 4; ++e){
                    float iv = acc[r][0][e] + b0;
                    float fv = acc[r][1][e] + b1;
                    float gv = acc[r][2][e] + b2;
                    float ov = acc[r][3][e] + b3;
                    float c  = fsigm(fv) * cpre[r][e] + fsigm(iv) * ftanh(gv);
                    cn[e] = c;
                    hn[e] = fsigm(ov) * ftanh(c);
                }
                if (l == 0){
                    if (base == 0) c_root[mg] = cn[0];
                } else {
                    unsigned short* A_next = (unsigned short*)arena + offA(l - 1);
                    if (base < n){
                        int p0 = base >> 1;
                        A_next[(size_t)p0 * KTOT + IN_DIM + mg] = f2bf(hn[0] + hn[1]);
                        cs_out[(size_t)p0 * MEM + mg] = cn[0] + cn[1];
                    }
                    if (base + 2 < n){
                        int p1 = (base >> 1) + 1;
                        A_next[(size_t)p1 * KTOT + IN_DIM + mg] = f2bf(hn[2] + hn[3]);
                        cs_out[(size_t)p1 * MEM + mg] = cn[2] + cn[3];
                    }
                }
            }
            __builtin_amdgcn_s_barrier();
        }

        float* t = cs_in; cs_in = cs_out; cs_out = t;
        ++gen;
        grid_barrier(ctr, (unsigned)(NBLK_TAIL * gen));
    }

    if (blockIdx.x == 0){
        int w = wid;
        for (int cls = w * 3; cls < w * 3 + 3; ++cls){
            float s = 0.f;
            for (int m = lane; m < 256; m += 64)
                s += c_root[m] * W_fc[cls * 256 + m];
            #pragma unroll
            for (int off = 32; off; off >>= 1)
                s += __shfl_down(s, off, 64);
            if (lane == 0) out[cls] = s + b_fc[cls];
        }
    }
}

extern "C" void kernel_launch(void* const* d_in, const int* in_sizes, int n_in,
                              void* d_out, int out_size, void* d_ws, size_t ws_size,
                              hipStream_t stream)
{
    const float* x    = (const float*)d_in[0];
    const float* W_ih = (const float*)d_in[1];
    const float* b_ih = (const float*)d_in[2];
    const float* W_hh = (const float*)d_in[3];
    const float* b_hh = (const float*)d_in[4];
    const float* W_fc = (const float*)d_in[5];
    const float* b_fc = (const float*)d_in[6];
    float* out = (float*)d_out;

    const size_t OFF_WP = 0;
    const size_t OFF_BP = 786432;
    const size_t OFF_A  = 790528;
    const size_t OFF_CS0 = OFF_A + (size_t)(ARENA_ELEMS + ARENA_PAD) * 2;
    const size_t OFF_CS1 = OFF_CS0 + 33554432;
    const size_t OFF_CR  = OFF_CS1 + 33554432;
    const size_t OFF_CTR = OFF_CR + 1024;
    const size_t NEEDED  = OFF_CTR + 64;
    if (ws_size < NEEDED) return;

    char* ws = (char*)d_ws;
    unsigned short* Wp    = (unsigned short*)(ws + OFF_WP);
    float* bp             = (float*)(ws + OFF_BP);
    unsigned short* arena = (unsigned short*)(ws + OFF_A);
    float* cs0            = (float*)(ws + OFF_CS0);
    float* cs1            = (float*)(ws + OFF_CS1);
    float* c_root         = (float*)(ws + OFF_CR);
    unsigned* ctr         = (unsigned*)(ws + OFF_CTR);

    pack_kernel<<<dim3(2048), dim3(256), 0, stream>>>(
        x, W_ih, b_ih, W_hh, b_hh, Wp, bp, arena, ctr);

    // ---- leaf (l=16): n=65536, K=128 -> A(15), cs0 (proven 128-kernel)
    gemm_lstm_kernel<IN_DIM><<<dim3(NLEAF / BM, 8), dim3(256), 0, stream>>>(
        arena + offA(16), NLEAF, Wp, bp,
        nullptr, 1, arena + offA(15), cs0);

    // ---- l=15, l=14: 8-phase 256-row kernel
    gemm_lstm8p_kernel<KTOT><<<dim3(128, 4), dim3(512), 0, stream>>>(
        arena + offA(15), 32768, Wp, bp, cs0, arena + offA(14), cs1);
    gemm_lstm8p_kernel<KTOT><<<dim3(64, 4), dim3(512), 0, stream>>>(
        arena + offA(14), 16384, Wp, bp, cs1, arena + offA(13), cs0);

    // ---- l=13..8: proven 128-kernel
    float* cs_in = cs0; float* cs_out = cs1;
    for (int l = 13; l >= 8; --l){
        int n = 1 << l;
        gemm_lstm_kernel<KTOT><<<dim3(n / BM, 8), dim3(256), 0, stream>>>(
            arena + offA(l), n, Wp, bp,
            cs_in, 0, arena + offA(l - 1), cs_out);
        float* t = cs_in; cs_in = cs_out; cs_out = t;
    }

    // ---- tail: levels 7..0 + FC (8 co-resident blocks + grid barrier)
    tail_kernel<<<dim3(NBLK_TAIL), dim3(256), 0, stream>>>(
        arena, Wp, bp, cs_in, cs_out, c_root, W_fc, b_fc, out, ctr);
}

// Round 15
// 212.296 us; speedup vs baseline: 1.1153x; 1.0037x over previous
//
#include <hip/hip_runtime.h>
#include <hip/hip_bf16.h>
#include <cstddef>

#define IN_DIM 128
#define MEM 256
#define KTOT 384
#define NLEAF 65536
#define NBLK_TAIL 8

typedef float f32x4 __attribute__((ext_vector_type(4)));
typedef short s16x8 __attribute__((ext_vector_type(8)));
typedef unsigned int u32;

__device__ inline unsigned short f2bf(float f){
    unsigned int u = __builtin_bit_cast(unsigned int, f);
    u += 0x7fff + ((u >> 16) & 1);
    return (unsigned short)(u >> 16);
}

__device__ inline void gld_lds16(const void* g, void* l){
    __builtin_amdgcn_global_load_lds((const __attribute__((address_space(1))) u32*)g,
                                     (__attribute__((address_space(3))) u32*)l, 16, 0, 0);
}
// device-coherent (SC0|SC1 = 1|16 = 17): read from coherence point, bypass stale L1/L2
__device__ inline void gld_lds16_dev(const void* g, void* l){
    __builtin_amdgcn_global_load_lds((const __attribute__((address_space(1))) u32*)g,
                                     (__attribute__((address_space(3))) u32*)l, 16, 0, 17);
}
// write-through device-coherent stores (no dirty L2 lines -> cheap release fences)
__device__ inline void st16_dev(unsigned short* p, unsigned short v){
    unsigned int vv = v;
    asm volatile("global_store_short %0, %1, off sc0 sc1" :: "v"(p), "v"(vv) : "memory");
}
__device__ inline void st32_dev(float* p, float v){
    asm volatile("global_store_dword %0, %1, off sc0 sc1" :: "v"(p), "v"(v) : "memory");
}

__device__ inline float fsigm(float x){
    return __builtin_amdgcn_rcpf(1.f + __expf(-x));
}
__device__ inline float ftanh(float x){
    return 2.f * __builtin_amdgcn_rcpf(1.f + __expf(-2.f * x)) - 1.f;
}

// A-arena element offsets: leaf (l=16) at 0, stride 128; levels 15..0 stride 384.
__host__ __device__ inline size_t offA(int l){
    if (l == 16) return 0;
    return 8388608u + 384u * (65536u - (1u << (l + 1)));
}
#define ARENA_ELEMS 33554048u
#define ARENA_PAD   65536u

// device-scope grid barrier (8 co-resident blocks). RELAXED polls (round-10 lesson).
__device__ inline void grid_barrier(unsigned* ctr, unsigned target){
    __syncthreads();
    if (threadIdx.x == 0){
        __threadfence();
        __hip_atomic_fetch_add(ctr, 1u, __ATOMIC_RELEASE, __HIP_MEMORY_SCOPE_AGENT);
        while (__hip_atomic_load(ctr, __ATOMIC_RELAXED, __HIP_MEMORY_SCOPE_AGENT) < target)
            __builtin_amdgcn_s_sleep(2);
    }
    __syncthreads();
    __threadfence();
}

// ---------------- fused pack: W (+bias, +ctr reset) and all x rows -> bf16 arena
__global__ void pack_kernel(const float* __restrict__ x,
                            const float* __restrict__ W_ih, const float* __restrict__ b_ih,
                            const float* __restrict__ W_hh, const float* __restrict__ b_hh,
                            unsigned short* __restrict__ Wp, float* __restrict__ bp,
                            unsigned short* __restrict__ Aarena, unsigned* __restrict__ ctr){
    const int stride = gridDim.x * blockDim.x;
    const int tid0 = blockIdx.x * blockDim.x + threadIdx.x;
    if (tid0 == 0){ ctr[0] = 0; }

    for (int g = tid0; g < 1024 * 48; g += stride){
        int row = g / 48, ko = (g - row * 48) * 8;
        const float* s = (ko < IN_DIM) ? (W_ih + (size_t)row * IN_DIM + ko)
                                       : (W_hh + (size_t)row * MEM + (ko - IN_DIM));
        f32x4 v0 = *(const f32x4*)s, v1 = *(const f32x4*)(s + 4);
        s16x8 o;
        #pragma unroll
        for (int e = 0; e < 4; ++e){ o[e] = (short)f2bf(v0[e]); o[4+e] = (short)f2bf(v1[e]); }
        *(s16x8*)(Wp + (size_t)row * KTOT + ko) = o;
        if (ko == 0) bp[row] = b_ih[row] + b_hh[row];
    }

    const int TOTAL_G = 131071 * 16;
    for (int g = tid0; g < TOTAL_G; g += stride){
        int i  = g >> 4;
        int ko = (g & 15) * 8;
        int l  = 31 - __clz(i + 1);
        int j  = i + 1 - (1 << l);
        size_t dst = offA(l) + (size_t)j * ((l == 16) ? 128 : 384) + ko;
        const f32x4* s = (const f32x4*)(x + (size_t)i * IN_DIM + ko);
        f32x4 v0 = s[0], v1 = s[1];
        s16x8 o;
        #pragma unroll
        for (int e = 0; e < 4; ++e){ o[e] = (short)f2bf(v0[e]); o[4+e] = (short)f2bf(v1[e]); }
        *(s16x8*)(Aarena + dst) = o;
    }
}

// ================= 8-phase-style 256-row GEMM + LSTM + pair-sum (l15, l14) =================
// Block: 256 rows x 64 mem cols (256 gate cols). 512 threads, 8 waves (wm 2 x wn 4).
// Wave: 128 rows x 64 gate cols -> acc[8][4]; per-lane all 4 gates of col mg.
// Half-tile staging (A0/A1/B0/B1 = 16 KB each), 2-dbuf (128 KB LDS), counted vmcnt(4),
// 4 compute phases (quadrants) per K-tile, 2 sync points/K-tile, setprio around MFMA.
template<int NK>
__global__ __launch_bounds__(512, 1) void gemm_lstm8p_kernel(
    const unsigned short* __restrict__ A, int n,
    const unsigned short* __restrict__ Wp, const float* __restrict__ bp,
    const float* __restrict__ csum_in,
    unsigned short* __restrict__ A_next, float* __restrict__ csum_out)
{
    __shared__ __align__(16) unsigned short As[2][2][128 * 64];   // [buf][half] 64 KB
    __shared__ __align__(16) unsigned short Bs[2][2][128 * 64];   // 64 KB

    const int tid  = threadIdx.x;
    const int lane = tid & 63;
    const int wid  = tid >> 6;        // 0..7
    const int wm   = wid >> 2;        // A row-half (128 rows)
    const int wn   = wid & 3;         // mem 16-col group
    const int row0 = blockIdx.x * 256;
    const int m0   = blockIdx.y * 64;
    const int mg   = m0 + wn * 16 + (lane & 15);

    auto stageA = [&](int kt, int h){
        #pragma unroll
        for (int i = 0; i < 2; ++i){
            int p  = i * 512 + tid;
            int r  = p >> 3;                       // 0..127 within half
            int ls = (p & 7) ^ (r & 7);            // pre-swizzled source slot
            gld_lds16(A + (size_t)(row0 + h * 128 + r) * NK + kt * 64 + ls * 8,
                      (char*)As[kt & 1][h] + (size_t)(i * 512 + wid * 64) * 16);
        }
    };
    auto stageB = [&](int kt, int h){
        #pragma unroll
        for (int i = 0; i < 2; ++i){
            int p  = i * 512 + tid;
            int r  = p >> 3;
            int b  = h * 128 + r;                  // B tile row 0..255
            int grow = (b >> 6) * 256 + m0 + (b & 63);
            int ls = (p & 7) ^ (r & 7);            // b&7 == r&7
            gld_lds16(Wp + (size_t)grow * KTOT + kt * 64 + ls * 8,
                      (char*)Bs[kt & 1][h] + (size_t)(i * 512 + wid * 64) * 16);
        }
    };

    f32x4 acc[8][4];
    #pragma unroll
    for (int r = 0; r < 8; ++r)
        #pragma unroll
        for (int q = 0; q < 4; ++q)
            acc[r][q] = (f32x4){0.f, 0.f, 0.f, 0.f};

    constexpr int nkt = NK / 64;
    // prologue: A0(0), A1(0), B0(0), B0(1), B1(0)
    stageA(0, 0); stageA(0, 1); stageB(0, 0);
    if (nkt > 1) stageB(1, 0);
    stageB(0, 1);

    s16x8 bfr[2][2];   // B frags, reused across rh phases

    #pragma unroll
    for (int t = 0; t < nkt; ++t){
        const unsigned short* Ab = As[t & 1][wm];
        const unsigned short* Bb0 = Bs[t & 1][0];
        const unsigned short* Bb1 = Bs[t & 1][1];

        // ---- SYNC-1: A0(t),A1(t),B0(t) landed (allow B0(t+1),B1(t) in flight)
        if (t + 1 < nkt) { asm volatile("s_waitcnt vmcnt(4)" ::: "memory"); }
        else             { asm volatile("s_waitcnt vmcnt(2)" ::: "memory"); }
        __builtin_amdgcn_s_barrier();
        asm volatile("" ::: "memory");

        #pragma unroll
        for (int rh = 0; rh < 2; ++rh){
            s16x8 a[4][2];
            #pragma unroll
            for (int j = 0; j < 4; ++j)
                #pragma unroll
                for (int ks = 0; ks < 2; ++ks){
                    int kb = (((ks * 4 + (lane >> 4)) ^ (lane & 7))) * 8;
                    a[j][ks] = *(const s16x8*)(Ab + (size_t)(rh * 64 + j * 16 + (lane & 15)) * 64 + kb);
                }
            if (rh == 0){
                #pragma unroll
                for (int q2 = 0; q2 < 2; ++q2)
                    #pragma unroll
                    for (int ks = 0; ks < 2; ++ks){
                        int kb = (((ks * 4 + (lane >> 4)) ^ (lane & 7))) * 8;
                        bfr[q2][ks] = *(const s16x8*)(Bb0 + (size_t)(q2 * 64 + wn * 16 + (lane & 15)) * 64 + kb);
                    }
                if (t + 1 < nkt) stageA(t + 1, 0);
            } else {
                if (t + 1 < nkt) stageA(t + 1, 1);
            }
            __builtin_amdgcn_s_setprio(1);
            #pragma unroll
            for (int j = 0; j < 4; ++j)
                #pragma unroll
                for (int q2 = 0; q2 < 2; ++q2)
                    #pragma unroll
                    for (int ks = 0; ks < 2; ++ks)
                        acc[rh * 4 + j][q2] = __builtin_amdgcn_mfma_f32_16x16x32_bf16(
                            a[j][ks], bfr[q2][ks], acc[rh * 4 + j][q2], 0, 0, 0);
            __builtin_amdgcn_s_setprio(0);
        }

        // ---- SYNC-2: B1(t) landed (allow A0(t+1),A1(t+1) in flight); also B0(t) WAR done
        if (t + 1 < nkt) { asm volatile("s_waitcnt vmcnt(4)" ::: "memory"); }
        else             { asm volatile("s_waitcnt vmcnt(0)" ::: "memory"); }
        __builtin_amdgcn_s_barrier();
        asm volatile("" ::: "memory");

        #pragma unroll
        for (int rh = 0; rh < 2; ++rh){
            s16x8 a[4][2];
            #pragma unroll
            for (int j = 0; j < 4; ++j)
                #pragma unroll
                for (int ks = 0; ks < 2; ++ks){
                    int kb = (((ks * 4 + (lane >> 4)) ^ (lane & 7))) * 8;
                    a[j][ks] = *(const s16x8*)(Ab + (size_t)(rh * 64 + j * 16 + (lane & 15)) * 64 + kb);
                }
            if (rh == 0){
                #pragma unroll
                for (int q2 = 0; q2 < 2; ++q2)
                    #pragma unroll
                    for (int ks = 0; ks < 2; ++ks){
                        int kb = (((ks * 4 + (lane >> 4)) ^ (lane & 7))) * 8;
                        bfr[q2][ks] = *(const s16x8*)(Bb1 + (size_t)(q2 * 64 + wn * 16 + (lane & 15)) * 64 + kb);
                    }
                if (t + 2 < nkt) stageB(t + 2, 0);
            } else {
                if (t + 1 < nkt) stageB(t + 1, 1);
            }
            __builtin_amdgcn_s_setprio(1);
            #pragma unroll
            for (int j = 0; j < 4; ++j)
                #pragma unroll
                for (int q2 = 0; q2 < 2; ++q2)
                    #pragma unroll
                    for (int ks = 0; ks < 2; ++ks)
                        acc[rh * 4 + j][2 + q2] = __builtin_amdgcn_mfma_f32_16x16x32_bf16(
                            a[j][ks], bfr[q2][ks], acc[rh * 4 + j][2 + q2], 0, 0, 0);
            __builtin_amdgcn_s_setprio(0);
        }
        __builtin_amdgcn_s_barrier();   // close K-tile: protect A(t) before A(t+2) restage
        asm volatile("" ::: "memory");
    }

    // -------- epilogue: lane owns 32 rows x col mg, all 4 gates in acc[r][q]
    const float b0 = bp[0 * 256 + mg];
    const float b1 = bp[1 * 256 + mg];
    const float b2 = bp[2 * 256 + mg];
    const float b3 = bp[3 * 256 + mg];
    #pragma unroll
    for (int r = 0; r < 8; ++r){
        const int base = row0 + wm * 128 + r * 16 + (lane >> 4) * 4;
        float cpre[4];
        #pragma unroll
        for (int e = 0; e < 4; ++e)
            cpre[e] = csum_in[(size_t)(base + e) * MEM + mg];
        float cn[4], hn[4];
        #pragma unroll
        for (int e = 0; e < 4; ++e){
            float iv = acc[r][0][e] + b0;
            float fv = acc[r][1][e] + b1;
            float gv = acc[r][2][e] + b2;
            float ov = acc[r][3][e] + b3;
            float c  = fsigm(fv) * cpre[e] + fsigm(iv) * ftanh(gv);
            cn[e] = c;
            hn[e] = fsigm(ov) * ftanh(c);
        }
        int p0 = base >> 1;
        A_next[(size_t)p0 * KTOT + IN_DIM + mg] = f2bf(hn[0] + hn[1]);
        csum_out[(size_t)p0 * MEM + mg] = cn[0] + cn[1];
        A_next[(size_t)(p0 + 1) * KTOT + IN_DIM + mg] = f2bf(hn[2] + hn[3]);
        csum_out[(size_t)(p0 + 1) * MEM + mg] = cn[2] + cn[3];
    }
}

// ================= proven 128-row GEMM + LSTM + pair-sum (round-8 schedule, verbatim) =================
#define BM 128
#define KC 64

template<int NK>
__global__ __launch_bounds__(256) void gemm_lstm_kernel(
    const unsigned short* __restrict__ A, int n,
    const unsigned short* __restrict__ Wp, const float* __restrict__ bp,
    const float* __restrict__ csum_in, int leaf,
    unsigned short* __restrict__ A_next, float* __restrict__ csum_out)
{
    __shared__ __align__(16) unsigned short As[2][BM * KC];
    __shared__ __align__(16) unsigned short Bs[2][BM * KC];

    const int tid  = threadIdx.x;
    const int lane = tid & 63;
    const int wid  = tid >> 6;
    const int wm   = wid >> 1;
    const int wc   = wid & 1;
    const int row0 = blockIdx.x * BM;
    const int m0   = blockIdx.y * 32;

    const int srow = lane >> 3;
    const int scol = ((lane & 7) ^ srow) * 8;

    const int mg = m0 + wc * 16 + (lane & 15);

    const float b0 = bp[0 * 256 + mg];
    const float b1 = bp[1 * 256 + mg];
    const float b2 = bp[2 * 256 + mg];
    const float b3 = bp[3 * 256 + mg];
    float cpre[4][4];
    if (!leaf){
        #pragma unroll
        for (int r = 0; r < 4; ++r){
            const int base = row0 + wm * 64 + r * 16 + (lane >> 4) * 4;
            #pragma unroll
            for (int e = 0; e < 4; ++e)
                cpre[r][e] = csum_in[(size_t)(base + e) * MEM + mg];
        }
    } else {
        #pragma unroll
        for (int r = 0; r < 4; ++r)
            #pragma unroll
            for (int e = 0; e < 4; ++e) cpre[r][e] = 0.f;
    }

    f32x4 acc[4][4];
    #pragma unroll
    for (int r = 0; r < 4; ++r)
        #pragma unroll
        for (int q = 0; q < 4; ++q)
            acc[r][q] = (f32x4){0.f, 0.f, 0.f, 0.f};

    auto stage = [&](int d, int kk){
        char* asb = (char*)As[d];
        char* bsb = (char*)Bs[d];
        #pragma unroll
        for (int q = 0; q < 4; ++q){
            int t = wid * 4 + q;
            int r = t * 8 + srow;
            gld_lds16(A + (size_t)(row0 + r) * NK + kk + scol, asb + t * 1024);
        }
        #pragma unroll
        for (int q = 0; q < 4; ++q){
            int t = wid * 4 + q;
            int b = t * 8 + srow;
            int grow = (b >> 5) * 256 + m0 + (b & 31);
            gld_lds16(Wp + (size_t)grow * KTOT + kk + scol, bsb + t * 1024);
        }
    };

    constexpr int nIter = NK / KC;
    stage(0, 0);
    int buf = 0;
    #pragma unroll
    for (int it = 0; it < nIter; ++it){
        if (it + 1 < nIter){
            stage(buf ^ 1, (it + 1) * KC);
            asm volatile("s_waitcnt vmcnt(8)" ::: "memory");
        } else {
            asm volatile("s_waitcnt vmcnt(0)" ::: "memory");
        }
        __builtin_amdgcn_s_barrier();
        const unsigned short* Ab = As[buf];
        const unsigned short* Bb = Bs[buf];
        #pragma unroll
        for (int ks = 0; ks < 2; ++ks){
            const int slot = ks * 4 + (lane >> 4);
            const int kb = (slot ^ (lane & 7)) * 8;
            s16x8 a[4], b[4];
            #pragma unroll
            for (int r = 0; r < 4; ++r)
                a[r] = *(const s16x8*)(Ab + (wm * 64 + r * 16 + (lane & 15)) * KC + kb);
            #pragma unroll
            for (int q = 0; q < 4; ++q)
                b[q] = *(const s16x8*)(Bb + (q * 32 + wc * 16 + (lane & 15)) * KC + kb);
            #pragma unroll
            for (int r = 0; r < 4; ++r)
                #pragma unroll
                for (int q = 0; q < 4; ++q)
                    acc[r][q] = __builtin_amdgcn_mfma_f32_16x16x32_bf16(a[r], b[q], acc[r][q], 0, 0, 0);
        }
        __builtin_amdgcn_s_barrier();
        buf ^= 1;
    }

    #pragma unroll
    for (int r = 0; r < 4; ++r){
        const int base = row0 + wm * 64 + r * 16 + (lane >> 4) * 4;
        float cn[4], hn[4];
        #pragma unroll
        for (int e = 0; e < 4; ++e){
            float iv = acc[r][0][e] + b0;
            float fv = acc[r][1][e] + b1;
            float gv = acc[r][2][e] + b2;
            float ov = acc[r][3][e] + b3;
            float c  = fsigm(fv) * cpre[r][e] + fsigm(iv) * ftanh(gv);
            cn[e] = c;
            hn[e] = fsigm(ov) * ftanh(c);
        }
        if (base < n){
            int p0 = base >> 1;
            A_next[(size_t)p0 * KTOT + IN_DIM + mg] = f2bf(hn[0] + hn[1]);
            csum_out[(size_t)p0 * MEM + mg] = cn[0] + cn[1];
        }
        if (base + 2 < n){
            int p1 = (base >> 1) + 1;
            A_next[(size_t)p1 * KTOT + IN_DIM + mg] = f2bf(hn[2] + hn[3]);
            csum_out[(size_t)p1 * MEM + mg] = cn[2] + cn[3];
        }
    }
}

// ---------------- tail: levels 7..0 + FC fused, 8 blocks, device grid barrier
// All intra-kernel cross-block traffic is device-coherent (sc0|sc1): write-through
// stores + coherence-point loads -> the barrier fences have nothing to flush/invalidate.
__global__ __launch_bounds__(256) void tail_kernel(
    const unsigned short* __restrict__ arena,
    const unsigned short* __restrict__ Wp, const float* __restrict__ bp,
    float* cs_in, float* cs_out,
    float* __restrict__ c_root,
    const float* __restrict__ W_fc, const float* __restrict__ b_fc,
    float* __restrict__ out, unsigned* __restrict__ ctr)
{
    __shared__ __align__(16) unsigned short WpL[128 * KTOT];   // 96 KB
    __shared__ __align__(16) unsigned short AL[64 * KTOT];     // 48 KB

    const int tid  = threadIdx.x;
    const int lane = tid & 63;
    const int wid  = tid >> 6;
    const int wm   = wid >> 1;
    const int wc   = wid & 1;
    const int m0   = blockIdx.x * 32;
    const int mg   = m0 + wc * 16 + (lane & 15);

    #pragma unroll
    for (int i = 0; i < 24; ++i){
        int p0 = wid * 1536 + i * 64;
        int p  = p0 + lane;
        int lrow  = p / 48;
        int pslot = p % 48;
        int lslot = pslot ^ (lrow & 7);
        int grow  = (lrow >> 5) * 256 + m0 + (lrow & 31);
        gld_lds16(Wp + (size_t)grow * KTOT + lslot * 8, (char*)WpL + (size_t)p0 * 16);
    }

    const float b0 = bp[0 * 256 + mg];
    const float b1 = bp[1 * 256 + mg];
    const float b2 = bp[2 * 256 + mg];
    const float b3 = bp[3 * 256 + mg];

    asm volatile("s_waitcnt vmcnt(0)" ::: "memory");
    __builtin_amdgcn_s_barrier();

    unsigned gen = 0;
    for (int l = 7; l >= 0; --l){
        const int n = 1 << l;
        const unsigned short* Al = arena + offA(l);
        const int nhalf = (n > 64) ? (n >> 6) : 1;

        for (int h = 0; h < nhalf; ++h){
            const int r0 = h * 64;
            const int rows = (n < 64) ? n : 64;

            // ---- batched stage (device-coherent reads)
            const int nslots = rows * 48;
            for (int t = 0; t * 256 < nslots; ++t){
                int pbase = t * 256 + wid * 64;
                int p = pbase + lane;
                if (p < nslots){
                    int row   = p / 48;
                    int pslot = p - row * 48;
                    int lslot = pslot ^ (row & 7);
                    gld_lds16_dev(Al + (size_t)(r0 + row) * KTOT + lslot * 8,
                                  (char*)AL + (size_t)pbase * 16);
                }
            }

            // ---- csum prefetch (device-coherent)
            float cpre[2][4];
            #pragma unroll
            for (int r = 0; r < 2; ++r){
                const int base = r0 + wm * 32 + r * 16 + (lane >> 4) * 4;
                #pragma unroll
                for (int e = 0; e < 4; ++e)
                    cpre[r][e] = __hip_atomic_load(&cs_in[(size_t)(base + e) * MEM + mg],
                                                   __ATOMIC_RELAXED, __HIP_MEMORY_SCOPE_AGENT);
            }

            asm volatile("s_waitcnt vmcnt(0)" ::: "memory");
            __builtin_amdgcn_s_barrier();

            f32x4 acc[2][4];
            #pragma unroll
            for (int r = 0; r < 2; ++r)
                #pragma unroll
                for (int q = 0; q < 4; ++q)
                    acc[r][q] = (f32x4){0.f, 0.f, 0.f, 0.f};

            #pragma unroll
            for (int kc = 0; kc < 12; ++kc){
                const int ls = kc * 4 + (lane >> 4);
                const int kb = (ls ^ (lane & 7)) * 8;
                s16x8 a[2], b[4];
                #pragma unroll
                for (int r = 0; r < 2; ++r)
                    a[r] = *(const s16x8*)(AL + (size_t)(wm * 32 + r * 16 + (lane & 15)) * KTOT + kb);
                #pragma unroll
                for (int q = 0; q < 4; ++q)
                    b[q] = *(const s16x8*)(WpL + (q * 32 + wc * 16 + (lane & 15)) * KTOT + kb);
                #pragma unroll
                for (int r = 0; r < 2; ++r)
                    #pragma unroll
                    for (int q = 0; q < 4; ++q)
                        acc[r][q] = __builtin_amdgcn_mfma_f32_16x16x32_bf16(a[r], b[q], acc[r][q], 0, 0, 0);
            }

            #pragma unroll
            for (int r = 0; r < 2; ++r){
                const int base = r0 + wm * 32 + r * 16 + (lane >> 4) * 4;
                float cn[4], hn[4];
                #pragma unroll
                for (int e = 0; e < 4; ++e){
                    float iv = acc[r][0][e] + b0;
                    float fv = acc[r][1][e] + b1;
                    float gv = acc[r][2][e] + b2;
                    float ov = acc[r][3][e] + b3;
                    float c  = fsigm(fv) * cpre[r][e] + fsigm(iv) * ftanh(gv);
                    cn[e] = c;
                    hn[e] = fsigm(ov) * ftanh(c);
                }
                if (l == 0){
                    if (base == 0) st32_dev(&c_root[mg], cn[0]);
                } else {
                    unsigned short* A_next = (unsigned short*)arena + offA(l - 1);
                    if (base < n){
                        int p0 = base >> 1;
                        st16_dev(&A_next[(size_t)p0 * KTOT + IN_DIM + mg], f2bf(hn[0] + hn[1]));
                        st32_dev(&cs_out[(size_t)p0 * MEM + mg], cn[0] + cn[1]);
                    }
                    if (base + 2 < n){
                        int p1 = (base >> 1) + 1;
                        st16_dev(&A_next[(size_t)p1 * KTOT + IN_DIM + mg], f2bf(hn[2] + hn[3]));
                        st32_dev(&cs_out[(size_t)p1 * MEM + mg], cn[2] + cn[3]);
                    }
                }
            }
            __builtin_amdgcn_s_barrier();
        }

        float* t = cs_in; cs_in = cs_out; cs_out = t;
        ++gen;
        grid_barrier(ctr, (unsigned)(NBLK_TAIL * gen));
    }

    if (blockIdx.x == 0){
        int w = wid;
        for (int cls = w * 3; cls < w * 3 + 3; ++cls){
            float s = 0.f;
            for (int m = lane; m < 256; m += 64)
                s += c_root[m] * W_fc[cls * 256 + m];
            #pragma unroll
            for (int off = 32; off; off >>= 1)
                s += __shfl_down(s, off, 64);
            if (lane == 0) out[cls] = s + b_fc[cls];
        }
    }
}

extern "C" void kernel_launch(void* const* d_in, const int* in_sizes, int n_in,
                              void* d_out, int out_size, void* d_ws, size_t ws_size,
                              hipStream_t stream)
{
    const float* x    = (const float*)d_in[0];
    const float* W_ih = (const float*)d_in[1];
    const float* b_ih = (const float*)d_in[2];
    const float* W_hh = (const float*)d_in[3];
    const float* b_hh = (const float*)d_in[4];
    const float* W_fc = (const float*)d_in[5];
    const float* b_fc = (const float*)d_in[6];
    float* out = (float*)d_out;

    const size_t OFF_WP = 0;
    const size_t OFF_BP = 786432;
    const size_t OFF_A  = 790528;
    const size_t OFF_CS0 = OFF_A + (size_t)(ARENA_ELEMS + ARENA_PAD) * 2;
    const size_t OFF_CS1 = OFF_CS0 + 33554432;
    const size_t OFF_CR  = OFF_CS1 + 33554432;
    const size_t OFF_CTR = OFF_CR + 1024;
    const size_t NEEDED  = OFF_CTR + 64;
    if (ws_size < NEEDED) return;

    char* ws = (char*)d_ws;
    unsigned short* Wp    = (unsigned short*)(ws + OFF_WP);
    float* bp             = (float*)(ws + OFF_BP);
    unsigned short* arena = (unsigned short*)(ws + OFF_A);
    float* cs0            = (float*)(ws + OFF_CS0);
    float* cs1            = (float*)(ws + OFF_CS1);
    float* c_root         = (float*)(ws + OFF_CR);
    unsigned* ctr         = (unsigned*)(ws + OFF_CTR);

    pack_kernel<<<dim3(2048), dim3(256), 0, stream>>>(
        x, W_ih, b_ih, W_hh, b_hh, Wp, bp, arena, ctr);

    // ---- leaf (l=16): n=65536, K=128 -> A(15), cs0 (proven 128-kernel)
    gemm_lstm_kernel<IN_DIM><<<dim3(NLEAF / BM, 8), dim3(256), 0, stream>>>(
        arena + offA(16), NLEAF, Wp, bp,
        nullptr, 1, arena + offA(15), cs0);

    // ---- l=15, l=14: 8-phase 256-row kernel
    gemm_lstm8p_kernel<KTOT><<<dim3(128, 4), dim3(512), 0, stream>>>(
        arena + offA(15), 32768, Wp, bp, cs0, arena + offA(14), cs1);
    gemm_lstm8p_kernel<KTOT><<<dim3(64, 4), dim3(512), 0, stream>>>(
        arena + offA(14), 16384, Wp, bp, cs1, arena + offA(13), cs0);

    // ---- l=13..8: proven 128-kernel
    float* cs_in = cs0; float* cs_out = cs1;
    for (int l = 13; l >= 8; --l){
        int n = 1 << l;
        gemm_lstm_kernel<KTOT><<<dim3(n / BM, 8), dim3(256), 0, stream>>>(
            arena + offA(l), n, Wp, bp,
            cs_in, 0, arena + offA(l - 1), cs_out);
        float* t = cs_in; cs_in = cs_out; cs_out = t;
    }

    // ---- tail: levels 7..0 + FC (8 co-resident blocks + grid barrier)
    tail_kernel<<<dim3(NBLK_TAIL), dim3(256), 0, stream>>>(
        arena, Wp, bp, cs_in, cs_out, c_root, W_fc, b_fc, out, ctr);
}

// Round 16
// 207.196 us; speedup vs baseline: 1.1427x; 1.0246x over previous
//
#include <hip/hip_runtime.h>
#include <hip/hip_bf16.h>
#include <cstddef>

#define IN_DIM 128
#define MEM 256
#define KTOT 384
#define NLEAF 65536
#define NBLK_TAIL 8

typedef float f32x4 __attribute__((ext_vector_type(4)));
typedef short s16x8 __attribute__((ext_vector_type(8)));
typedef unsigned int u32;

__device__ inline unsigned short f2bf(float f){
    unsigned int u = __builtin_bit_cast(unsigned int, f);
    u += 0x7fff + ((u >> 16) & 1);
    return (unsigned short)(u >> 16);
}

__device__ inline void gld_lds16(const void* g, void* l){
    __builtin_amdgcn_global_load_lds((const __attribute__((address_space(1))) u32*)g,
                                     (__attribute__((address_space(3))) u32*)l, 16, 0, 0);
}
// device-coherent (SC0|SC1 = 1|16 = 17): read from coherence point, bypass stale L1/L2
__device__ inline void gld_lds16_dev(const void* g, void* l){
    __builtin_amdgcn_global_load_lds((const __attribute__((address_space(1))) u32*)g,
                                     (__attribute__((address_space(3))) u32*)l, 16, 0, 17);
}
// write-through device-coherent stores (coherence point direct; no dirty cache lines)
__device__ inline void st16_dev(unsigned short* p, unsigned short v){
    unsigned int vv = v;
    asm volatile("global_store_short %0, %1, off sc0 sc1" :: "v"(p), "v"(vv) : "memory");
}
__device__ inline void st32_dev(float* p, float v){
    asm volatile("global_store_dword %0, %1, off sc0 sc1" :: "v"(p), "v"(v) : "memory");
}

__device__ inline float fsigm(float x){
    return __builtin_amdgcn_rcpf(1.f + __expf(-x));
}
__device__ inline float ftanh(float x){
    return 2.f * __builtin_amdgcn_rcpf(1.f + __expf(-2.f * x)) - 1.f;
}

// A-arena element offsets: leaf (l=16) at 0, stride 128; levels 15..0 stride 384.
__host__ __device__ inline size_t offA(int l){
    if (l == 16) return 0;
    return 8388608u + 384u * (65536u - (1u << (l + 1)));
}
#define ARENA_ELEMS 33554048u
#define ARENA_PAD   65536u

// FENCE-FREE grid barrier (8 co-resident blocks). All cross-block data already
// flows through the coherence point (sc0sc1 stores / aux=17 LDS loads / agent
// atomics), so no __threadfence (buffer_wbl2/inv: fixed whole-L2-scan cost) is
// needed. Ordering: per-thread vmcnt(0) -> syncthreads -> relaxed atomic inc.
__device__ inline void grid_barrier_nf(unsigned* ctr, unsigned target){
    asm volatile("s_waitcnt vmcnt(0)" ::: "memory");   // own coherent stores ack'd
    __syncthreads();
    if (threadIdx.x == 0){
        __hip_atomic_fetch_add(ctr, 1u, __ATOMIC_RELAXED, __HIP_MEMORY_SCOPE_AGENT);
        while (__hip_atomic_load(ctr, __ATOMIC_RELAXED, __HIP_MEMORY_SCOPE_AGENT) < target)
            __builtin_amdgcn_s_sleep(2);
    }
    __syncthreads();
}

// ---------------- fused pack: W (+bias, +ctr reset) and all x rows -> bf16 arena
__global__ void pack_kernel(const float* __restrict__ x,
                            const float* __restrict__ W_ih, const float* __restrict__ b_ih,
                            const float* __restrict__ W_hh, const float* __restrict__ b_hh,
                            unsigned short* __restrict__ Wp, float* __restrict__ bp,
                            unsigned short* __restrict__ Aarena, unsigned* __restrict__ ctr){
    const int stride = gridDim.x * blockDim.x;
    const int tid0 = blockIdx.x * blockDim.x + threadIdx.x;
    if (tid0 == 0){ ctr[0] = 0; }

    for (int g = tid0; g < 1024 * 48; g += stride){
        int row = g / 48, ko = (g - row * 48) * 8;
        const float* s = (ko < IN_DIM) ? (W_ih + (size_t)row * IN_DIM + ko)
                                       : (W_hh + (size_t)row * MEM + (ko - IN_DIM));
        f32x4 v0 = *(const f32x4*)s, v1 = *(const f32x4*)(s + 4);
        s16x8 o;
        #pragma unroll
        for (int e = 0; e < 4; ++e){ o[e] = (short)f2bf(v0[e]); o[4+e] = (short)f2bf(v1[e]); }
        *(s16x8*)(Wp + (size_t)row * KTOT + ko) = o;
        if (ko == 0) bp[row] = b_ih[row] + b_hh[row];
    }

    const int TOTAL_G = 131071 * 16;
    for (int g = tid0; g < TOTAL_G; g += stride){
        int i  = g >> 4;
        int ko = (g & 15) * 8;
        int l  = 31 - __clz(i + 1);
        int j  = i + 1 - (1 << l);
        size_t dst = offA(l) + (size_t)j * ((l == 16) ? 128 : 384) + ko;
        const f32x4* s = (const f32x4*)(x + (size_t)i * IN_DIM + ko);
        f32x4 v0 = s[0], v1 = s[1];
        s16x8 o;
        #pragma unroll
        for (int e = 0; e < 4; ++e){ o[e] = (short)f2bf(v0[e]); o[4+e] = (short)f2bf(v1[e]); }
        *(s16x8*)(Aarena + dst) = o;
    }
}

// ================= 8-phase-style 256-row GEMM + LSTM + pair-sum (l15, l14) =================
// Block: 256 rows x 64 mem cols (256 gate cols). 512 threads, 8 waves (wm 2 x wn 4).
// Wave: 128 rows x 64 gate cols -> acc[8][4]; per-lane all 4 gates of col mg.
// Half-tile staging (A0/A1/B0/B1 = 16 KB each), 2-dbuf (128 KB LDS), counted vmcnt(4),
// 4 compute phases (quadrants) per K-tile, 2 sync points/K-tile, setprio around MFMA.
template<int NK>
__global__ __launch_bounds__(512, 1) void gemm_lstm8p_kernel(
    const unsigned short* __restrict__ A, int n,
    const unsigned short* __restrict__ Wp, const float* __restrict__ bp,
    const float* __restrict__ csum_in,
    unsigned short* __restrict__ A_next, float* __restrict__ csum_out)
{
    __shared__ __align__(16) unsigned short As[2][2][128 * 64];   // [buf][half] 64 KB
    __shared__ __align__(16) unsigned short Bs[2][2][128 * 64];   // 64 KB

    const int tid  = threadIdx.x;
    const int lane = tid & 63;
    const int wid  = tid >> 6;        // 0..7
    const int wm   = wid >> 2;        // A row-half (128 rows)
    const int wn   = wid & 3;         // mem 16-col group
    const int row0 = blockIdx.x * 256;
    const int m0   = blockIdx.y * 64;
    const int mg   = m0 + wn * 16 + (lane & 15);

    auto stageA = [&](int kt, int h){
        #pragma unroll
        for (int i = 0; i < 2; ++i){
            int p  = i * 512 + tid;
            int r  = p >> 3;                       // 0..127 within half
            int ls = (p & 7) ^ (r & 7);            // pre-swizzled source slot
            gld_lds16(A + (size_t)(row0 + h * 128 + r) * NK + kt * 64 + ls * 8,
                      (char*)As[kt & 1][h] + (size_t)(i * 512 + wid * 64) * 16);
        }
    };
    auto stageB = [&](int kt, int h){
        #pragma unroll
        for (int i = 0; i < 2; ++i){
            int p  = i * 512 + tid;
            int r  = p >> 3;
            int b  = h * 128 + r;                  // B tile row 0..255
            int grow = (b >> 6) * 256 + m0 + (b & 63);
            int ls = (p & 7) ^ (r & 7);            // b&7 == r&7
            gld_lds16(Wp + (size_t)grow * KTOT + kt * 64 + ls * 8,
                      (char*)Bs[kt & 1][h] + (size_t)(i * 512 + wid * 64) * 16);
        }
    };

    f32x4 acc[8][4];
    #pragma unroll
    for (int r = 0; r < 8; ++r)
        #pragma unroll
        for (int q = 0; q < 4; ++q)
            acc[r][q] = (f32x4){0.f, 0.f, 0.f, 0.f};

    constexpr int nkt = NK / 64;
    // prologue: A0(0), A1(0), B0(0), B0(1), B1(0)
    stageA(0, 0); stageA(0, 1); stageB(0, 0);
    if (nkt > 1) stageB(1, 0);
    stageB(0, 1);

    s16x8 bfr[2][2];   // B frags, reused across rh phases

    #pragma unroll
    for (int t = 0; t < nkt; ++t){
        const unsigned short* Ab = As[t & 1][wm];
        const unsigned short* Bb0 = Bs[t & 1][0];
        const unsigned short* Bb1 = Bs[t & 1][1];

        // ---- SYNC-1: A0(t),A1(t),B0(t) landed (allow B0(t+1),B1(t) in flight)
        if (t + 1 < nkt) { asm volatile("s_waitcnt vmcnt(4)" ::: "memory"); }
        else             { asm volatile("s_waitcnt vmcnt(2)" ::: "memory"); }
        __builtin_amdgcn_s_barrier();
        asm volatile("" ::: "memory");

        #pragma unroll
        for (int rh = 0; rh < 2; ++rh){
            s16x8 a[4][2];
            #pragma unroll
            for (int j = 0; j < 4; ++j)
                #pragma unroll
                for (int ks = 0; ks < 2; ++ks){
                    int kb = (((ks * 4 + (lane >> 4)) ^ (lane & 7))) * 8;
                    a[j][ks] = *(const s16x8*)(Ab + (size_t)(rh * 64 + j * 16 + (lane & 15)) * 64 + kb);
                }
            if (rh == 0){
                #pragma unroll
                for (int q2 = 0; q2 < 2; ++q2)
                    #pragma unroll
                    for (int ks = 0; ks < 2; ++ks){
                        int kb = (((ks * 4 + (lane >> 4)) ^ (lane & 7))) * 8;
                        bfr[q2][ks] = *(const s16x8*)(Bb0 + (size_t)(q2 * 64 + wn * 16 + (lane & 15)) * 64 + kb);
                    }
                if (t + 1 < nkt) stageA(t + 1, 0);
            } else {
                if (t + 1 < nkt) stageA(t + 1, 1);
            }
            __builtin_amdgcn_s_setprio(1);
            #pragma unroll
            for (int j = 0; j < 4; ++j)
                #pragma unroll
                for (int q2 = 0; q2 < 2; ++q2)
                    #pragma unroll
                    for (int ks = 0; ks < 2; ++ks)
                        acc[rh * 4 + j][q2] = __builtin_amdgcn_mfma_f32_16x16x32_bf16(
                            a[j][ks], bfr[q2][ks], acc[rh * 4 + j][q2], 0, 0, 0);
            __builtin_amdgcn_s_setprio(0);
        }

        // ---- SYNC-2: B1(t) landed (allow A0(t+1),A1(t+1) in flight); also B0(t) WAR done
        if (t + 1 < nkt) { asm volatile("s_waitcnt vmcnt(4)" ::: "memory"); }
        else             { asm volatile("s_waitcnt vmcnt(0)" ::: "memory"); }
        __builtin_amdgcn_s_barrier();
        asm volatile("" ::: "memory");

        #pragma unroll
        for (int rh = 0; rh < 2; ++rh){
            s16x8 a[4][2];
            #pragma unroll
            for (int j = 0; j < 4; ++j)
                #pragma unroll
                for (int ks = 0; ks < 2; ++ks){
                    int kb = (((ks * 4 + (lane >> 4)) ^ (lane & 7))) * 8;
                    a[j][ks] = *(const s16x8*)(Ab + (size_t)(rh * 64 + j * 16 + (lane & 15)) * 64 + kb);
                }
            if (rh == 0){
                #pragma unroll
                for (int q2 = 0; q2 < 2; ++q2)
                    #pragma unroll
                    for (int ks = 0; ks < 2; ++ks){
                        int kb = (((ks * 4 + (lane >> 4)) ^ (lane & 7))) * 8;
                        bfr[q2][ks] = *(const s16x8*)(Bb1 + (size_t)(q2 * 64 + wn * 16 + (lane & 15)) * 64 + kb);
                    }
                if (t + 2 < nkt) stageB(t + 2, 0);
            } else {
                if (t + 1 < nkt) stageB(t + 1, 1);
            }
            __builtin_amdgcn_s_setprio(1);
            #pragma unroll
            for (int j = 0; j < 4; ++j)
                #pragma unroll
                for (int q2 = 0; q2 < 2; ++q2)
                    #pragma unroll
                    for (int ks = 0; ks < 2; ++ks)
                        acc[rh * 4 + j][2 + q2] = __builtin_amdgcn_mfma_f32_16x16x32_bf16(
                            a[j][ks], bfr[q2][ks], acc[rh * 4 + j][2 + q2], 0, 0, 0);
            __builtin_amdgcn_s_setprio(0);
        }
        __builtin_amdgcn_s_barrier();   // close K-tile: protect A(t) before A(t+2) restage
        asm volatile("" ::: "memory");
    }

    // -------- epilogue: lane owns 32 rows x col mg, all 4 gates in acc[r][q]
    const float b0 = bp[0 * 256 + mg];
    const float b1 = bp[1 * 256 + mg];
    const float b2 = bp[2 * 256 + mg];
    const float b3 = bp[3 * 256 + mg];
    #pragma unroll
    for (int r = 0; r < 8; ++r){
        const int base = row0 + wm * 128 + r * 16 + (lane >> 4) * 4;
        float cpre[4];
        #pragma unroll
        for (int e = 0; e < 4; ++e)
            cpre[e] = csum_in[(size_t)(base + e) * MEM + mg];
        float cn[4], hn[4];
        #pragma unroll
        for (int e = 0; e < 4; ++e){
            float iv = acc[r][0][e] + b0;
            float fv = acc[r][1][e] + b1;
            float gv = acc[r][2][e] + b2;
            float ov = acc[r][3][e] + b3;
            float c  = fsigm(fv) * cpre[e] + fsigm(iv) * ftanh(gv);
            cn[e] = c;
            hn[e] = fsigm(ov) * ftanh(c);
        }
        int p0 = base >> 1;
        A_next[(size_t)p0 * KTOT + IN_DIM + mg] = f2bf(hn[0] + hn[1]);
        csum_out[(size_t)p0 * MEM + mg] = cn[0] + cn[1];
        A_next[(size_t)(p0 + 1) * KTOT + IN_DIM + mg] = f2bf(hn[2] + hn[3]);
        csum_out[(size_t)(p0 + 1) * MEM + mg] = cn[2] + cn[3];
    }
}

// ================= proven 128-row GEMM + LSTM + pair-sum (round-8 schedule, verbatim) =================
#define BM 128
#define KC 64

template<int NK>
__global__ __launch_bounds__(256) void gemm_lstm_kernel(
    const unsigned short* __restrict__ A, int n,
    const unsigned short* __restrict__ Wp, const float* __restrict__ bp,
    const float* __restrict__ csum_in, int leaf,
    unsigned short* __restrict__ A_next, float* __restrict__ csum_out)
{
    __shared__ __align__(16) unsigned short As[2][BM * KC];
    __shared__ __align__(16) unsigned short Bs[2][BM * KC];

    const int tid  = threadIdx.x;
    const int lane = tid & 63;
    const int wid  = tid >> 6;
    const int wm   = wid >> 1;
    const int wc   = wid & 1;
    const int row0 = blockIdx.x * BM;
    const int m0   = blockIdx.y * 32;

    const int srow = lane >> 3;
    const int scol = ((lane & 7) ^ srow) * 8;

    const int mg = m0 + wc * 16 + (lane & 15);

    const float b0 = bp[0 * 256 + mg];
    const float b1 = bp[1 * 256 + mg];
    const float b2 = bp[2 * 256 + mg];
    const float b3 = bp[3 * 256 + mg];
    float cpre[4][4];
    if (!leaf){
        #pragma unroll
        for (int r = 0; r < 4; ++r){
            const int base = row0 + wm * 64 + r * 16 + (lane >> 4) * 4;
            #pragma unroll
            for (int e = 0; e < 4; ++e)
                cpre[r][e] = csum_in[(size_t)(base + e) * MEM + mg];
        }
    } else {
        #pragma unroll
        for (int r = 0; r < 4; ++r)
            #pragma unroll
            for (int e = 0; e < 4; ++e) cpre[r][e] = 0.f;
    }

    f32x4 acc[4][4];
    #pragma unroll
    for (int r = 0; r < 4; ++r)
        #pragma unroll
        for (int q = 0; q < 4; ++q)
            acc[r][q] = (f32x4){0.f, 0.f, 0.f, 0.f};

    auto stage = [&](int d, int kk){
        char* asb = (char*)As[d];
        char* bsb = (char*)Bs[d];
        #pragma unroll
        for (int q = 0; q < 4; ++q){
            int t = wid * 4 + q;
            int r = t * 8 + srow;
            gld_lds16(A + (size_t)(row0 + r) * NK + kk + scol, asb + t * 1024);
        }
        #pragma unroll
        for (int q = 0; q < 4; ++q){
            int t = wid * 4 + q;
            int b = t * 8 + srow;
            int grow = (b >> 5) * 256 + m0 + (b & 31);
            gld_lds16(Wp + (size_t)grow * KTOT + kk + scol, bsb + t * 1024);
        }
    };

    constexpr int nIter = NK / KC;
    stage(0, 0);
    int buf = 0;
    #pragma unroll
    for (int it = 0; it < nIter; ++it){
        if (it + 1 < nIter){
            stage(buf ^ 1, (it + 1) * KC);
            asm volatile("s_waitcnt vmcnt(8)" ::: "memory");
        } else {
            asm volatile("s_waitcnt vmcnt(0)" ::: "memory");
        }
        __builtin_amdgcn_s_barrier();
        const unsigned short* Ab = As[buf];
        const unsigned short* Bb = Bs[buf];
        #pragma unroll
        for (int ks = 0; ks < 2; ++ks){
            const int slot = ks * 4 + (lane >> 4);
            const int kb = (slot ^ (lane & 7)) * 8;
            s16x8 a[4], b[4];
            #pragma unroll
            for (int r = 0; r < 4; ++r)
                a[r] = *(const s16x8*)(Ab + (wm * 64 + r * 16 + (lane & 15)) * KC + kb);
            #pragma unroll
            for (int q = 0; q < 4; ++q)
                b[q] = *(const s16x8*)(Bb + (q * 32 + wc * 16 + (lane & 15)) * KC + kb);
            #pragma unroll
            for (int r = 0; r < 4; ++r)
                #pragma unroll
                for (int q = 0; q < 4; ++q)
                    acc[r][q] = __builtin_amdgcn_mfma_f32_16x16x32_bf16(a[r], b[q], acc[r][q], 0, 0, 0);
        }
        __builtin_amdgcn_s_barrier();
        buf ^= 1;
    }

    #pragma unroll
    for (int r = 0; r < 4; ++r){
        const int base = row0 + wm * 64 + r * 16 + (lane >> 4) * 4;
        float cn[4], hn[4];
        #pragma unroll
        for (int e = 0; e < 4; ++e){
            float iv = acc[r][0][e] + b0;
            float fv = acc[r][1][e] + b1;
            float gv = acc[r][2][e] + b2;
            float ov = acc[r][3][e] + b3;
            float c  = fsigm(fv) * cpre[r][e] + fsigm(iv) * ftanh(gv);
            cn[e] = c;
            hn[e] = fsigm(ov) * ftanh(c);
        }
        if (base < n){
            int p0 = base >> 1;
            A_next[(size_t)p0 * KTOT + IN_DIM + mg] = f2bf(hn[0] + hn[1]);
            csum_out[(size_t)p0 * MEM + mg] = cn[0] + cn[1];
        }
        if (base + 2 < n){
            int p1 = (base >> 1) + 1;
            A_next[(size_t)p1 * KTOT + IN_DIM + mg] = f2bf(hn[2] + hn[3]);
            csum_out[(size_t)p1 * MEM + mg] = cn[2] + cn[3];
        }
    }
}

// ---------------- tail: levels 7..0 + FC fused, 8 blocks, FENCE-FREE grid barrier.
// All cross-block traffic is device-coherent: sc0sc1 write-through stores,
// aux=17 LDS stages, agent-relaxed atomic loads -> barriers need no cache maintenance.
__global__ __launch_bounds__(256) void tail_kernel(
    const unsigned short* __restrict__ arena,
    const unsigned short* __restrict__ Wp, const float* __restrict__ bp,
    float* cs_in, float* cs_out,
    float* __restrict__ c_root,
    const float* __restrict__ W_fc, const float* __restrict__ b_fc,
    float* __restrict__ out, unsigned* __restrict__ ctr)
{
    __shared__ __align__(16) unsigned short WpL[128 * KTOT];   // 96 KB
    __shared__ __align__(16) unsigned short AL[64 * KTOT];     // 48 KB

    const int tid  = threadIdx.x;
    const int lane = tid & 63;
    const int wid  = tid >> 6;
    const int wm   = wid >> 1;
    const int wc   = wid & 1;
    const int m0   = blockIdx.x * 32;
    const int mg   = m0 + wc * 16 + (lane & 15);

    #pragma unroll
    for (int i = 0; i < 24; ++i){
        int p0 = wid * 1536 + i * 64;
        int p  = p0 + lane;
        int lrow  = p / 48;
        int pslot = p % 48;
        int lslot = pslot ^ (lrow & 7);
        int grow  = (lrow >> 5) * 256 + m0 + (lrow & 31);
        gld_lds16(Wp + (size_t)grow * KTOT + lslot * 8, (char*)WpL + (size_t)p0 * 16);
    }

    const float b0 = bp[0 * 256 + mg];
    const float b1 = bp[1 * 256 + mg];
    const float b2 = bp[2 * 256 + mg];
    const float b3 = bp[3 * 256 + mg];

    asm volatile("s_waitcnt vmcnt(0)" ::: "memory");
    __builtin_amdgcn_s_barrier();

    unsigned gen = 0;
    for (int l = 7; l >= 0; --l){
        const int n = 1 << l;
        const unsigned short* Al = arena + offA(l);
        const int nhalf = (n > 64) ? (n >> 6) : 1;

        for (int h = 0; h < nhalf; ++h){
            const int r0 = h * 64;
            const int rows = (n < 64) ? n : 64;

            // ---- batched stage (device-coherent reads)
            const int nslots = rows * 48;
            for (int t = 0; t * 256 < nslots; ++t){
                int pbase = t * 256 + wid * 64;
                int p = pbase + lane;
                if (p < nslots){
                    int row   = p / 48;
                    int pslot = p - row * 48;
                    int lslot = pslot ^ (row & 7);
                    gld_lds16_dev(Al + (size_t)(r0 + row) * KTOT + lslot * 8,
                                  (char*)AL + (size_t)pbase * 16);
                }
            }

            // ---- csum prefetch (device-coherent)
            float cpre[2][4];
            #pragma unroll
            for (int r = 0; r < 2; ++r){
                const int base = r0 + wm * 32 + r * 16 + (lane >> 4) * 4;
                #pragma unroll
                for (int e = 0; e < 4; ++e)
                    cpre[r][e] = __hip_atomic_load(&cs_in[(size_t)(base + e) * MEM + mg],
                                                   __ATOMIC_RELAXED, __HIP_MEMORY_SCOPE_AGENT);
            }

            asm volatile("s_waitcnt vmcnt(0)" ::: "memory");
            __builtin_amdgcn_s_barrier();

            f32x4 acc[2][4];
            #pragma unroll
            for (int r = 0; r < 2; ++r)
                #pragma unroll
                for (int q = 0; q < 4; ++q)
                    acc[r][q] = (f32x4){0.f, 0.f, 0.f, 0.f};

            #pragma unroll
            for (int kc = 0; kc < 12; ++kc){
                const int ls = kc * 4 + (lane >> 4);
                const int kb = (ls ^ (lane & 7)) * 8;
                s16x8 a[2], b[4];
                #pragma unroll
                for (int r = 0; r < 2; ++r)
                    a[r] = *(const s16x8*)(AL + (size_t)(wm * 32 + r * 16 + (lane & 15)) * KTOT + kb);
                #pragma unroll
                for (int q = 0; q < 4; ++q)
                    b[q] = *(const s16x8*)(WpL + (q * 32 + wc * 16 + (lane & 15)) * KTOT + kb);
                #pragma unroll
                for (int r = 0; r < 2; ++r)
                    #pragma unroll
                    for (int q = 0; q < 4; ++q)
                        acc[r][q] = __builtin_amdgcn_mfma_f32_16x16x32_bf16(a[r], b[q], acc[r][q], 0, 0, 0);
            }

            #pragma unroll
            for (int r = 0; r < 2; ++r){
                const int base = r0 + wm * 32 + r * 16 + (lane >> 4) * 4;
                float cn[4], hn[4];
                #pragma unroll
                for (int e = 0; e < 4; ++e){
                    float iv = acc[r][0][e] + b0;
                    float fv = acc[r][1][e] + b1;
                    float gv = acc[r][2][e] + b2;
                    float ov = acc[r][3][e] + b3;
                    float c  = fsigm(fv) * cpre[r][e] + fsigm(iv) * ftanh(gv);
                    cn[e] = c;
                    hn[e] = fsigm(ov) * ftanh(c);
                }
                if (l == 0){
                    if (base == 0) st32_dev(&c_root[mg], cn[0]);
                } else {
                    unsigned short* A_next = (unsigned short*)arena + offA(l - 1);
                    if (base < n){
                        int p0 = base >> 1;
                        st16_dev(&A_next[(size_t)p0 * KTOT + IN_DIM + mg], f2bf(hn[0] + hn[1]));
                        st32_dev(&cs_out[(size_t)p0 * MEM + mg], cn[0] + cn[1]);
                    }
                    if (base + 2 < n){
                        int p1 = (base >> 1) + 1;
                        st16_dev(&A_next[(size_t)p1 * KTOT + IN_DIM + mg], f2bf(hn[2] + hn[3]));
                        st32_dev(&cs_out[(size_t)p1 * MEM + mg], cn[2] + cn[3]);
                    }
                }
            }
            __builtin_amdgcn_s_barrier();
        }

        float* t = cs_in; cs_in = cs_out; cs_out = t;
        ++gen;
        grid_barrier_nf(ctr, (unsigned)(NBLK_TAIL * gen));
    }

    // FC: c_root was written with sc0sc1 by all blocks -> read device-coherent.
    if (blockIdx.x == 0){
        int w = wid;
        for (int cls = w * 3; cls < w * 3 + 3; ++cls){
            float s = 0.f;
            for (int m = lane; m < 256; m += 64){
                float cr = __hip_atomic_load(&c_root[m], __ATOMIC_RELAXED, __HIP_MEMORY_SCOPE_AGENT);
                s += cr * W_fc[cls * 256 + m];
            }
            #pragma unroll
            for (int off = 32; off; off >>= 1)
                s += __shfl_down(s, off, 64);
            if (lane == 0) out[cls] = s + b_fc[cls];
        }
    }
}

extern "C" void kernel_launch(void* const* d_in, const int* in_sizes, int n_in,
                              void* d_out, int out_size, void* d_ws, size_t ws_size,
                              hipStream_t stream)
{
    const float* x    = (const float*)d_in[0];
    const float* W_ih = (const float*)d_in[1];
    const float* b_ih = (const float*)d_in[2];
    const float* W_hh = (const float*)d_in[3];
    const float* b_hh = (const float*)d_in[4];
    const float* W_fc = (const float*)d_in[5];
    const float* b_fc = (const float*)d_in[6];
    float* out = (float*)d_out;

    const size_t OFF_WP = 0;
    const size_t OFF_BP = 786432;
    const size_t OFF_A  = 790528;
    const size_t OFF_CS0 = OFF_A + (size_t)(ARENA_ELEMS + ARENA_PAD) * 2;
    const size_t OFF_CS1 = OFF_CS0 + 33554432;
    const size_t OFF_CR  = OFF_CS1 + 33554432;
    const size_t OFF_CTR = OFF_CR + 1024;
    const size_t NEEDED  = OFF_CTR + 64;
    if (ws_size < NEEDED) return;

    char* ws = (char*)d_ws;
    unsigned short* Wp    = (unsigned short*)(ws + OFF_WP);
    float* bp             = (float*)(ws + OFF_BP);
    unsigned short* arena = (unsigned short*)(ws + OFF_A);
    float* cs0            = (float*)(ws + OFF_CS0);
    float* cs1            = (float*)(ws + OFF_CS1);
    float* c_root         = (float*)(ws + OFF_CR);
    unsigned* ctr         = (unsigned*)(ws + OFF_CTR);

    pack_kernel<<<dim3(2048), dim3(256), 0, stream>>>(
        x, W_ih, b_ih, W_hh, b_hh, Wp, bp, arena, ctr);

    // ---- leaf (l=16): n=65536, K=128 -> A(15), cs0 (proven 128-kernel)
    gemm_lstm_kernel<IN_DIM><<<dim3(NLEAF / BM, 8), dim3(256), 0, stream>>>(
        arena + offA(16), NLEAF, Wp, bp,
        nullptr, 1, arena + offA(15), cs0);

    // ---- l=15, l=14: 8-phase 256-row kernel
    gemm_lstm8p_kernel<KTOT><<<dim3(128, 4), dim3(512), 0, stream>>>(
        arena + offA(15), 32768, Wp, bp, cs0, arena + offA(14), cs1);
    gemm_lstm8p_kernel<KTOT><<<dim3(64, 4), dim3(512), 0, stream>>>(
        arena + offA(14), 16384, Wp, bp, cs1, arena + offA(13), cs0);

    // ---- l=13..8: proven 128-kernel
    float* cs_in = cs0; float* cs_out = cs1;
    for (int l = 13; l >= 8; --l){
        int n = 1 << l;
        gemm_lstm_kernel<KTOT><<<dim3(n / BM, 8), dim3(256), 0, stream>>>(
            arena + offA(l), n, Wp, bp,
            cs_in, 0, arena + offA(l - 1), cs_out);
        float* t = cs_in; cs_in = cs_out; cs_out = t;
    }

    // ---- tail: levels 7..0 + FC (8 co-resident blocks, fence-free barrier)
    tail_kernel<<<dim3(NBLK_TAIL), dim3(256), 0, stream>>>(
        arena, Wp, bp, cs_in, cs_out, c_root, W_fc, b_fc, out, ctr);
}

// Round 17
// 197.494 us; speedup vs baseline: 1.1989x; 1.0491x over previous
//
#include <hip/hip_runtime.h>
#include <hip/hip_bf16.h>
#include <cstddef>

#define IN_DIM 128
#define MEM 256
#define KTOT 384
#define NLEAF 65536
#define NBLK_TAIL 8

typedef float f32x4 __attribute__((ext_vector_type(4)));
typedef short s16x8 __attribute__((ext_vector_type(8)));
typedef unsigned int u32;

__device__ inline unsigned short f2bf(float f){
    unsigned int u = __builtin_bit_cast(unsigned int, f);
    u += 0x7fff + ((u >> 16) & 1);
    return (unsigned short)(u >> 16);
}

__device__ inline void gld_lds16(const void* g, void* l){
    __builtin_amdgcn_global_load_lds((const __attribute__((address_space(1))) u32*)g,
                                     (__attribute__((address_space(3))) u32*)l, 16, 0, 0);
}
// device-coherent (SC0|SC1): read from coherence point, bypass stale L1/L2
__device__ inline void gld_lds16_dev(const void* g, void* l){
    __builtin_amdgcn_global_load_lds((const __attribute__((address_space(1))) u32*)g,
                                     (__attribute__((address_space(3))) u32*)l, 16, 0, 17);
}
// write-through device-coherent stores
__device__ inline void st16_dev(unsigned short* p, unsigned short v){
    unsigned int vv = v;
    asm volatile("global_store_short %0, %1, off sc0 sc1" :: "v"(p), "v"(vv) : "memory");
}
__device__ inline void st32_dev(float* p, float v){
    asm volatile("global_store_dword %0, %1, off sc0 sc1" :: "v"(p), "v"(v) : "memory");
}

__device__ inline float fsigm(float x){
    return __builtin_amdgcn_rcpf(1.f + __expf(-x));
}
__device__ inline float ftanh(float x){
    return 2.f * __builtin_amdgcn_rcpf(1.f + __expf(-2.f * x)) - 1.f;
}

// A-arena element offsets: leaf (l=16) at 0, stride 128; levels 15..0 stride 384.
__host__ __device__ inline size_t offA(int l){
    if (l == 16) return 0;
    return 8388608u + 384u * (65536u - (1u << (l + 1)));
}
#define ARENA_ELEMS 33554048u
#define ARENA_PAD   65536u

// FENCE-FREE grid barrier (8 co-resident blocks): all cross-block data flows via
// coherence point (sc0sc1 stores / aux=17 loads / agent atomics) -> no wbl2/inv.
__device__ inline void grid_barrier_nf(unsigned* ctr, unsigned target){
    asm volatile("s_waitcnt vmcnt(0)" ::: "memory");
    __syncthreads();
    if (threadIdx.x == 0){
        __hip_atomic_fetch_add(ctr, 1u, __ATOMIC_RELAXED, __HIP_MEMORY_SCOPE_AGENT);
        while (__hip_atomic_load(ctr, __ATOMIC_RELAXED, __HIP_MEMORY_SCOPE_AGENT) < target)
            __builtin_amdgcn_s_sleep(2);
    }
    __syncthreads();
}

// ---------------- fused pack: W (+bias, +ctr reset) and all x rows -> bf16 arena
__global__ void pack_kernel(const float* __restrict__ x,
                            const float* __restrict__ W_ih, const float* __restrict__ b_ih,
                            const float* __restrict__ W_hh, const float* __restrict__ b_hh,
                            unsigned short* __restrict__ Wp, float* __restrict__ bp,
                            unsigned short* __restrict__ Aarena, unsigned* __restrict__ ctr){
    const int stride = gridDim.x * blockDim.x;
    const int tid0 = blockIdx.x * blockDim.x + threadIdx.x;
    if (tid0 == 0){ ctr[0] = 0; }

    for (int g = tid0; g < 1024 * 48; g += stride){
        int row = g / 48, ko = (g - row * 48) * 8;
        const float* s = (ko < IN_DIM) ? (W_ih + (size_t)row * IN_DIM + ko)
                                       : (W_hh + (size_t)row * MEM + (ko - IN_DIM));
        f32x4 v0 = *(const f32x4*)s, v1 = *(const f32x4*)(s + 4);
        s16x8 o;
        #pragma unroll
        for (int e = 0; e < 4; ++e){ o[e] = (short)f2bf(v0[e]); o[4+e] = (short)f2bf(v1[e]); }
        *(s16x8*)(Wp + (size_t)row * KTOT + ko) = o;
        if (ko == 0) bp[row] = b_ih[row] + b_hh[row];
    }

    const int TOTAL_G = 131071 * 16;
    for (int g = tid0; g < TOTAL_G; g += stride){
        int i  = g >> 4;
        int ko = (g & 15) * 8;
        int l  = 31 - __clz(i + 1);
        int j  = i + 1 - (1 << l);
        size_t dst = offA(l) + (size_t)j * ((l == 16) ? 128 : 384) + ko;
        const f32x4* s = (const f32x4*)(x + (size_t)i * IN_DIM + ko);
        f32x4 v0 = s[0], v1 = s[1];
        s16x8 o;
        #pragma unroll
        for (int e = 0; e < 4; ++e){ o[e] = (short)f2bf(v0[e]); o[4+e] = (short)f2bf(v1[e]); }
        *(s16x8*)(Aarena + dst) = o;
    }
}

// ================= 8-phase-style 256-row GEMM + LSTM + pair-sum (l15, l14) — frozen =================
template<int NK>
__global__ __launch_bounds__(512, 1) void gemm_lstm8p_kernel(
    const unsigned short* __restrict__ A, int n,
    const unsigned short* __restrict__ Wp, const float* __restrict__ bp,
    const float* __restrict__ csum_in,
    unsigned short* __restrict__ A_next, float* __restrict__ csum_out)
{
    __shared__ __align__(16) unsigned short As[2][2][128 * 64];   // [buf][half] 64 KB
    __shared__ __align__(16) unsigned short Bs[2][2][128 * 64];   // 64 KB

    const int tid  = threadIdx.x;
    const int lane = tid & 63;
    const int wid  = tid >> 6;        // 0..7
    const int wm   = wid >> 2;        // A row-half (128 rows)
    const int wn   = wid & 3;         // mem 16-col group
    const int row0 = blockIdx.x * 256;
    const int m0   = blockIdx.y * 64;
    const int mg   = m0 + wn * 16 + (lane & 15);

    auto stageA = [&](int kt, int h){
        #pragma unroll
        for (int i = 0; i < 2; ++i){
            int p  = i * 512 + tid;
            int r  = p >> 3;
            int ls = (p & 7) ^ (r & 7);
            gld_lds16(A + (size_t)(row0 + h * 128 + r) * NK + kt * 64 + ls * 8,
                      (char*)As[kt & 1][h] + (size_t)(i * 512 + wid * 64) * 16);
        }
    };
    auto stageB = [&](int kt, int h){
        #pragma unroll
        for (int i = 0; i < 2; ++i){
            int p  = i * 512 + tid;
            int r  = p >> 3;
            int b  = h * 128 + r;
            int grow = (b >> 6) * 256 + m0 + (b & 63);
            int ls = (p & 7) ^ (r & 7);
            gld_lds16(Wp + (size_t)grow * KTOT + kt * 64 + ls * 8,
                      (char*)Bs[kt & 1][h] + (size_t)(i * 512 + wid * 64) * 16);
        }
    };

    f32x4 acc[8][4];
    #pragma unroll
    for (int r = 0; r < 8; ++r)
        #pragma unroll
        for (int q = 0; q < 4; ++q)
            acc[r][q] = (f32x4){0.f, 0.f, 0.f, 0.f};

    constexpr int nkt = NK / 64;
    stageA(0, 0); stageA(0, 1); stageB(0, 0);
    if (nkt > 1) stageB(1, 0);
    stageB(0, 1);

    s16x8 bfr[2][2];

    #pragma unroll
    for (int t = 0; t < nkt; ++t){
        const unsigned short* Ab = As[t & 1][wm];
        const unsigned short* Bb0 = Bs[t & 1][0];
        const unsigned short* Bb1 = Bs[t & 1][1];

        if (t + 1 < nkt) { asm volatile("s_waitcnt vmcnt(4)" ::: "memory"); }
        else             { asm volatile("s_waitcnt vmcnt(2)" ::: "memory"); }
        __builtin_amdgcn_s_barrier();
        asm volatile("" ::: "memory");

        #pragma unroll
        for (int rh = 0; rh < 2; ++rh){
            s16x8 a[4][2];
            #pragma unroll
            for (int j = 0; j < 4; ++j)
                #pragma unroll
                for (int ks = 0; ks < 2; ++ks){
                    int kb = (((ks * 4 + (lane >> 4)) ^ (lane & 7))) * 8;
                    a[j][ks] = *(const s16x8*)(Ab + (size_t)(rh * 64 + j * 16 + (lane & 15)) * 64 + kb);
                }
            if (rh == 0){
                #pragma unroll
                for (int q2 = 0; q2 < 2; ++q2)
                    #pragma unroll
                    for (int ks = 0; ks < 2; ++ks){
                        int kb = (((ks * 4 + (lane >> 4)) ^ (lane & 7))) * 8;
                        bfr[q2][ks] = *(const s16x8*)(Bb0 + (size_t)(q2 * 64 + wn * 16 + (lane & 15)) * 64 + kb);
                    }
                if (t + 1 < nkt) stageA(t + 1, 0);
            } else {
                if (t + 1 < nkt) stageA(t + 1, 1);
            }
            __builtin_amdgcn_s_setprio(1);
            #pragma unroll
            for (int j = 0; j < 4; ++j)
                #pragma unroll
                for (int q2 = 0; q2 < 2; ++q2)
                    #pragma unroll
                    for (int ks = 0; ks < 2; ++ks)
                        acc[rh * 4 + j][q2] = __builtin_amdgcn_mfma_f32_16x16x32_bf16(
                            a[j][ks], bfr[q2][ks], acc[rh * 4 + j][q2], 0, 0, 0);
            __builtin_amdgcn_s_setprio(0);
        }

        if (t + 1 < nkt) { asm volatile("s_waitcnt vmcnt(4)" ::: "memory"); }
        else             { asm volatile("s_waitcnt vmcnt(0)" ::: "memory"); }
        __builtin_amdgcn_s_barrier();
        asm volatile("" ::: "memory");

        #pragma unroll
        for (int rh = 0; rh < 2; ++rh){
            s16x8 a[4][2];
            #pragma unroll
            for (int j = 0; j < 4; ++j)
                #pragma unroll
                for (int ks = 0; ks < 2; ++ks){
                    int kb = (((ks * 4 + (lane >> 4)) ^ (lane & 7))) * 8;
                    a[j][ks] = *(const s16x8*)(Ab + (size_t)(rh * 64 + j * 16 + (lane & 15)) * 64 + kb);
                }
            if (rh == 0){
                #pragma unroll
                for (int q2 = 0; q2 < 2; ++q2)
                    #pragma unroll
                    for (int ks = 0; ks < 2; ++ks){
                        int kb = (((ks * 4 + (lane >> 4)) ^ (lane & 7))) * 8;
                        bfr[q2][ks] = *(const s16x8*)(Bb1 + (size_t)(q2 * 64 + wn * 16 + (lane & 15)) * 64 + kb);
                    }
                if (t + 2 < nkt) stageB(t + 2, 0);
            } else {
                if (t + 1 < nkt) stageB(t + 1, 1);
            }
            __builtin_amdgcn_s_setprio(1);
            #pragma unroll
            for (int j = 0; j < 4; ++j)
                #pragma unroll
                for (int q2 = 0; q2 < 2; ++q2)
                    #pragma unroll
                    for (int ks = 0; ks < 2; ++ks)
                        acc[rh * 4 + j][2 + q2] = __builtin_amdgcn_mfma_f32_16x16x32_bf16(
                            a[j][ks], bfr[q2][ks], acc[rh * 4 + j][2 + q2], 0, 0, 0);
            __builtin_amdgcn_s_setprio(0);
        }
        __builtin_amdgcn_s_barrier();
        asm volatile("" ::: "memory");
    }

    const float b0 = bp[0 * 256 + mg];
    const float b1 = bp[1 * 256 + mg];
    const float b2 = bp[2 * 256 + mg];
    const float b3 = bp[3 * 256 + mg];
    #pragma unroll
    for (int r = 0; r < 8; ++r){
        const int base = row0 + wm * 128 + r * 16 + (lane >> 4) * 4;
        float cpre[4];
        #pragma unroll
        for (int e = 0; e < 4; ++e)
            cpre[e] = csum_in[(size_t)(base + e) * MEM + mg];
        float cn[4], hn[4];
        #pragma unroll
        for (int e = 0; e < 4; ++e){
            float iv = acc[r][0][e] + b0;
            float fv = acc[r][1][e] + b1;
            float gv = acc[r][2][e] + b2;
            float ov = acc[r][3][e] + b3;
            float c  = fsigm(fv) * cpre[e] + fsigm(iv) * ftanh(gv);
            cn[e] = c;
            hn[e] = fsigm(ov) * ftanh(c);
        }
        int p0 = base >> 1;
        A_next[(size_t)p0 * KTOT + IN_DIM + mg] = f2bf(hn[0] + hn[1]);
        csum_out[(size_t)p0 * MEM + mg] = cn[0] + cn[1];
        A_next[(size_t)(p0 + 1) * KTOT + IN_DIM + mg] = f2bf(hn[2] + hn[3]);
        csum_out[(size_t)(p0 + 1) * MEM + mg] = cn[2] + cn[3];
    }
}

// ================= proven GEMM + LSTM + pair-sum, templated tile height =================
// RB = row-fragments per wave; BM = 32*RB. RB=4: the verbatim round-8 kernel (64 KB LDS,
// 2 blocks/CU). RB=2: BM=64, 48 KB LDS -> 3 blocks/CU, half per-thread epilogue —
// for the epilogue-bound leaf and the parallelism-starved small levels.
#define KC 64

template<int NK, int RB>
__global__ __launch_bounds__(256) void gemm_lstm_kernel(
    const unsigned short* __restrict__ A, int n,
    const unsigned short* __restrict__ Wp, const float* __restrict__ bp,
    const float* __restrict__ csum_in, int leaf,
    unsigned short* __restrict__ A_next, float* __restrict__ csum_out)
{
    constexpr int BM = RB * 32;
    __shared__ __align__(16) unsigned short As[2][BM * KC];
    __shared__ __align__(16) unsigned short Bs[2][128 * KC];

    const int tid  = threadIdx.x;
    const int lane = tid & 63;
    const int wid  = tid >> 6;
    const int wm   = wid >> 1;
    const int wc   = wid & 1;
    const int row0 = blockIdx.x * BM;
    const int m0   = blockIdx.y * 32;

    const int srow = lane >> 3;
    const int scol = ((lane & 7) ^ srow) * 8;

    const int mg = m0 + wc * 16 + (lane & 15);

    const float b0 = bp[0 * 256 + mg];
    const float b1 = bp[1 * 256 + mg];
    const float b2 = bp[2 * 256 + mg];
    const float b3 = bp[3 * 256 + mg];
    float cpre[RB][4];
    if (!leaf){
        #pragma unroll
        for (int r = 0; r < RB; ++r){
            const int base = row0 + wm * (RB * 16) + r * 16 + (lane >> 4) * 4;
            #pragma unroll
            for (int e = 0; e < 4; ++e)
                cpre[r][e] = csum_in[(size_t)(base + e) * MEM + mg];
        }
    } else {
        #pragma unroll
        for (int r = 0; r < RB; ++r)
            #pragma unroll
            for (int e = 0; e < 4; ++e) cpre[r][e] = 0.f;
    }

    f32x4 acc[RB][4];
    #pragma unroll
    for (int r = 0; r < RB; ++r)
        #pragma unroll
        for (int q = 0; q < 4; ++q)
            acc[r][q] = (f32x4){0.f, 0.f, 0.f, 0.f};

    auto stage = [&](int d, int kk){
        char* asb = (char*)As[d];
        char* bsb = (char*)Bs[d];
        #pragma unroll
        for (int q = 0; q < RB; ++q){
            int t = wid * RB + q;
            int r = t * 8 + srow;
            gld_lds16(A + (size_t)(row0 + r) * NK + kk + scol, asb + t * 1024);
        }
        #pragma unroll
        for (int q = 0; q < 4; ++q){
            int t = wid * 4 + q;
            int b = t * 8 + srow;
            int grow = (b >> 5) * 256 + m0 + (b & 31);
            gld_lds16(Wp + (size_t)grow * KTOT + kk + scol, bsb + t * 1024);
        }
    };

    constexpr int nIter = NK / KC;
    stage(0, 0);
    int buf = 0;
    #pragma unroll
    for (int it = 0; it < nIter; ++it){
        if (it + 1 < nIter){
            stage(buf ^ 1, (it + 1) * KC);
            if constexpr (RB == 4) asm volatile("s_waitcnt vmcnt(8)" ::: "memory");
            else                   asm volatile("s_waitcnt vmcnt(6)" ::: "memory");
        } else {
            asm volatile("s_waitcnt vmcnt(0)" ::: "memory");
        }
        __builtin_amdgcn_s_barrier();
        const unsigned short* Ab = As[buf];
        const unsigned short* Bb = Bs[buf];
        #pragma unroll
        for (int ks = 0; ks < 2; ++ks){
            const int slot = ks * 4 + (lane >> 4);
            const int kb = (slot ^ (lane & 7)) * 8;
            s16x8 a[RB], b[4];
            #pragma unroll
            for (int r = 0; r < RB; ++r)
                a[r] = *(const s16x8*)(Ab + (wm * (RB * 16) + r * 16 + (lane & 15)) * KC + kb);
            #pragma unroll
            for (int q = 0; q < 4; ++q)
                b[q] = *(const s16x8*)(Bb + (q * 32 + wc * 16 + (lane & 15)) * KC + kb);
            #pragma unroll
            for (int r = 0; r < RB; ++r)
                #pragma unroll
                for (int q = 0; q < 4; ++q)
                    acc[r][q] = __builtin_amdgcn_mfma_f32_16x16x32_bf16(a[r], b[q], acc[r][q], 0, 0, 0);
        }
        __builtin_amdgcn_s_barrier();
        buf ^= 1;
    }

    #pragma unroll
    for (int r = 0; r < RB; ++r){
        const int base = row0 + wm * (RB * 16) + r * 16 + (lane >> 4) * 4;
        float cn[4], hn[4];
        #pragma unroll
        for (int e = 0; e < 4; ++e){
            float iv = acc[r][0][e] + b0;
            float fv = acc[r][1][e] + b1;
            float gv = acc[r][2][e] + b2;
            float ov = acc[r][3][e] + b3;
            float c  = fsigm(fv) * cpre[r][e] + fsigm(iv) * ftanh(gv);
            cn[e] = c;
            hn[e] = fsigm(ov) * ftanh(c);
        }
        if (base < n){
            int p0 = base >> 1;
            A_next[(size_t)p0 * KTOT + IN_DIM + mg] = f2bf(hn[0] + hn[1]);
            csum_out[(size_t)p0 * MEM + mg] = cn[0] + cn[1];
        }
        if (base + 2 < n){
            int p1 = (base >> 1) + 1;
            A_next[(size_t)p1 * KTOT + IN_DIM + mg] = f2bf(hn[2] + hn[3]);
            csum_out[(size_t)p1 * MEM + mg] = cn[2] + cn[3];
        }
    }
}

// ---------------- tail: levels 7..0 + FC fused, 8 blocks, fence-free barrier (frozen)
__global__ __launch_bounds__(256) void tail_kernel(
    const unsigned short* __restrict__ arena,
    const unsigned short* __restrict__ Wp, const float* __restrict__ bp,
    float* cs_in, float* cs_out,
    float* __restrict__ c_root,
    const float* __restrict__ W_fc, const float* __restrict__ b_fc,
    float* __restrict__ out, unsigned* __restrict__ ctr)
{
    __shared__ __align__(16) unsigned short WpL[128 * KTOT];   // 96 KB
    __shared__ __align__(16) unsigned short AL[64 * KTOT];     // 48 KB

    const int tid  = threadIdx.x;
    const int lane = tid & 63;
    const int wid  = tid >> 6;
    const int wm   = wid >> 1;
    const int wc   = wid & 1;
    const int m0   = blockIdx.x * 32;
    const int mg   = m0 + wc * 16 + (lane & 15);

    #pragma unroll
    for (int i = 0; i < 24; ++i){
        int p0 = wid * 1536 + i * 64;
        int p  = p0 + lane;
        int lrow  = p / 48;
        int pslot = p % 48;
        int lslot = pslot ^ (lrow & 7);
        int grow  = (lrow >> 5) * 256 + m0 + (lrow & 31);
        gld_lds16(Wp + (size_t)grow * KTOT + lslot * 8, (char*)WpL + (size_t)p0 * 16);
    }

    const float b0 = bp[0 * 256 + mg];
    const float b1 = bp[1 * 256 + mg];
    const float b2 = bp[2 * 256 + mg];
    const float b3 = bp[3 * 256 + mg];

    asm volatile("s_waitcnt vmcnt(0)" ::: "memory");
    __builtin_amdgcn_s_barrier();

    unsigned gen = 0;
    for (int l = 7; l >= 0; --l){
        const int n = 1 << l;
        const unsigned short* Al = arena + offA(l);
        const int nhalf = (n > 64) ? (n >> 6) : 1;

        for (int h = 0; h < nhalf; ++h){
            const int r0 = h * 64;
            const int rows = (n < 64) ? n : 64;

            const int nslots = rows * 48;
            for (int t = 0; t * 256 < nslots; ++t){
                int pbase = t * 256 + wid * 64;
                int p = pbase + lane;
                if (p < nslots){
                    int row   = p / 48;
                    int pslot = p - row * 48;
                    int lslot = pslot ^ (row & 7);
                    gld_lds16_dev(Al + (size_t)(r0 + row) * KTOT + lslot * 8,
                                  (char*)AL + (size_t)pbase * 16);
                }
            }

            float cpre[2][4];
            #pragma unroll
            for (int r = 0; r < 2; ++r){
                const int base = r0 + wm * 32 + r * 16 + (lane >> 4) * 4;
                #pragma unroll
                for (int e = 0; e < 4; ++e)
                    cpre[r][e] = __hip_atomic_load(&cs_in[(size_t)(base + e) * MEM + mg],
                                                   __ATOMIC_RELAXED, __HIP_MEMORY_SCOPE_AGENT);
            }

            asm volatile("s_waitcnt vmcnt(0)" ::: "memory");
            __builtin_amdgcn_s_barrier();

            f32x4 acc[2][4];
            #pragma unroll
            for (int r = 0; r < 2; ++r)
                #pragma unroll
                for (int q = 0; q < 4; ++q)
                    acc[r][q] = (f32x4){0.f, 0.f, 0.f, 0.f};

            #pragma unroll
            for (int kc = 0; kc < 12; ++kc){
                const int ls = kc * 4 + (lane >> 4);
                const int kb = (ls ^ (lane & 7)) * 8;
                s16x8 a[2], b[4];
                #pragma unroll
                for (int r = 0; r < 2; ++r)
                    a[r] = *(const s16x8*)(AL + (size_t)(wm * 32 + r * 16 + (lane & 15)) * KTOT + kb);
                #pragma unroll
                for (int q = 0; q < 4; ++q)
                    b[q] = *(const s16x8*)(WpL + (q * 32 + wc * 16 + (lane & 15)) * KTOT + kb);
                #pragma unroll
                for (int r = 0; r < 2; ++r)
                    #pragma unroll
                    for (int q = 0; q < 4; ++q)
                        acc[r][q] = __builtin_amdgcn_mfma_f32_16x16x32_bf16(a[r], b[q], acc[r][q], 0, 0, 0);
            }

            #pragma unroll
            for (int r = 0; r < 2; ++r){
                const int base = r0 + wm * 32 + r * 16 + (lane >> 4) * 4;
                float cn[4], hn[4];
                #pragma unroll
                for (int e = 0; e < 4; ++e){
                    float iv = acc[r][0][e] + b0;
                    float fv = acc[r][1][e] + b1;
                    float gv = acc[r][2][e] + b2;
                    float ov = acc[r][3][e] + b3;
                    float c  = fsigm(fv) * cpre[r][e] + fsigm(iv) * ftanh(gv);
                    cn[e] = c;
                    hn[e] = fsigm(ov) * ftanh(c);
                }
                if (l == 0){
                    if (base == 0) st32_dev(&c_root[mg], cn[0]);
                } else {
                    unsigned short* A_next = (unsigned short*)arena + offA(l - 1);
                    if (base < n){
                        int p0 = base >> 1;
                        st16_dev(&A_next[(size_t)p0 * KTOT + IN_DIM + mg], f2bf(hn[0] + hn[1]));
                        st32_dev(&cs_out[(size_t)p0 * MEM + mg], cn[0] + cn[1]);
                    }
                    if (base + 2 < n){
                        int p1 = (base >> 1) + 1;
                        st16_dev(&A_next[(size_t)p1 * KTOT + IN_DIM + mg], f2bf(hn[2] + hn[3]));
                        st32_dev(&cs_out[(size_t)p1 * MEM + mg], cn[2] + cn[3]);
                    }
                }
            }
            __builtin_amdgcn_s_barrier();
        }

        float* t = cs_in; cs_in = cs_out; cs_out = t;
        ++gen;
        grid_barrier_nf(ctr, (unsigned)(NBLK_TAIL * gen));
    }

    if (blockIdx.x == 0){
        int w = wid;
        for (int cls = w * 3; cls < w * 3 + 3; ++cls){
            float s = 0.f;
            for (int m = lane; m < 256; m += 64){
                float cr = __hip_atomic_load(&c_root[m], __ATOMIC_RELAXED, __HIP_MEMORY_SCOPE_AGENT);
                s += cr * W_fc[cls * 256 + m];
            }
            #pragma unroll
            for (int off = 32; off; off >>= 1)
                s += __shfl_down(s, off, 64);
            if (lane == 0) out[cls] = s + b_fc[cls];
        }
    }
}

extern "C" void kernel_launch(void* const* d_in, const int* in_sizes, int n_in,
                              void* d_out, int out_size, void* d_ws, size_t ws_size,
                              hipStream_t stream)
{
    const float* x    = (const float*)d_in[0];
    const float* W_ih = (const float*)d_in[1];
    const float* b_ih = (const float*)d_in[2];
    const float* W_hh = (const float*)d_in[3];
    const float* b_hh = (const float*)d_in[4];
    const float* W_fc = (const float*)d_in[5];
    const float* b_fc = (const float*)d_in[6];
    float* out = (float*)d_out;

    const size_t OFF_WP = 0;
    const size_t OFF_BP = 786432;
    const size_t OFF_A  = 790528;
    const size_t OFF_CS0 = OFF_A + (size_t)(ARENA_ELEMS + ARENA_PAD) * 2;
    const size_t OFF_CS1 = OFF_CS0 + 33554432;
    const size_t OFF_CR  = OFF_CS1 + 33554432;
    const size_t OFF_CTR = OFF_CR + 1024;
    const size_t NEEDED  = OFF_CTR + 64;
    if (ws_size < NEEDED) return;

    char* ws = (char*)d_ws;
    unsigned short* Wp    = (unsigned short*)(ws + OFF_WP);
    float* bp             = (float*)(ws + OFF_BP);
    unsigned short* arena = (unsigned short*)(ws + OFF_A);
    float* cs0            = (float*)(ws + OFF_CS0);
    float* cs1            = (float*)(ws + OFF_CS1);
    float* c_root         = (float*)(ws + OFF_CR);
    unsigned* ctr         = (unsigned*)(ws + OFF_CTR);

    pack_kernel<<<dim3(2048), dim3(256), 0, stream>>>(
        x, W_ih, b_ih, W_hh, b_hh, Wp, bp, arena, ctr);

    // ---- leaf (l=16): n=65536, K=128 -> A(15), cs0. RB=2: 48 KB LDS, 3 blocks/CU,
    // half per-thread epilogue (leaf is epilogue-trans-bound).
    gemm_lstm_kernel<IN_DIM, 2><<<dim3(NLEAF / 64, 8), dim3(256), 0, stream>>>(
        arena + offA(16), NLEAF, Wp, bp,
        nullptr, 1, arena + offA(15), cs0);

    // ---- l=15, l=14: 8-phase 256-row kernel (frozen)
    gemm_lstm8p_kernel<KTOT><<<dim3(128, 4), dim3(512), 0, stream>>>(
        arena + offA(15), 32768, Wp, bp, cs0, arena + offA(14), cs1);
    gemm_lstm8p_kernel<KTOT><<<dim3(64, 4), dim3(512), 0, stream>>>(
        arena + offA(14), 16384, Wp, bp, cs1, arena + offA(13), cs0);

    // ---- l=13: RB=4 (512 blocks, GEMM-bound)
    gemm_lstm_kernel<KTOT, 4><<<dim3(64, 8), dim3(256), 0, stream>>>(
        arena + offA(13), 8192, Wp, bp, cs0, 0, arena + offA(12), cs1);

    // ---- l=12..8: RB=2 (doubles grid at parallelism-starved sizes)
    float* cs_in = cs1; float* cs_out = cs0;
    for (int l = 12; l >= 8; --l){
        int n = 1 << l;
        gemm_lstm_kernel<KTOT, 2><<<dim3(n / 64, 8), dim3(256), 0, stream>>>(
            arena + offA(l), n, Wp, bp,
            cs_in, 0, arena + offA(l - 1), cs_out);
        float* t = cs_in; cs_in = cs_out; cs_out = t;
    }

    // ---- tail: levels 7..0 + FC (8 co-resident blocks, fence-free barrier)
    tail_kernel<<<dim3(NBLK_TAIL), dim3(256), 0, stream>>>(
        arena, Wp, bp, cs_in, cs_out, c_root, W_fc, b_fc, out, ctr);
}

// Round 18
// 193.856 us; speedup vs baseline: 1.2214x; 1.0188x over previous
//
#include <hip/hip_runtime.h>
#include <hip/hip_bf16.h>
#include <cstddef>

#define IN_DIM 128
#define MEM 256
#define KTOT 384
#define NLEAF 65536
#define NBLK_TAIL 8

typedef float f32x4 __attribute__((ext_vector_type(4)));
typedef short s16x8 __attribute__((ext_vector_type(8)));
typedef unsigned int u32;

__device__ inline unsigned short f2bf(float f){
    unsigned int u = __builtin_bit_cast(unsigned int, f);
    u += 0x7fff + ((u >> 16) & 1);
    return (unsigned short)(u >> 16);
}

__device__ inline void gld_lds16(const void* g, void* l){
    __builtin_amdgcn_global_load_lds((const __attribute__((address_space(1))) u32*)g,
                                     (__attribute__((address_space(3))) u32*)l, 16, 0, 0);
}
// device-coherent (SC0|SC1): read from coherence point, bypass stale L1/L2
__device__ inline void gld_lds16_dev(const void* g, void* l){
    __builtin_amdgcn_global_load_lds((const __attribute__((address_space(1))) u32*)g,
                                     (__attribute__((address_space(3))) u32*)l, 16, 0, 17);
}
// write-through device-coherent stores
__device__ inline void st16_dev(unsigned short* p, unsigned short v){
    unsigned int vv = v;
    asm volatile("global_store_short %0, %1, off sc0 sc1" :: "v"(p), "v"(vv) : "memory");
}
__device__ inline void st32_dev(float* p, float v){
    asm volatile("global_store_dword %0, %1, off sc0 sc1" :: "v"(p), "v"(v) : "memory");
}

__device__ inline float fsigm(float x){
    return __builtin_amdgcn_rcpf(1.f + __expf(-x));
}
__device__ inline float ftanh(float x){
    return 2.f * __builtin_amdgcn_rcpf(1.f + __expf(-2.f * x)) - 1.f;
}

// A-arena element offsets: leaf (l=16) at 0, stride 128; levels 15..0 stride 384.
__host__ __device__ inline size_t offA(int l){
    if (l == 16) return 0;
    return 8388608u + 384u * (65536u - (1u << (l + 1)));
}
#define ARENA_ELEMS 33554048u
#define ARENA_PAD   65536u

// FENCE-FREE grid barrier (8 co-resident blocks): all cross-block data flows via
// coherence point (sc0sc1 stores / aux=17 loads / agent atomics) -> no wbl2/inv.
__device__ inline void grid_barrier_nf(unsigned* ctr, unsigned target){
    asm volatile("s_waitcnt vmcnt(0)" ::: "memory");
    __syncthreads();
    if (threadIdx.x == 0){
        __hip_atomic_fetch_add(ctr, 1u, __ATOMIC_RELAXED, __HIP_MEMORY_SCOPE_AGENT);
        while (__hip_atomic_load(ctr, __ATOMIC_RELAXED, __HIP_MEMORY_SCOPE_AGENT) < target)
            __builtin_amdgcn_s_sleep(2);
    }
    __syncthreads();
}

// ---------------- fused pack: W (+bias, +ctr reset) and all x rows -> bf16 arena
__global__ void pack_kernel(const float* __restrict__ x,
                            const float* __restrict__ W_ih, const float* __restrict__ b_ih,
                            const float* __restrict__ W_hh, const float* __restrict__ b_hh,
                            unsigned short* __restrict__ Wp, float* __restrict__ bp,
                            unsigned short* __restrict__ Aarena, unsigned* __restrict__ ctr){
    const int stride = gridDim.x * blockDim.x;
    const int tid0 = blockIdx.x * blockDim.x + threadIdx.x;
    if (tid0 == 0){ ctr[0] = 0; }

    for (int g = tid0; g < 1024 * 48; g += stride){
        int row = g / 48, ko = (g - row * 48) * 8;
        const float* s = (ko < IN_DIM) ? (W_ih + (size_t)row * IN_DIM + ko)
                                       : (W_hh + (size_t)row * MEM + (ko - IN_DIM));
        f32x4 v0 = *(const f32x4*)s, v1 = *(const f32x4*)(s + 4);
        s16x8 o;
        #pragma unroll
        for (int e = 0; e < 4; ++e){ o[e] = (short)f2bf(v0[e]); o[4+e] = (short)f2bf(v1[e]); }
        *(s16x8*)(Wp + (size_t)row * KTOT + ko) = o;
        if (ko == 0) bp[row] = b_ih[row] + b_hh[row];
    }

    const int TOTAL_G = 131071 * 16;
    for (int g = tid0; g < TOTAL_G; g += stride){
        int i  = g >> 4;
        int ko = (g & 15) * 8;
        int l  = 31 - __clz(i + 1);
        int j  = i + 1 - (1 << l);
        size_t dst = offA(l) + (size_t)j * ((l == 16) ? 128 : 384) + ko;
        const f32x4* s = (const f32x4*)(x + (size_t)i * IN_DIM + ko);
        f32x4 v0 = s[0], v1 = s[1];
        s16x8 o;
        #pragma unroll
        for (int e = 0; e < 4; ++e){ o[e] = (short)f2bf(v0[e]); o[4+e] = (short)f2bf(v1[e]); }
        *(s16x8*)(Aarena + dst) = o;
    }
}

// ================= 8-phase-style 256-row GEMM + LSTM + pair-sum (l15, l14) — frozen =================
template<int NK>
__global__ __launch_bounds__(512, 1) void gemm_lstm8p_kernel(
    const unsigned short* __restrict__ A, int n,
    const unsigned short* __restrict__ Wp, const float* __restrict__ bp,
    const float* __restrict__ csum_in,
    unsigned short* __restrict__ A_next, float* __restrict__ csum_out)
{
    __shared__ __align__(16) unsigned short As[2][2][128 * 64];   // [buf][half] 64 KB
    __shared__ __align__(16) unsigned short Bs[2][2][128 * 64];   // 64 KB

    const int tid  = threadIdx.x;
    const int lane = tid & 63;
    const int wid  = tid >> 6;        // 0..7
    const int wm   = wid >> 2;        // A row-half (128 rows)
    const int wn   = wid & 3;         // mem 16-col group
    const int row0 = blockIdx.x * 256;
    const int m0   = blockIdx.y * 64;
    const int mg   = m0 + wn * 16 + (lane & 15);

    auto stageA = [&](int kt, int h){
        #pragma unroll
        for (int i = 0; i < 2; ++i){
            int p  = i * 512 + tid;
            int r  = p >> 3;
            int ls = (p & 7) ^ (r & 7);
            gld_lds16(A + (size_t)(row0 + h * 128 + r) * NK + kt * 64 + ls * 8,
                      (char*)As[kt & 1][h] + (size_t)(i * 512 + wid * 64) * 16);
        }
    };
    auto stageB = [&](int kt, int h){
        #pragma unroll
        for (int i = 0; i < 2; ++i){
            int p  = i * 512 + tid;
            int r  = p >> 3;
            int b  = h * 128 + r;
            int grow = (b >> 6) * 256 + m0 + (b & 63);
            int ls = (p & 7) ^ (r & 7);
            gld_lds16(Wp + (size_t)grow * KTOT + kt * 64 + ls * 8,
                      (char*)Bs[kt & 1][h] + (size_t)(i * 512 + wid * 64) * 16);
        }
    };

    f32x4 acc[8][4];
    #pragma unroll
    for (int r = 0; r < 8; ++r)
        #pragma unroll
        for (int q = 0; q < 4; ++q)
            acc[r][q] = (f32x4){0.f, 0.f, 0.f, 0.f};

    constexpr int nkt = NK / 64;
    stageA(0, 0); stageA(0, 1); stageB(0, 0);
    if (nkt > 1) stageB(1, 0);
    stageB(0, 1);

    s16x8 bfr[2][2];

    #pragma unroll
    for (int t = 0; t < nkt; ++t){
        const unsigned short* Ab = As[t & 1][wm];
        const unsigned short* Bb0 = Bs[t & 1][0];
        const unsigned short* Bb1 = Bs[t & 1][1];

        if (t + 1 < nkt) { asm volatile("s_waitcnt vmcnt(4)" ::: "memory"); }
        else             { asm volatile("s_waitcnt vmcnt(2)" ::: "memory"); }
        __builtin_amdgcn_s_barrier();
        asm volatile("" ::: "memory");

        #pragma unroll
        for (int rh = 0; rh < 2; ++rh){
            s16x8 a[4][2];
            #pragma unroll
            for (int j = 0; j < 4; ++j)
                #pragma unroll
                for (int ks = 0; ks < 2; ++ks){
                    int kb = (((ks * 4 + (lane >> 4)) ^ (lane & 7))) * 8;
                    a[j][ks] = *(const s16x8*)(Ab + (size_t)(rh * 64 + j * 16 + (lane & 15)) * 64 + kb);
                }
            if (rh == 0){
                #pragma unroll
                for (int q2 = 0; q2 < 2; ++q2)
                    #pragma unroll
                    for (int ks = 0; ks < 2; ++ks){
                        int kb = (((ks * 4 + (lane >> 4)) ^ (lane & 7))) * 8;
                        bfr[q2][ks] = *(const s16x8*)(Bb0 + (size_t)(q2 * 64 + wn * 16 + (lane & 15)) * 64 + kb);
                    }
                if (t + 1 < nkt) stageA(t + 1, 0);
            } else {
                if (t + 1 < nkt) stageA(t + 1, 1);
            }
            __builtin_amdgcn_s_setprio(1);
            #pragma unroll
            for (int j = 0; j < 4; ++j)
                #pragma unroll
                for (int q2 = 0; q2 < 2; ++q2)
                    #pragma unroll
                    for (int ks = 0; ks < 2; ++ks)
                        acc[rh * 4 + j][q2] = __builtin_amdgcn_mfma_f32_16x16x32_bf16(
                            a[j][ks], bfr[q2][ks], acc[rh * 4 + j][q2], 0, 0, 0);
            __builtin_amdgcn_s_setprio(0);
        }

        if (t + 1 < nkt) { asm volatile("s_waitcnt vmcnt(4)" ::: "memory"); }
        else             { asm volatile("s_waitcnt vmcnt(0)" ::: "memory"); }
        __builtin_amdgcn_s_barrier();
        asm volatile("" ::: "memory");

        #pragma unroll
        for (int rh = 0; rh < 2; ++rh){
            s16x8 a[4][2];
            #pragma unroll
            for (int j = 0; j < 4; ++j)
                #pragma unroll
                for (int ks = 0; ks < 2; ++ks){
                    int kb = (((ks * 4 + (lane >> 4)) ^ (lane & 7))) * 8;
                    a[j][ks] = *(const s16x8*)(Ab + (size_t)(rh * 64 + j * 16 + (lane & 15)) * 64 + kb);
                }
            if (rh == 0){
                #pragma unroll
                for (int q2 = 0; q2 < 2; ++q2)
                    #pragma unroll
                    for (int ks = 0; ks < 2; ++ks){
                        int kb = (((ks * 4 + (lane >> 4)) ^ (lane & 7))) * 8;
                        bfr[q2][ks] = *(const s16x8*)(Bb1 + (size_t)(q2 * 64 + wn * 16 + (lane & 15)) * 64 + kb);
                    }
                if (t + 2 < nkt) stageB(t + 2, 0);
            } else {
                if (t + 1 < nkt) stageB(t + 1, 1);
            }
            __builtin_amdgcn_s_setprio(1);
            #pragma unroll
            for (int j = 0; j < 4; ++j)
                #pragma unroll
                for (int q2 = 0; q2 < 2; ++q2)
                    #pragma unroll
                    for (int ks = 0; ks < 2; ++ks)
                        acc[rh * 4 + j][2 + q2] = __builtin_amdgcn_mfma_f32_16x16x32_bf16(
                            a[j][ks], bfr[q2][ks], acc[rh * 4 + j][2 + q2], 0, 0, 0);
            __builtin_amdgcn_s_setprio(0);
        }
        __builtin_amdgcn_s_barrier();
        asm volatile("" ::: "memory");
    }

    const float b0 = bp[0 * 256 + mg];
    const float b1 = bp[1 * 256 + mg];
    const float b2 = bp[2 * 256 + mg];
    const float b3 = bp[3 * 256 + mg];
    #pragma unroll
    for (int r = 0; r < 8; ++r){
        const int base = row0 + wm * 128 + r * 16 + (lane >> 4) * 4;
        float cpre[4];
        #pragma unroll
        for (int e = 0; e < 4; ++e)
            cpre[e] = csum_in[(size_t)(base + e) * MEM + mg];
        float cn[4], hn[4];
        #pragma unroll
        for (int e = 0; e < 4; ++e){
            float iv = acc[r][0][e] + b0;
            float fv = acc[r][1][e] + b1;
            float gv = acc[r][2][e] + b2;
            float ov = acc[r][3][e] + b3;
            float c  = fsigm(fv) * cpre[e] + fsigm(iv) * ftanh(gv);
            cn[e] = c;
            hn[e] = fsigm(ov) * ftanh(c);
        }
        int p0 = base >> 1;
        A_next[(size_t)p0 * KTOT + IN_DIM + mg] = f2bf(hn[0] + hn[1]);
        csum_out[(size_t)p0 * MEM + mg] = cn[0] + cn[1];
        A_next[(size_t)(p0 + 1) * KTOT + IN_DIM + mg] = f2bf(hn[2] + hn[3]);
        csum_out[(size_t)(p0 + 1) * MEM + mg] = cn[2] + cn[3];
    }
}

// ================= proven GEMM + LSTM + pair-sum, templated tile height + leaf-DCE =================
// RB = row-fragments per wave (BM = 32*RB). LEAF=true dead-codes the f-gate path (chc==0).
#define KC 64

template<int NK, int RB, bool LEAF>
__global__ __launch_bounds__(256) void gemm_lstm_kernel(
    const unsigned short* __restrict__ A, int n,
    const unsigned short* __restrict__ Wp, const float* __restrict__ bp,
    const float* __restrict__ csum_in,
    unsigned short* __restrict__ A_next, float* __restrict__ csum_out)
{
    constexpr int BM = RB * 32;
    __shared__ __align__(16) unsigned short As[2][BM * KC];
    __shared__ __align__(16) unsigned short Bs[2][128 * KC];

    const int tid  = threadIdx.x;
    const int lane = tid & 63;
    const int wid  = tid >> 6;
    const int wm   = wid >> 1;
    const int wc   = wid & 1;
    const int row0 = blockIdx.x * BM;
    const int m0   = blockIdx.y * 32;

    const int srow = lane >> 3;
    const int scol = ((lane & 7) ^ srow) * 8;

    const int mg = m0 + wc * 16 + (lane & 15);

    const float b0 = bp[0 * 256 + mg];
    const float b1 = LEAF ? 0.f : bp[1 * 256 + mg];
    const float b2 = bp[2 * 256 + mg];
    const float b3 = bp[3 * 256 + mg];
    float cpre[RB][4];
    if (!LEAF){
        #pragma unroll
        for (int r = 0; r < RB; ++r){
            const int base = row0 + wm * (RB * 16) + r * 16 + (lane >> 4) * 4;
            #pragma unroll
            for (int e = 0; e < 4; ++e)
                cpre[r][e] = csum_in[(size_t)(base + e) * MEM + mg];
        }
    }

    f32x4 acc[RB][4];
    #pragma unroll
    for (int r = 0; r < RB; ++r)
        #pragma unroll
        for (int q = 0; q < 4; ++q)
            acc[r][q] = (f32x4){0.f, 0.f, 0.f, 0.f};

    auto stage = [&](int d, int kk){
        char* asb = (char*)As[d];
        char* bsb = (char*)Bs[d];
        #pragma unroll
        for (int q = 0; q < RB; ++q){
            int t = wid * RB + q;
            int r = t * 8 + srow;
            gld_lds16(A + (size_t)(row0 + r) * NK + kk + scol, asb + t * 1024);
        }
        #pragma unroll
        for (int q = 0; q < 4; ++q){
            int t = wid * 4 + q;
            int b = t * 8 + srow;
            int grow = (b >> 5) * 256 + m0 + (b & 31);
            gld_lds16(Wp + (size_t)grow * KTOT + kk + scol, bsb + t * 1024);
        }
    };

    constexpr int nIter = NK / KC;
    stage(0, 0);
    int buf = 0;
    #pragma unroll
    for (int it = 0; it < nIter; ++it){
        if (it + 1 < nIter){
            stage(buf ^ 1, (it + 1) * KC);
            if constexpr (RB == 4) asm volatile("s_waitcnt vmcnt(8)" ::: "memory");
            else                   asm volatile("s_waitcnt vmcnt(6)" ::: "memory");
        } else {
            asm volatile("s_waitcnt vmcnt(0)" ::: "memory");
        }
        __builtin_amdgcn_s_barrier();
        const unsigned short* Ab = As[buf];
        const unsigned short* Bb = Bs[buf];
        #pragma unroll
        for (int ks = 0; ks < 2; ++ks){
            const int slot = ks * 4 + (lane >> 4);
            const int kb = (slot ^ (lane & 7)) * 8;
            s16x8 a[RB], b[4];
            #pragma unroll
            for (int r = 0; r < RB; ++r)
                a[r] = *(const s16x8*)(Ab + (wm * (RB * 16) + r * 16 + (lane & 15)) * KC + kb);
            #pragma unroll
            for (int q = 0; q < 4; ++q)
                b[q] = *(const s16x8*)(Bb + (q * 32 + wc * 16 + (lane & 15)) * KC + kb);
            #pragma unroll
            for (int r = 0; r < RB; ++r)
                #pragma unroll
                for (int q = 0; q < 4; ++q)
                    acc[r][q] = __builtin_amdgcn_mfma_f32_16x16x32_bf16(a[r], b[q], acc[r][q], 0, 0, 0);
        }
        __builtin_amdgcn_s_barrier();
        buf ^= 1;
    }

    #pragma unroll
    for (int r = 0; r < RB; ++r){
        const int base = row0 + wm * (RB * 16) + r * 16 + (lane >> 4) * 4;
        float cn[4], hn[4];
        #pragma unroll
        for (int e = 0; e < 4; ++e){
            float iv = acc[r][0][e] + b0;
            float gv = acc[r][2][e] + b2;
            float ov = acc[r][3][e] + b3;
            float c;
            if (LEAF){
                c = fsigm(iv) * ftanh(gv);                 // f-gate path dead (chc==0)
            } else {
                float fv = acc[r][1][e] + b1;
                c = fsigm(fv) * cpre[r][e] + fsigm(iv) * ftanh(gv);
            }
            cn[e] = c;
            hn[e] = fsigm(ov) * ftanh(c);
        }
        if (base < n){
            int p0 = base >> 1;
            A_next[(size_t)p0 * KTOT + IN_DIM + mg] = f2bf(hn[0] + hn[1]);
            csum_out[(size_t)p0 * MEM + mg] = cn[0] + cn[1];
        }
        if (base + 2 < n){
            int p1 = (base >> 1) + 1;
            A_next[(size_t)p1 * KTOT + IN_DIM + mg] = f2bf(hn[2] + hn[3]);
            csum_out[(size_t)p1 * MEM + mg] = cn[2] + cn[3];
        }
    }
}

// ---------------- tail: levels 7..0 + FC fused, 8 blocks x 512 threads, fence-free barrier.
// 8 waves: wm (0..3) = 16-row fragment, wc (0..1) = mem 16-half. Halves per-thread
// epilogue/stage vs the 256-thread version; same LDS, same barrier structure.
__global__ __launch_bounds__(512) void tail_kernel(
    const unsigned short* __restrict__ arena,
    const unsigned short* __restrict__ Wp, const float* __restrict__ bp,
    float* cs_in, float* cs_out,
    float* __restrict__ c_root,
    const float* __restrict__ W_fc, const float* __restrict__ b_fc,
    float* __restrict__ out, unsigned* __restrict__ ctr)
{
    __shared__ __align__(16) unsigned short WpL[128 * KTOT];   // 96 KB
    __shared__ __align__(16) unsigned short AL[64 * KTOT];     // 48 KB

    const int tid  = threadIdx.x;
    const int lane = tid & 63;
    const int wid  = tid >> 6;        // 0..7
    const int wm   = wid >> 1;        // 0..3: 16-row fragment
    const int wc   = wid & 1;         // mem 16-half
    const int m0   = blockIdx.x * 32;
    const int mg   = m0 + wc * 16 + (lane & 15);

    #pragma unroll
    for (int i = 0; i < 12; ++i){
        int p0 = wid * 768 + i * 64;
        int p  = p0 + lane;
        int lrow  = p / 48;
        int pslot = p % 48;
        int lslot = pslot ^ (lrow & 7);
        int grow  = (lrow >> 5) * 256 + m0 + (lrow & 31);
        gld_lds16(Wp + (size_t)grow * KTOT + lslot * 8, (char*)WpL + (size_t)p0 * 16);
    }

    const float b0 = bp[0 * 256 + mg];
    const float b1 = bp[1 * 256 + mg];
    const float b2 = bp[2 * 256 + mg];
    const float b3 = bp[3 * 256 + mg];

    asm volatile("s_waitcnt vmcnt(0)" ::: "memory");
    __builtin_amdgcn_s_barrier();

    unsigned gen = 0;
    for (int l = 7; l >= 0; --l){
        const int n = 1 << l;
        const unsigned short* Al = arena + offA(l);
        const int nhalf = (n > 64) ? (n >> 6) : 1;

        for (int h = 0; h < nhalf; ++h){
            const int r0 = h * 64;
            const int rows = (n < 64) ? n : 64;

            // ---- batched stage (device-coherent reads)
            const int nslots = rows * 48;
            for (int t = 0; t * 512 < nslots; ++t){
                int pbase = t * 512 + wid * 64;
                int p = pbase + lane;
                if (p < nslots){
                    int row   = p / 48;
                    int pslot = p - row * 48;
                    int lslot = pslot ^ (row & 7);
                    gld_lds16_dev(Al + (size_t)(r0 + row) * KTOT + lslot * 8,
                                  (char*)AL + (size_t)pbase * 16);
                }
            }

            // ---- csum prefetch (device-coherent)
            const int base = r0 + wm * 16 + (lane >> 4) * 4;
            float cpre[4];
            #pragma unroll
            for (int e = 0; e < 4; ++e)
                cpre[e] = __hip_atomic_load(&cs_in[(size_t)(base + e) * MEM + mg],
                                            __ATOMIC_RELAXED, __HIP_MEMORY_SCOPE_AGENT);

            asm volatile("s_waitcnt vmcnt(0)" ::: "memory");
            __builtin_amdgcn_s_barrier();

            f32x4 acc[4];
            #pragma unroll
            for (int q = 0; q < 4; ++q)
                acc[q] = (f32x4){0.f, 0.f, 0.f, 0.f};

            #pragma unroll
            for (int kc = 0; kc < 12; ++kc){
                const int ls = kc * 4 + (lane >> 4);
                const int kb = (ls ^ (lane & 7)) * 8;
                s16x8 a = *(const s16x8*)(AL + (size_t)(wm * 16 + (lane & 15)) * KTOT + kb);
                s16x8 b[4];
                #pragma unroll
                for (int q = 0; q < 4; ++q)
                    b[q] = *(const s16x8*)(WpL + (q * 32 + wc * 16 + (lane & 15)) * KTOT + kb);
                #pragma unroll
                for (int q = 0; q < 4; ++q)
                    acc[q] = __builtin_amdgcn_mfma_f32_16x16x32_bf16(a, b[q], acc[q], 0, 0, 0);
            }

            {
                float cn[4], hn[4];
                #pragma unroll
                for (int e = 0; e < 4; ++e){
                    float iv = acc[0][e] + b0;
                    float fv = acc[1][e] + b1;
                    float gv = acc[2][e] + b2;
                    float ov = acc[3][e] + b3;
                    float c  = fsigm(fv) * cpre[e] + fsigm(iv) * ftanh(gv);
                    cn[e] = c;
                    hn[e] = fsigm(ov) * ftanh(c);
                }
                if (l == 0){
                    if (base == 0) st32_dev(&c_root[mg], cn[0]);
                } else {
                    unsigned short* A_next = (unsigned short*)arena + offA(l - 1);
                    if (base < n){
                        int p0 = base >> 1;
                        st16_dev(&A_next[(size_t)p0 * KTOT + IN_DIM + mg], f2bf(hn[0] + hn[1]));
                        st32_dev(&cs_out[(size_t)p0 * MEM + mg], cn[0] + cn[1]);
                    }
                    if (base + 2 < n){
                        int p1 = (base >> 1) + 1;
                        st16_dev(&A_next[(size_t)p1 * KTOT + IN_DIM + mg], f2bf(hn[2] + hn[3]));
                        st32_dev(&cs_out[(size_t)p1 * MEM + mg], cn[2] + cn[3]);
                    }
                }
            }
            __builtin_amdgcn_s_barrier();   // all waves done with AL before restage
        }

        float* t = cs_in; cs_in = cs_out; cs_out = t;
        ++gen;
        grid_barrier_nf(ctr, (unsigned)(NBLK_TAIL * gen));
    }

    if (blockIdx.x == 0 && wid < 4){
        int w = wid;
        for (int cls = w * 3; cls < w * 3 + 3; ++cls){
            float s = 0.f;
            for (int m = lane; m < 256; m += 64){
                float cr = __hip_atomic_load(&c_root[m], __ATOMIC_RELAXED, __HIP_MEMORY_SCOPE_AGENT);
                s += cr * W_fc[cls * 256 + m];
            }
            #pragma unroll
            for (int off = 32; off; off >>= 1)
                s += __shfl_down(s, off, 64);
            if (lane == 0) out[cls] = s + b_fc[cls];
        }
    }
}

extern "C" void kernel_launch(void* const* d_in, const int* in_sizes, int n_in,
                              void* d_out, int out_size, void* d_ws, size_t ws_size,
                              hipStream_t stream)
{
    const float* x    = (const float*)d_in[0];
    const float* W_ih = (const float*)d_in[1];
    const float* b_ih = (const float*)d_in[2];
    const float* W_hh = (const float*)d_in[3];
    const float* b_hh = (const float*)d_in[4];
    const float* W_fc = (const float*)d_in[5];
    const float* b_fc = (const float*)d_in[6];
    float* out = (float*)d_out;

    const size_t OFF_WP = 0;
    const size_t OFF_BP = 786432;
    const size_t OFF_A  = 790528;
    const size_t OFF_CS0 = OFF_A + (size_t)(ARENA_ELEMS + ARENA_PAD) * 2;
    const size_t OFF_CS1 = OFF_CS0 + 33554432;
    const size_t OFF_CR  = OFF_CS1 + 33554432;
    const size_t OFF_CTR = OFF_CR + 1024;
    const size_t NEEDED  = OFF_CTR + 64;
    if (ws_size < NEEDED) return;

    char* ws = (char*)d_ws;
    unsigned short* Wp    = (unsigned short*)(ws + OFF_WP);
    float* bp             = (float*)(ws + OFF_BP);
    unsigned short* arena = (unsigned short*)(ws + OFF_A);
    float* cs0            = (float*)(ws + OFF_CS0);
    float* cs1            = (float*)(ws + OFF_CS1);
    float* c_root         = (float*)(ws + OFF_CR);
    unsigned* ctr         = (unsigned*)(ws + OFF_CTR);

    pack_kernel<<<dim3(2048), dim3(256), 0, stream>>>(
        x, W_ih, b_ih, W_hh, b_hh, Wp, bp, arena, ctr);

    // ---- leaf (l=16): n=65536, K=128 -> A(15), cs0. RB=2 + LEAF dead-code (f-gate removed).
    gemm_lstm_kernel<IN_DIM, 2, true><<<dim3(NLEAF / 64, 8), dim3(256), 0, stream>>>(
        arena + offA(16), NLEAF, Wp, bp,
        nullptr, arena + offA(15), cs0);

    // ---- l=15, l=14: 8-phase 256-row kernel (frozen)
    gemm_lstm8p_kernel<KTOT><<<dim3(128, 4), dim3(512), 0, stream>>>(
        arena + offA(15), 32768, Wp, bp, cs0, arena + offA(14), cs1);
    gemm_lstm8p_kernel<KTOT><<<dim3(64, 4), dim3(512), 0, stream>>>(
        arena + offA(14), 16384, Wp, bp, cs1, arena + offA(13), cs0);

    // ---- l=13: RB=4
    gemm_lstm_kernel<KTOT, 4, false><<<dim3(64, 8), dim3(256), 0, stream>>>(
        arena + offA(13), 8192, Wp, bp, cs0, arena + offA(12), cs1);

    // ---- l=12..8: RB=2
    float* cs_in = cs1; float* cs_out = cs0;
    for (int l = 12; l >= 8; --l){
        int n = 1 << l;
        gemm_lstm_kernel<KTOT, 2, false><<<dim3(n / 64, 8), dim3(256), 0, stream>>>(
            arena + offA(l), n, Wp, bp,
            cs_in, arena + offA(l - 1), cs_out);
        float* t = cs_in; cs_in = cs_out; cs_out = t;
    }

    // ---- tail: levels 7..0 + FC (8 blocks x 512 threads, fence-free barrier)
    tail_kernel<<<dim3(NBLK_TAIL), dim3(512), 0, stream>>>(
        arena, Wp, bp, cs_in, cs_out, c_root, W_fc, b_fc, out, ctr);
}

// Round 19
// 193.349 us; speedup vs baseline: 1.2246x; 1.0026x over previous
//
#include <hip/hip_runtime.h>
#include <hip/hip_bf16.h>
#include <cstddef>

#define IN_DIM 128
#define MEM 256
#define KTOT 384
#define NLEAF 65536
#define NBLK_TAIL 8

typedef float f32x4 __attribute__((ext_vector_type(4)));
typedef short s16x8 __attribute__((ext_vector_type(8)));
typedef unsigned int u32;

__device__ inline unsigned short f2bf(float f){
    unsigned int u = __builtin_bit_cast(unsigned int, f);
    u += 0x7fff + ((u >> 16) & 1);
    return (unsigned short)(u >> 16);
}

__device__ inline void gld_lds16(const void* g, void* l){
    __builtin_amdgcn_global_load_lds((const __attribute__((address_space(1))) u32*)g,
                                     (__attribute__((address_space(3))) u32*)l, 16, 0, 0);
}
// device-coherent (SC0|SC1): read from coherence point, bypass stale L1/L2
__device__ inline void gld_lds16_dev(const void* g, void* l){
    __builtin_amdgcn_global_load_lds((const __attribute__((address_space(1))) u32*)g,
                                     (__attribute__((address_space(3))) u32*)l, 16, 0, 17);
}
// write-through device-coherent stores
__device__ inline void st16_dev(unsigned short* p, unsigned short v){
    unsigned int vv = v;
    asm volatile("global_store_short %0, %1, off sc0 sc1" :: "v"(p), "v"(vv) : "memory");
}
__device__ inline void st32_dev(float* p, float v){
    asm volatile("global_store_dword %0, %1, off sc0 sc1" :: "v"(p), "v"(v) : "memory");
}

__device__ inline float fsigm(float x){
    return __builtin_amdgcn_rcpf(1.f + __expf(-x));
}
__device__ inline float ftanh(float x){
    return 2.f * __builtin_amdgcn_rcpf(1.f + __expf(-2.f * x)) - 1.f;
}

// A-arena element offsets: leaf (l=16) at 0, stride 128; levels 15..0 stride 384.
__host__ __device__ inline size_t offA(int l){
    if (l == 16) return 0;
    return 8388608u + 384u * (65536u - (1u << (l + 1)));
}
#define ARENA_ELEMS 33554048u
#define ARENA_PAD   65536u

// FENCE-FREE grid barrier (8 co-resident blocks): all cross-block data flows via
// coherence point (sc0sc1 stores / aux=17 loads / agent atomics) -> no wbl2/inv.
__device__ inline void grid_barrier_nf(unsigned* ctr, unsigned target){
    asm volatile("s_waitcnt vmcnt(0)" ::: "memory");
    __syncthreads();
    if (threadIdx.x == 0){
        __hip_atomic_fetch_add(ctr, 1u, __ATOMIC_RELAXED, __HIP_MEMORY_SCOPE_AGENT);
        while (__hip_atomic_load(ctr, __ATOMIC_RELAXED, __HIP_MEMORY_SCOPE_AGENT) < target)
            __builtin_amdgcn_s_sleep(2);
    }
    __syncthreads();
}

// ---------------- pack: W (+bias, +ctr reset) and LEAF x rows only -> bf16 arena
// (inner-level x packing is fused into the leaf GEMM kernel, overlapping its VALU phase)
__global__ void pack_kernel(const float* __restrict__ x,
                            const float* __restrict__ W_ih, const float* __restrict__ b_ih,
                            const float* __restrict__ W_hh, const float* __restrict__ b_hh,
                            unsigned short* __restrict__ Wp, float* __restrict__ bp,
                            unsigned short* __restrict__ Aarena, unsigned* __restrict__ ctr){
    const int stride = gridDim.x * blockDim.x;
    const int tid0 = blockIdx.x * blockDim.x + threadIdx.x;
    if (tid0 == 0){ ctr[0] = 0; }

    for (int g = tid0; g < 1024 * 48; g += stride){
        int row = g / 48, ko = (g - row * 48) * 8;
        const float* s = (ko < IN_DIM) ? (W_ih + (size_t)row * IN_DIM + ko)
                                       : (W_hh + (size_t)row * MEM + (ko - IN_DIM));
        f32x4 v0 = *(const f32x4*)s, v1 = *(const f32x4*)(s + 4);
        s16x8 o;
        #pragma unroll
        for (int e = 0; e < 4; ++e){ o[e] = (short)f2bf(v0[e]); o[4+e] = (short)f2bf(v1[e]); }
        *(s16x8*)(Wp + (size_t)row * KTOT + ko) = o;
        if (ko == 0) bp[row] = b_ih[row] + b_hh[row];
    }

    // leaf x: rows 65535..131070 -> arena[j][0..127], stride 128
    const int TOTAL_G = 65536 * 16;
    for (int g = tid0; g < TOTAL_G; g += stride){
        int j  = g >> 4;
        int ko = (g & 15) * 8;
        const f32x4* s = (const f32x4*)(x + (size_t)(65535 + j) * IN_DIM + ko);
        f32x4 v0 = s[0], v1 = s[1];
        s16x8 o;
        #pragma unroll
        for (int e = 0; e < 4; ++e){ o[e] = (short)f2bf(v0[e]); o[4+e] = (short)f2bf(v1[e]); }
        *(s16x8*)(Aarena + (size_t)j * IN_DIM + ko) = o;
    }
}

// ================= 8-phase-style 256-row GEMM + LSTM + pair-sum (l15, l14) — frozen =================
template<int NK>
__global__ __launch_bounds__(512, 1) void gemm_lstm8p_kernel(
    const unsigned short* __restrict__ A, int n,
    const unsigned short* __restrict__ Wp, const float* __restrict__ bp,
    const float* __restrict__ csum_in,
    unsigned short* __restrict__ A_next, float* __restrict__ csum_out)
{
    __shared__ __align__(16) unsigned short As[2][2][128 * 64];   // [buf][half] 64 KB
    __shared__ __align__(16) unsigned short Bs[2][2][128 * 64];   // 64 KB

    const int tid  = threadIdx.x;
    const int lane = tid & 63;
    const int wid  = tid >> 6;        // 0..7
    const int wm   = wid >> 2;        // A row-half (128 rows)
    const int wn   = wid & 3;         // mem 16-col group
    const int row0 = blockIdx.x * 256;
    const int m0   = blockIdx.y * 64;
    const int mg   = m0 + wn * 16 + (lane & 15);

    auto stageA = [&](int kt, int h){
        #pragma unroll
        for (int i = 0; i < 2; ++i){
            int p  = i * 512 + tid;
            int r  = p >> 3;
            int ls = (p & 7) ^ (r & 7);
            gld_lds16(A + (size_t)(row0 + h * 128 + r) * NK + kt * 64 + ls * 8,
                      (char*)As[kt & 1][h] + (size_t)(i * 512 + wid * 64) * 16);
        }
    };
    auto stageB = [&](int kt, int h){
        #pragma unroll
        for (int i = 0; i < 2; ++i){
            int p  = i * 512 + tid;
            int r  = p >> 3;
            int b  = h * 128 + r;
            int grow = (b >> 6) * 256 + m0 + (b & 63);
            int ls = (p & 7) ^ (r & 7);
            gld_lds16(Wp + (size_t)grow * KTOT + kt * 64 + ls * 8,
                      (char*)Bs[kt & 1][h] + (size_t)(i * 512 + wid * 64) * 16);
        }
    };

    f32x4 acc[8][4];
    #pragma unroll
    for (int r = 0; r < 8; ++r)
        #pragma unroll
        for (int q = 0; q < 4; ++q)
            acc[r][q] = (f32x4){0.f, 0.f, 0.f, 0.f};

    constexpr int nkt = NK / 64;
    stageA(0, 0); stageA(0, 1); stageB(0, 0);
    if (nkt > 1) stageB(1, 0);
    stageB(0, 1);

    s16x8 bfr[2][2];

    #pragma unroll
    for (int t = 0; t < nkt; ++t){
        const unsigned short* Ab = As[t & 1][wm];
        const unsigned short* Bb0 = Bs[t & 1][0];
        const unsigned short* Bb1 = Bs[t & 1][1];

        if (t + 1 < nkt) { asm volatile("s_waitcnt vmcnt(4)" ::: "memory"); }
        else             { asm volatile("s_waitcnt vmcnt(2)" ::: "memory"); }
        __builtin_amdgcn_s_barrier();
        asm volatile("" ::: "memory");

        #pragma unroll
        for (int rh = 0; rh < 2; ++rh){
            s16x8 a[4][2];
            #pragma unroll
            for (int j = 0; j < 4; ++j)
                #pragma unroll
                for (int ks = 0; ks < 2; ++ks){
                    int kb = (((ks * 4 + (lane >> 4)) ^ (lane & 7))) * 8;
                    a[j][ks] = *(const s16x8*)(Ab + (size_t)(rh * 64 + j * 16 + (lane & 15)) * 64 + kb);
                }
            if (rh == 0){
                #pragma unroll
                for (int q2 = 0; q2 < 2; ++q2)
                    #pragma unroll
                    for (int ks = 0; ks < 2; ++ks){
                        int kb = (((ks * 4 + (lane >> 4)) ^ (lane & 7))) * 8;
                        bfr[q2][ks] = *(const s16x8*)(Bb0 + (size_t)(q2 * 64 + wn * 16 + (lane & 15)) * 64 + kb);
                    }
                if (t + 1 < nkt) stageA(t + 1, 0);
            } else {
                if (t + 1 < nkt) stageA(t + 1, 1);
            }
            __builtin_amdgcn_s_setprio(1);
            #pragma unroll
            for (int j = 0; j < 4; ++j)
                #pragma unroll
                for (int q2 = 0; q2 < 2; ++q2)
                    #pragma unroll
                    for (int ks = 0; ks < 2; ++ks)
                        acc[rh * 4 + j][q2] = __builtin_amdgcn_mfma_f32_16x16x32_bf16(
                            a[j][ks], bfr[q2][ks], acc[rh * 4 + j][q2], 0, 0, 0);
            __builtin_amdgcn_s_setprio(0);
        }

        if (t + 1 < nkt) { asm volatile("s_waitcnt vmcnt(4)" ::: "memory"); }
        else             { asm volatile("s_waitcnt vmcnt(0)" ::: "memory"); }
        __builtin_amdgcn_s_barrier();
        asm volatile("" ::: "memory");

        #pragma unroll
        for (int rh = 0; rh < 2; ++rh){
            s16x8 a[4][2];
            #pragma unroll
            for (int j = 0; j < 4; ++j)
                #pragma unroll
                for (int ks = 0; ks < 2; ++ks){
                    int kb = (((ks * 4 + (lane >> 4)) ^ (lane & 7))) * 8;
                    a[j][ks] = *(const s16x8*)(Ab + (size_t)(rh * 64 + j * 16 + (lane & 15)) * 64 + kb);
                }
            if (rh == 0){
                #pragma unroll
                for (int q2 = 0; q2 < 2; ++q2)
                    #pragma unroll
                    for (int ks = 0; ks < 2; ++ks){
                        int kb = (((ks * 4 + (lane >> 4)) ^ (lane & 7))) * 8;
                        bfr[q2][ks] = *(const s16x8*)(Bb1 + (size_t)(q2 * 64 + wn * 16 + (lane & 15)) * 64 + kb);
                    }
                if (t + 2 < nkt) stageB(t + 2, 0);
            } else {
                if (t + 1 < nkt) stageB(t + 1, 1);
            }
            __builtin_amdgcn_s_setprio(1);
            #pragma unroll
            for (int j = 0; j < 4; ++j)
                #pragma unroll
                for (int q2 = 0; q2 < 2; ++q2)
                    #pragma unroll
                    for (int ks = 0; ks < 2; ++ks)
                        acc[rh * 4 + j][2 + q2] = __builtin_amdgcn_mfma_f32_16x16x32_bf16(
                            a[j][ks], bfr[q2][ks], acc[rh * 4 + j][2 + q2], 0, 0, 0);
            __builtin_amdgcn_s_setprio(0);
        }
        __builtin_amdgcn_s_barrier();
        asm volatile("" ::: "memory");
    }

    const float b0 = bp[0 * 256 + mg];
    const float b1 = bp[1 * 256 + mg];
    const float b2 = bp[2 * 256 + mg];
    const float b3 = bp[3 * 256 + mg];
    #pragma unroll
    for (int r = 0; r < 8; ++r){
        const int base = row0 + wm * 128 + r * 16 + (lane >> 4) * 4;
        float cpre[4];
        #pragma unroll
        for (int e = 0; e < 4; ++e)
            cpre[e] = csum_in[(size_t)(base + e) * MEM + mg];
        float cn[4], hn[4];
        #pragma unroll
        for (int e = 0; e < 4; ++e){
            float iv = acc[r][0][e] + b0;
            float fv = acc[r][1][e] + b1;
            float gv = acc[r][2][e] + b2;
            float ov = acc[r][3][e] + b3;
            float c  = fsigm(fv) * cpre[e] + fsigm(iv) * ftanh(gv);
            cn[e] = c;
            hn[e] = fsigm(ov) * ftanh(c);
        }
        int p0 = base >> 1;
        A_next[(size_t)p0 * KTOT + IN_DIM + mg] = f2bf(hn[0] + hn[1]);
        csum_out[(size_t)p0 * MEM + mg] = cn[0] + cn[1];
        A_next[(size_t)(p0 + 1) * KTOT + IN_DIM + mg] = f2bf(hn[2] + hn[3]);
        csum_out[(size_t)(p0 + 1) * MEM + mg] = cn[2] + cn[3];
    }
}

// ================= proven GEMM + LSTM + pair-sum, templated tile height + leaf-DCE + PACKX =================
// RB = row-fragments per wave (BM = 32*RB). LEAF dead-codes the f-gate path (chc==0).
// PACKX: after the final vmcnt(0) drain, a grid-stride loop packs inner-level x rows
// (f32 -> bf16) into the arena — overlapped with this kernel's VALU-bound execution.
#define KC 64

template<int NK, int RB, bool LEAF, bool PACKX>
__global__ __launch_bounds__(256) void gemm_lstm_kernel(
    const unsigned short* __restrict__ A, int n,
    const unsigned short* __restrict__ Wp, const float* __restrict__ bp,
    const float* __restrict__ csum_in,
    unsigned short* __restrict__ A_next, float* __restrict__ csum_out,
    const float* __restrict__ xsrc, unsigned short* __restrict__ arena)
{
    constexpr int BM = RB * 32;
    __shared__ __align__(16) unsigned short As[2][BM * KC];
    __shared__ __align__(16) unsigned short Bs[2][128 * KC];

    const int tid  = threadIdx.x;
    const int lane = tid & 63;
    const int wid  = tid >> 6;
    const int wm   = wid >> 1;
    const int wc   = wid & 1;
    const int row0 = blockIdx.x * BM;
    const int m0   = blockIdx.y * 32;

    const int srow = lane >> 3;
    const int scol = ((lane & 7) ^ srow) * 8;

    const int mg = m0 + wc * 16 + (lane & 15);

    const float b0 = bp[0 * 256 + mg];
    const float b1 = LEAF ? 0.f : bp[1 * 256 + mg];
    const float b2 = bp[2 * 256 + mg];
    const float b3 = bp[3 * 256 + mg];
    float cpre[RB][4];
    if (!LEAF){
        #pragma unroll
        for (int r = 0; r < RB; ++r){
            const int base = row0 + wm * (RB * 16) + r * 16 + (lane >> 4) * 4;
            #pragma unroll
            for (int e = 0; e < 4; ++e)
                cpre[r][e] = csum_in[(size_t)(base + e) * MEM + mg];
        }
    }

    f32x4 acc[RB][4];
    #pragma unroll
    for (int r = 0; r < RB; ++r)
        #pragma unroll
        for (int q = 0; q < 4; ++q)
            acc[r][q] = (f32x4){0.f, 0.f, 0.f, 0.f};

    auto stage = [&](int d, int kk){
        char* asb = (char*)As[d];
        char* bsb = (char*)Bs[d];
        #pragma unroll
        for (int q = 0; q < RB; ++q){
            int t = wid * RB + q;
            int r = t * 8 + srow;
            gld_lds16(A + (size_t)(row0 + r) * NK + kk + scol, asb + t * 1024);
        }
        #pragma unroll
        for (int q = 0; q < 4; ++q){
            int t = wid * 4 + q;
            int b = t * 8 + srow;
            int grow = (b >> 5) * 256 + m0 + (b & 31);
            gld_lds16(Wp + (size_t)grow * KTOT + kk + scol, bsb + t * 1024);
        }
    };

    constexpr int nIter = NK / KC;
    stage(0, 0);
    int buf = 0;
    #pragma unroll
    for (int it = 0; it < nIter; ++it){
        if (it + 1 < nIter){
            stage(buf ^ 1, (it + 1) * KC);
            if constexpr (RB == 4) asm volatile("s_waitcnt vmcnt(8)" ::: "memory");
            else                   asm volatile("s_waitcnt vmcnt(6)" ::: "memory");
        } else {
            asm volatile("s_waitcnt vmcnt(0)" ::: "memory");
        }
        __builtin_amdgcn_s_barrier();
        const unsigned short* Ab = As[buf];
        const unsigned short* Bb = Bs[buf];
        #pragma unroll
        for (int ks = 0; ks < 2; ++ks){
            const int slot = ks * 4 + (lane >> 4);
            const int kb = (slot ^ (lane & 7)) * 8;
            s16x8 a[RB], b[4];
            #pragma unroll
            for (int r = 0; r < RB; ++r)
                a[r] = *(const s16x8*)(Ab + (wm * (RB * 16) + r * 16 + (lane & 15)) * KC + kb);
            #pragma unroll
            for (int q = 0; q < 4; ++q)
                b[q] = *(const s16x8*)(Bb + (q * 32 + wc * 16 + (lane & 15)) * KC + kb);
            #pragma unroll
            for (int r = 0; r < RB; ++r)
                #pragma unroll
                for (int q = 0; q < 4; ++q)
                    acc[r][q] = __builtin_amdgcn_mfma_f32_16x16x32_bf16(a[r], b[q], acc[r][q], 0, 0, 0);
        }
        __builtin_amdgcn_s_barrier();
        buf ^= 1;
    }

    #pragma unroll
    for (int r = 0; r < RB; ++r){
        const int base = row0 + wm * (RB * 16) + r * 16 + (lane >> 4) * 4;
        float cn[4], hn[4];
        #pragma unroll
        for (int e = 0; e < 4; ++e){
            float iv = acc[r][0][e] + b0;
            float gv = acc[r][2][e] + b2;
            float ov = acc[r][3][e] + b3;
            float c;
            if (LEAF){
                c = fsigm(iv) * ftanh(gv);                 // f-gate path dead (chc==0)
            } else {
                float fv = acc[r][1][e] + b1;
                c = fsigm(fv) * cpre[r][e] + fsigm(iv) * ftanh(gv);
            }
            cn[e] = c;
            hn[e] = fsigm(ov) * ftanh(c);
        }
        if (base < n){
            int p0 = base >> 1;
            A_next[(size_t)p0 * KTOT + IN_DIM + mg] = f2bf(hn[0] + hn[1]);
            csum_out[(size_t)p0 * MEM + mg] = cn[0] + cn[1];
        }
        if (base + 2 < n){
            int p1 = (base >> 1) + 1;
            A_next[(size_t)p1 * KTOT + IN_DIM + mg] = f2bf(hn[2] + hn[3]);
            csum_out[(size_t)p1 * MEM + mg] = cn[2] + cn[3];
        }
    }

    // ---- fused inner-x pack (levels 15..0): nodes 0..65534, stride-384 arena rows
    if constexpr (PACKX){
        const int TG = 65535 * 16;
        const int bid = blockIdx.y * gridDim.x + blockIdx.x;
        const int stride_g = gridDim.x * gridDim.y * 256;
        for (int g = bid * 256 + tid; g < TG; g += stride_g){
            int i  = g >> 4;
            int ko = (g & 15) * 8;
            int l  = 31 - __clz(i + 1);
            int j  = i + 1 - (1 << l);
            size_t dst = offA(l) + (size_t)j * KTOT + ko;
            const f32x4* s = (const f32x4*)(xsrc + (size_t)i * IN_DIM + ko);
            f32x4 v0 = s[0], v1 = s[1];
            s16x8 o;
            #pragma unroll
            for (int e = 0; e < 4; ++e){ o[e] = (short)f2bf(v0[e]); o[4+e] = (short)f2bf(v1[e]); }
            *(s16x8*)(arena + dst) = o;
        }
    }
}

// ---------------- tail: levels 7..0 + FC fused, 8 blocks x 512 threads, fence-free barrier (frozen)
__global__ __launch_bounds__(512) void tail_kernel(
    const unsigned short* __restrict__ arena,
    const unsigned short* __restrict__ Wp, const float* __restrict__ bp,
    float* cs_in, float* cs_out,
    float* __restrict__ c_root,
    const float* __restrict__ W_fc, const float* __restrict__ b_fc,
    float* __restrict__ out, unsigned* __restrict__ ctr)
{
    __shared__ __align__(16) unsigned short WpL[128 * KTOT];   // 96 KB
    __shared__ __align__(16) unsigned short AL[64 * KTOT];     // 48 KB

    const int tid  = threadIdx.x;
    const int lane = tid & 63;
    const int wid  = tid >> 6;        // 0..7
    const int wm   = wid >> 1;        // 0..3: 16-row fragment
    const int wc   = wid & 1;         // mem 16-half
    const int m0   = blockIdx.x * 32;
    const int mg   = m0 + wc * 16 + (lane & 15);

    #pragma unroll
    for (int i = 0; i < 12; ++i){
        int p0 = wid * 768 + i * 64;
        int p  = p0 + lane;
        int lrow  = p / 48;
        int pslot = p % 48;
        int lslot = pslot ^ (lrow & 7);
        int grow  = (lrow >> 5) * 256 + m0 + (lrow & 31);
        gld_lds16(Wp + (size_t)grow * KTOT + lslot * 8, (char*)WpL + (size_t)p0 * 16);
    }

    const float b0 = bp[0 * 256 + mg];
    const float b1 = bp[1 * 256 + mg];
    const float b2 = bp[2 * 256 + mg];
    const float b3 = bp[3 * 256 + mg];

    asm volatile("s_waitcnt vmcnt(0)" ::: "memory");
    __builtin_amdgcn_s_barrier();

    unsigned gen = 0;
    for (int l = 7; l >= 0; --l){
        const int n = 1 << l;
        const unsigned short* Al = arena + offA(l);
        const int nhalf = (n > 64) ? (n >> 6) : 1;

        for (int h = 0; h < nhalf; ++h){
            const int r0 = h * 64;
            const int rows = (n < 64) ? n : 64;

            const int nslots = rows * 48;
            for (int t = 0; t * 512 < nslots; ++t){
                int pbase = t * 512 + wid * 64;
                int p = pbase + lane;
                if (p < nslots){
                    int row   = p / 48;
                    int pslot = p - row * 48;
                    int lslot = pslot ^ (row & 7);
                    gld_lds16_dev(Al + (size_t)(r0 + row) * KTOT + lslot * 8,
                                  (char*)AL + (size_t)pbase * 16);
                }
            }

            const int base = r0 + wm * 16 + (lane >> 4) * 4;
            float cpre[4];
            #pragma unroll
            for (int e = 0; e < 4; ++e)
                cpre[e] = __hip_atomic_load(&cs_in[(size_t)(base + e) * MEM + mg],
                                            __ATOMIC_RELAXED, __HIP_MEMORY_SCOPE_AGENT);

            asm volatile("s_waitcnt vmcnt(0)" ::: "memory");
            __builtin_amdgcn_s_barrier();

            f32x4 acc[4];
            #pragma unroll
            for (int q = 0; q < 4; ++q)
                acc[q] = (f32x4){0.f, 0.f, 0.f, 0.f};

            #pragma unroll
            for (int kc = 0; kc < 12; ++kc){
                const int ls = kc * 4 + (lane >> 4);
                const int kb = (ls ^ (lane & 7)) * 8;
                s16x8 a = *(const s16x8*)(AL + (size_t)(wm * 16 + (lane & 15)) * KTOT + kb);
                s16x8 b[4];
                #pragma unroll
                for (int q = 0; q < 4; ++q)
                    b[q] = *(const s16x8*)(WpL + (q * 32 + wc * 16 + (lane & 15)) * KTOT + kb);
                #pragma unroll
                for (int q = 0; q < 4; ++q)
                    acc[q] = __builtin_amdgcn_mfma_f32_16x16x32_bf16(a, b[q], acc[q], 0, 0, 0);
            }

            {
                float cn[4], hn[4];
                #pragma unroll
                for (int e = 0; e < 4; ++e){
                    float iv = acc[0][e] + b0;
                    float fv = acc[1][e] + b1;
                    float gv = acc[2][e] + b2;
                    float ov = acc[3][e] + b3;
                    float c  = fsigm(fv) * cpre[e] + fsigm(iv) * ftanh(gv);
                    cn[e] = c;
                    hn[e] = fsigm(ov) * ftanh(c);
                }
                if (l == 0){
                    if (base == 0) st32_dev(&c_root[mg], cn[0]);
                } else {
                    unsigned short* A_next = (unsigned short*)arena + offA(l - 1);
                    if (base < n){
                        int p0 = base >> 1;
                        st16_dev(&A_next[(size_t)p0 * KTOT + IN_DIM + mg], f2bf(hn[0] + hn[1]));
                        st32_dev(&cs_out[(size_t)p0 * MEM + mg], cn[0] + cn[1]);
                    }
                    if (base + 2 < n){
                        int p1 = (base >> 1) + 1;
                        st16_dev(&A_next[(size_t)p1 * KTOT + IN_DIM + mg], f2bf(hn[2] + hn[3]));
                        st32_dev(&cs_out[(size_t)p1 * MEM + mg], cn[2] + cn[3]);
                    }
                }
            }
            __builtin_amdgcn_s_barrier();
        }

        float* t = cs_in; cs_in = cs_out; cs_out = t;
        ++gen;
        grid_barrier_nf(ctr, (unsigned)(NBLK_TAIL * gen));
    }

    if (blockIdx.x == 0 && wid < 4){
        int w = wid;
        for (int cls = w * 3; cls < w * 3 + 3; ++cls){
            float s = 0.f;
            for (int m = lane; m < 256; m += 64){
                float cr = __hip_atomic_load(&c_root[m], __ATOMIC_RELAXED, __HIP_MEMORY_SCOPE_AGENT);
                s += cr * W_fc[cls * 256 + m];
            }
            #pragma unroll
            for (int off = 32; off; off >>= 1)
                s += __shfl_down(s, off, 64);
            if (lane == 0) out[cls] = s + b_fc[cls];
        }
    }
}

extern "C" void kernel_launch(void* const* d_in, const int* in_sizes, int n_in,
                              void* d_out, int out_size, void* d_ws, size_t ws_size,
                              hipStream_t stream)
{
    const float* x    = (const float*)d_in[0];
    const float* W_ih = (const float*)d_in[1];
    const float* b_ih = (const float*)d_in[2];
    const float* W_hh = (const float*)d_in[3];
    const float* b_hh = (const float*)d_in[4];
    const float* W_fc = (const float*)d_in[5];
    const float* b_fc = (const float*)d_in[6];
    float* out = (float*)d_out;

    const size_t OFF_WP = 0;
    const size_t OFF_BP = 786432;
    const size_t OFF_A  = 790528;
    const size_t OFF_CS0 = OFF_A + (size_t)(ARENA_ELEMS + ARENA_PAD) * 2;
    const size_t OFF_CS1 = OFF_CS0 + 33554432;
    const size_t OFF_CR  = OFF_CS1 + 33554432;
    const size_t OFF_CTR = OFF_CR + 1024;
    const size_t NEEDED  = OFF_CTR + 64;
    if (ws_size < NEEDED) return;

    char* ws = (char*)d_ws;
    unsigned short* Wp    = (unsigned short*)(ws + OFF_WP);
    float* bp             = (float*)(ws + OFF_BP);
    unsigned short* arena = (unsigned short*)(ws + OFF_A);
    float* cs0            = (float*)(ws + OFF_CS0);
    float* cs1            = (float*)(ws + OFF_CS1);
    float* c_root         = (float*)(ws + OFF_CR);
    unsigned* ctr         = (unsigned*)(ws + OFF_CTR);

    pack_kernel<<<dim3(2048), dim3(256), 0, stream>>>(
        x, W_ih, b_ih, W_hh, b_hh, Wp, bp, arena, ctr);

    // ---- leaf (l=16): RB=4 (halves B L2-traffic vs RB=2) + LEAF-DCE + fused inner-x pack
    gemm_lstm_kernel<IN_DIM, 4, true, true><<<dim3(NLEAF / 128, 8), dim3(256), 0, stream>>>(
        arena + offA(16), NLEAF, Wp, bp,
        nullptr, arena + offA(15), cs0, x, arena);

    // ---- l=15, l=14: 8-phase 256-row kernel (frozen)
    gemm_lstm8p_kernel<KTOT><<<dim3(128, 4), dim3(512), 0, stream>>>(
        arena + offA(15), 32768, Wp, bp, cs0, arena + offA(14), cs1);
    gemm_lstm8p_kernel<KTOT><<<dim3(64, 4), dim3(512), 0, stream>>>(
        arena + offA(14), 16384, Wp, bp, cs1, arena + offA(13), cs0);

    // ---- l=13: RB=4
    gemm_lstm_kernel<KTOT, 4, false, false><<<dim3(64, 8), dim3(256), 0, stream>>>(
        arena + offA(13), 8192, Wp, bp, cs0, arena + offA(12), cs1, nullptr, nullptr);

    // ---- l=12..8: RB=2
    float* cs_in = cs1; float* cs_out = cs0;
    for (int l = 12; l >= 8; --l){
        int n = 1 << l;
        gemm_lstm_kernel<KTOT, 2, false, false><<<dim3(n / 64, 8), dim3(256), 0, stream>>>(
            arena + offA(l), n, Wp, bp,
            cs_in, arena + offA(l - 1), cs_out, nullptr, nullptr);
        float* t = cs_in; cs_in = cs_out; cs_out = t;
    }

    // ---- tail: levels 7..0 + FC (8 blocks x 512 threads, fence-free barrier)
    tail_kernel<<<dim3(NBLK_TAIL), dim3(512), 0, stream>>>(
        arena, Wp, bp, cs_in, cs_out, c_root, W_fc, b_fc, out, ctr);
}